// Round 17
// baseline (613.108 us; speedup 1.0000x reference)
//
#include <hip/hip_runtime.h>
#include <hip/hip_bf16.h>

#define CDIM 512
#define HWSZ 4096
#define BATCH 16
#define NQTOT 33

typedef short bf16x8 __attribute__((ext_vector_type(8)));
typedef float f32x4 __attribute__((ext_vector_type(4)));

__device__ __forceinline__ unsigned short f2bf(float f) {
  unsigned int u = __float_as_uint(f);
  u += 0x7fffu + ((u >> 16) & 1u);   // round-to-nearest-even
  return (unsigned short)(u >> 16);
}
__device__ __forceinline__ float bf2f(unsigned short s) {
  return __uint_as_float((unsigned int)s << 16);
}
__device__ __forceinline__ void gload16(const void* g, void* l) {
  __builtin_amdgcn_global_load_lds((const __attribute__((address_space(1))) void*)g,
                                   (__attribute__((address_space(3))) void*)l, 16, 0, 0);
}
// XCD-aware bijective swizzle (nwg % 8 == 0)
__device__ __forceinline__ int2 swz_tiles(int nwgx) {
  int nwg = gridDim.x * gridDim.y;
  int l = blockIdx.y * gridDim.x + blockIdx.x;
  int w = (l & 7) * (nwg >> 3) + (l >> 3);
  return make_int2((w % nwgx) * 128, (w / nwgx) * 128);  // (n0, m0)
}
// Round-12 lesson: never break global coalescing for LDS conflicts. BK=64 rows
// (128B stride) hit the 16-way cliff -> XOR chunk swizzle via pre-swizzled
// GLOBAL source with linear gload_lds dest (rule-21-compliant).

// ---------------- f32 NT GEMM (small M only): C = A*W^T + bias ----------------
#define BM 128
#define BN 128
#define BK 16

__global__ __launch_bounds__(256) void gemm_nt(const float* __restrict__ A,
                                               const float* __restrict__ Wt,
                                               const float* __restrict__ bias,
                                               float* __restrict__ C, int M) {
  const int K = CDIM, N = CDIM;
  __shared__ float As[BK][BM + 4];
  __shared__ float Bs[BK][BN + 4];
  int tid = threadIdx.x;
  int n0 = blockIdx.x * BN;
  int m0 = blockIdx.y * BM;
  int ty = tid >> 4, tx = tid & 15;
  float acc[8][8];
#pragma unroll
  for (int i = 0; i < 8; ++i)
#pragma unroll
    for (int j = 0; j < 8; ++j) acc[i][j] = 0.f;

  for (int k0 = 0; k0 < K; k0 += BK) {
    for (int e = tid; e < (BM * BK / 4); e += 256) {
      int row = e >> 2, kk = (e & 3) << 2;
      float4 va = make_float4(0.f, 0.f, 0.f, 0.f);
      if (m0 + row < M) va = *(const float4*)(A + (size_t)(m0 + row) * K + k0 + kk);
      As[kk + 0][row] = va.x; As[kk + 1][row] = va.y;
      As[kk + 2][row] = va.z; As[kk + 3][row] = va.w;
      float4 vb = *(const float4*)(Wt + (size_t)(n0 + row) * K + k0 + kk);
      Bs[kk + 0][row] = vb.x; Bs[kk + 1][row] = vb.y;
      Bs[kk + 2][row] = vb.z; Bs[kk + 3][row] = vb.w;
    }
    __syncthreads();
#pragma unroll
    for (int k = 0; k < BK; ++k) {
      float a[8], b[8];
      *(float4*)&a[0] = *(float4*)&As[k][ty * 4];
      *(float4*)&a[4] = *(float4*)&As[k][ty * 4 + 64];
      *(float4*)&b[0] = *(float4*)&Bs[k][tx * 4];
      *(float4*)&b[4] = *(float4*)&Bs[k][tx * 4 + 64];
#pragma unroll
      for (int i = 0; i < 8; ++i)
#pragma unroll
        for (int j = 0; j < 8; ++j) acc[i][j] = fmaf(a[i], b[j], acc[i][j]);
    }
    __syncthreads();
  }
#pragma unroll
  for (int i = 0; i < 8; ++i) {
    int m = m0 + ty * 4 + (i < 4 ? i : 60 + i);
    if (m >= M) continue;
#pragma unroll
    for (int jh = 0; jh < 2; ++jh) {
      int n = n0 + tx * 4 + jh * 64;
      float4 v;
      v.x = acc[i][jh * 4 + 0] + bias[n + 0];
      v.y = acc[i][jh * 4 + 1] + bias[n + 1];
      v.z = acc[i][jh * 4 + 2] + bias[n + 2];
      v.w = acc[i][jh * 4 + 3] + bias[n + 3];
      *(float4*)(C + (size_t)m * N + n) = v;
    }
  }
}

// ------- merged K|V bf16 MFMA NT GEMM; BK=64 + XOR chunk swizzle (round-16 transform) -------
__global__ __launch_bounds__(256) void gemm_kv_nt(const unsigned short* __restrict__ A,
                                                  const unsigned short* __restrict__ Wkv,
                                                  const float* __restrict__ bk,
                                                  const float* __restrict__ bv,
                                                  unsigned short* __restrict__ K,
                                                  unsigned short* __restrict__ V) {
  __shared__ unsigned short As[128 * 64];
  __shared__ unsigned short Ws[128 * 64];
  int tid = threadIdx.x;
  int wave = tid >> 6, lane = tid & 63;
  int2 t = swz_tiles(gridDim.x);        // gridDim.x = 8 N-tiles
  int n0 = t.x, m0 = t.y;
  int wm = (wave >> 1) * 64, wn = (wave & 1) * 64;
  f32x4 acc[4][4];
#pragma unroll
  for (int i = 0; i < 4; ++i)
#pragma unroll
    for (int j = 0; j < 4; ++j) acc[i][j] = (f32x4){0.f, 0.f, 0.f, 0.f};

  int rsel = lane & 15;
  int kcsel = lane >> 4;   // 16B chunk within a 32-k subtile (0..3)

  for (int k0 = 0; k0 < CDIM; k0 += 64) {
#pragma unroll
    for (int c = 0; c < 4; ++c) {
      int s = c * 256 + tid;
      int row = s >> 3, ch = s & 7;
      size_t off8 = (size_t)(ch ^ (row & 7)) * 8;
      gload16(A + (size_t)(m0 + row) * CDIM + k0 + off8, (void*)(As + (size_t)s * 8));
      gload16(Wkv + (size_t)(n0 + row) * CDIM + k0 + off8, (void*)(Ws + (size_t)s * 8));
    }
    __syncthreads();
#pragma unroll
    for (int half = 0; half < 2; ++half) {
      int cb = half * 4 + kcsel;
      bf16x8 af[4], bfr[4];
#pragma unroll
      for (int mf = 0; mf < 4; ++mf) {
        int row = wm + mf * 16 + rsel;
        af[mf] = *(const bf16x8*)&As[(row * 8 + (cb ^ (row & 7))) * 8];
      }
#pragma unroll
      for (int nf = 0; nf < 4; ++nf) {
        int row = wn + nf * 16 + rsel;
        bfr[nf] = *(const bf16x8*)&Ws[(row * 8 + (cb ^ (row & 7))) * 8];
      }
#pragma unroll
      for (int mf = 0; mf < 4; ++mf)
#pragma unroll
        for (int nf = 0; nf < 4; ++nf)
          acc[mf][nf] = __builtin_amdgcn_mfma_f32_16x16x32_bf16(af[mf], bfr[nf], acc[mf][nf], 0, 0, 0);
    }
    __syncthreads();
  }
  const float* bias = (n0 < 512) ? bk : bv;
  unsigned short* C = (n0 < 512) ? K : V;
  int nb = (n0 < 512) ? n0 : n0 - 512;
#pragma unroll
  for (int nf = 0; nf < 4; ++nf) {
    int col = nb + wn + nf * 16 + (lane & 15);
    float bv2 = bias[col];
#pragma unroll
    for (int mf = 0; mf < 4; ++mf) {
      int rbase = m0 + wm + mf * 16 + (lane >> 4) * 4;
#pragma unroll
      for (int i = 0; i < 4; ++i)
        C[(size_t)(rbase + i) * CDIM + col] = f2bf(acc[mf][nf][i] + bv2);
    }
  }
}

// ------- split-bf16 f32-precision NT GEMM; BK=64, XOR chunk swizzle (round-16 proven) -------
__global__ __launch_bounds__(256) void gemm3_nt(const float* __restrict__ A,
                                                const unsigned short* __restrict__ Whi,
                                                const unsigned short* __restrict__ Wlo,
                                                const float* __restrict__ bias,
                                                float* __restrict__ C) {
  __shared__ unsigned short AsH[128 * 64];
  __shared__ unsigned short AsL[128 * 64];
  __shared__ unsigned short WsH[128 * 64];
  __shared__ unsigned short WsL[128 * 64];
  int tid = threadIdx.x;
  int wave = tid >> 6, lane = tid & 63;
  int2 t = swz_tiles(gridDim.x);
  int n0 = t.x, m0 = t.y;
  int wm = (wave >> 1) * 64, wn = (wave & 1) * 64;
  f32x4 acc[4][4];
#pragma unroll
  for (int i = 0; i < 4; ++i)
#pragma unroll
    for (int j = 0; j < 4; ++j) acc[i][j] = (f32x4){0.f, 0.f, 0.f, 0.f};

  int rsel = lane & 15;
  int kcsel = lane >> 4;

  for (int k0 = 0; k0 < CDIM; k0 += 64) {
#pragma unroll
    for (int c = 0; c < 4; ++c) {
      int s = c * 256 + tid;
      int row = s >> 3, ch = s & 7;
      size_t gw = (size_t)(n0 + row) * CDIM + k0 + (size_t)(ch ^ (row & 7)) * 8;
      gload16(Whi + gw, (void*)(WsH + (size_t)s * 8));
      gload16(Wlo + gw, (void*)(WsL + (size_t)s * 8));
    }
#pragma unroll
    for (int c = 0; c < 4; ++c) {
      int s = c * 256 + tid;
      int row = s >> 3, q = s & 7;
      const float4* src = (const float4*)(A + (size_t)(m0 + row) * CDIM + k0 + (size_t)(q ^ (row & 7)) * 8);
      float4 v0 = src[0], v1 = src[1];
      float vv[8] = {v0.x, v0.y, v0.z, v0.w, v1.x, v1.y, v1.z, v1.w};
      unsigned int hw[4], lw[4];
#pragma unroll
      for (int j = 0; j < 4; ++j) {
        unsigned int u0 = __float_as_uint(vv[2 * j]);
        unsigned int u1 = __float_as_uint(vv[2 * j + 1]);
        hw[j] = (u0 >> 16) | (u1 & 0xffff0000u);        // truncated hi pair
        float l0 = vv[2 * j] - __uint_as_float(u0 & 0xffff0000u);
        float l1 = vv[2 * j + 1] - __uint_as_float(u1 & 0xffff0000u);
        __hip_bfloat162 l2 = __float22bfloat162_rn(make_float2(l0, l1));
        lw[j] = *reinterpret_cast<unsigned int*>(&l2);  // RNE lo pair
      }
      *(uint4*)&AsH[(size_t)s * 8] = make_uint4(hw[0], hw[1], hw[2], hw[3]);
      *(uint4*)&AsL[(size_t)s * 8] = make_uint4(lw[0], lw[1], lw[2], lw[3]);
    }
    __syncthreads();
#pragma unroll
    for (int half = 0; half < 2; ++half) {
      int cb = half * 4 + kcsel;
      bf16x8 ah[4], al[4], bh[4], bl[4];
#pragma unroll
      for (int mf = 0; mf < 4; ++mf) {
        int row = wm + mf * 16 + rsel;
        int off = (row * 8 + (cb ^ (row & 7))) * 8;
        ah[mf] = *(const bf16x8*)&AsH[off];
        al[mf] = *(const bf16x8*)&AsL[off];
      }
#pragma unroll
      for (int nf = 0; nf < 4; ++nf) {
        int row = wn + nf * 16 + rsel;
        int off = (row * 8 + (cb ^ (row & 7))) * 8;
        bh[nf] = *(const bf16x8*)&WsH[off];
        bl[nf] = *(const bf16x8*)&WsL[off];
      }
#pragma unroll
      for (int mf = 0; mf < 4; ++mf)
#pragma unroll
        for (int nf = 0; nf < 4; ++nf) {
          acc[mf][nf] = __builtin_amdgcn_mfma_f32_16x16x32_bf16(ah[mf], bh[nf], acc[mf][nf], 0, 0, 0);
          acc[mf][nf] = __builtin_amdgcn_mfma_f32_16x16x32_bf16(ah[mf], bl[nf], acc[mf][nf], 0, 0, 0);
          acc[mf][nf] = __builtin_amdgcn_mfma_f32_16x16x32_bf16(al[mf], bh[nf], acc[mf][nf], 0, 0, 0);
        }
    }
    __syncthreads();
  }
#pragma unroll
  for (int nf = 0; nf < 4; ++nf) {
    int col = n0 + wn + nf * 16 + (lane & 15);
    float bvs = bias[col];
#pragma unroll
    for (int mf = 0; mf < 4; ++mf) {
      int rbase = m0 + wm + mf * 16 + (lane >> 4) * 4;
#pragma unroll
      for (int i = 0; i < 4; ++i)
        C[(size_t)(rbase + i) * CDIM + col] = acc[mf][nf][i] + bvs;
    }
  }
}

// ------- ONE-SHOT weight prep: w_off_proj split | w_k conv | w_v conv | w_dw transpose -------
__global__ __launch_bounds__(256) void conv_all(const float* __restrict__ w_off_proj,
                                                const float* __restrict__ w_k,
                                                const float* __restrict__ w_v,
                                                const float* __restrict__ w_dw,
                                                unsigned short* __restrict__ wphi,
                                                unsigned short* __restrict__ wplo,
                                                unsigned short* __restrict__ wkv,
                                                float* __restrict__ wdwT) {
  int blk = blockIdx.x, tid = threadIdx.x;
  if (blk < 256) {                       // hi/lo split of w_off_proj (float4 granules)
    int i = blk * 256 + tid;
    float4 v = ((const float4*)w_off_proj)[i];
    ushort4 h, l;
    h.x = f2bf(v.x); l.x = f2bf(v.x - bf2f(h.x));
    h.y = f2bf(v.y); l.y = f2bf(v.y - bf2f(h.y));
    h.z = f2bf(v.z); l.z = f2bf(v.z - bf2f(h.z));
    h.w = f2bf(v.w); l.w = f2bf(v.w - bf2f(h.w));
    ((ushort4*)wphi)[i] = h;
    ((ushort4*)wplo)[i] = l;
  } else if (blk < 512) {                // w_k -> wkv[0..]
    int i = (blk - 256) * 256 + tid;
    float4 v = ((const float4*)w_k)[i];
    ushort4 o;
    o.x = f2bf(v.x); o.y = f2bf(v.y); o.z = f2bf(v.z); o.w = f2bf(v.w);
    ((ushort4*)wkv)[i] = o;
  } else if (blk < 768) {                // w_v -> wkv[262144..]
    int i = (blk - 512) * 256 + tid;
    float4 v = ((const float4*)w_v)[i];
    ushort4 o;
    o.x = f2bf(v.x); o.y = f2bf(v.y); o.z = f2bf(v.z); o.w = f2bf(v.w);
    ((ushort4*)(wkv + (size_t)CDIM * CDIM))[i] = o;
  } else {                               // w_dw [512][9] -> [9][512]
    int id = (blk - 768) * 256 + tid;
    if (id < 9 * CDIM) wdwT[id] = w_dw[(id & 511) * 9 + (id >> 9)];
  }
}

// ------- FUSED: depthwise3x3 + LN + GELU + offset head + bilinear gather -> bf16 xs -------
__global__ __launch_bounds__(512) void offset_gather_kernel(
    const float* __restrict__ t0, const float* __restrict__ x,
    const float* __restrict__ w_dwT, const float* __restrict__ b_dw,
    const float* __restrict__ ln_g, const float* __restrict__ ln_b,
    const float* __restrict__ w_off, unsigned short* __restrict__ xs) {
  __shared__ float4 sten[18 * 128];
  __shared__ float redA[8], redB[8], redC[8], redD[8];
  __shared__ int4 sid[4];
  __shared__ float4 swt[4];

  int blk = blockIdx.x;
  int b = blk >> 10, rem = blk & 1023;
  int h = rem >> 4, w0 = (rem & 15) << 2;
  int t = threadIdx.x;
  const float* base = t0 + (size_t)b * HWSZ * CDIM;

  for (int s = t; s < 18 * 128; s += 512) {
    int ps = s >> 7, q = s & 127;
    int r = ps / 6, cs = ps - r * 6;
    int hh = h + r - 1, ww = w0 + cs - 1;
    if ((unsigned)hh < 64u && (unsigned)ww < 64u) {
      gload16(base + (size_t)(hh * 64 + ww) * CDIM + 4 * q, (void*)(sten + s));
    } else {
      sten[s] = make_float4(0.f, 0.f, 0.f, 0.f);
    }
  }
  __syncthreads();

  int p = t >> 7;
  int l128 = t & 127;
  float4 acc = ((const float4*)b_dw)[l128];
#pragma unroll
  for (int r = 0; r < 3; ++r)
#pragma unroll
    for (int dxi = 0; dxi < 3; ++dxi) {
      float4 w4 = ((const float4*)(w_dwT + (size_t)(r * 3 + dxi) * CDIM))[l128];
      float4 v = sten[(r * 6 + p + dxi) * 128 + l128];
      acc.x = fmaf(v.x, w4.x, acc.x);
      acc.y = fmaf(v.y, w4.y, acc.y);
      acc.z = fmaf(v.z, w4.z, acc.z);
      acc.w = fmaf(v.w, w4.w, acc.w);
    }
  float s = acc.x + acc.y + acc.z + acc.w;
  float s2 = acc.x * acc.x + acc.y * acc.y + acc.z * acc.z + acc.w * acc.w;
#pragma unroll
  for (int off = 32; off; off >>= 1) {
    s += __shfl_xor(s, off, 64);
    s2 += __shfl_xor(s2, off, 64);
  }
  int wv = t >> 6, lane = t & 63;
  if (!lane) { redA[wv] = s; redB[wv] = s2; }
  __syncthreads();
  s = redA[2 * p] + redA[2 * p + 1];
  s2 = redB[2 * p] + redB[2 * p + 1];
  float mean = s * (1.f / 512.f);
  float var = s2 * (1.f / 512.f) - mean * mean;
  float inv = 1.f / sqrtf(var + 1e-5f);

  float4 g4 = ((const float4*)ln_g)[l128];
  float4 lb4 = ((const float4*)ln_b)[l128];
  float4 wy4 = ((const float4*)w_off)[l128];
  float4 wx4 = ((const float4*)(w_off + CDIM))[l128];
  float4 xn;
  xn.x = (acc.x - mean) * inv * g4.x + lb4.x;
  xn.y = (acc.y - mean) * inv * g4.y + lb4.y;
  xn.z = (acc.z - mean) * inv * g4.z + lb4.z;
  xn.w = (acc.w - mean) * inv * g4.w + lb4.w;
  float4 ge;
  ge.x = xn.x * 0.5f * (1.f + erff(xn.x * 0.70710678118654752f));
  ge.y = xn.y * 0.5f * (1.f + erff(xn.y * 0.70710678118654752f));
  ge.z = xn.z * 0.5f * (1.f + erff(xn.z * 0.70710678118654752f));
  ge.w = xn.w * 0.5f * (1.f + erff(xn.w * 0.70710678118654752f));
  float oy = ge.x * wy4.x + ge.y * wy4.y + ge.z * wy4.z + ge.w * wy4.w;
  float ox = ge.x * wx4.x + ge.y * wx4.y + ge.z * wx4.z + ge.w * wx4.w;
#pragma unroll
  for (int off = 32; off; off >>= 1) {
    oy += __shfl_xor(oy, off, 64);
    ox += __shfl_xor(ox, off, 64);
  }
  if (!lane) { redC[wv] = oy; redD[wv] = ox; }
  __syncthreads();
  if (l128 == 0) {
    oy = redC[2 * p] + redC[2 * p + 1];
    ox = redD[2 * p] + redD[2 * p + 1];
    int wcol = w0 + p;
    float ry = ((float)h + 0.5f) / 64.f * 2.f - 1.f;
    float rx = ((float)wcol + 0.5f) / 64.f * 2.f - 1.f;
    float py = tanhf(oy + ry);
    float px = tanhf(ox + rx);
    float fx = (px + 1.f) * 0.5f * 63.f;
    float fy = (py + 1.f) * 0.5f * 63.f;
    float fx0 = floorf(fx), fy0 = floorf(fy);
    float fx1 = fx0 + 1.f, fy1 = fy0 + 1.f;
    float wx1 = fx - fx0, wx0 = fx1 - fx;
    float wy1 = fy - fy0, wy0 = fy1 - fy;
    float m00 = (fy0 >= 0.f && fy0 <= 63.f && fx0 >= 0.f && fx0 <= 63.f) ? 1.f : 0.f;
    float m01 = (fy0 >= 0.f && fy0 <= 63.f && fx1 >= 0.f && fx1 <= 63.f) ? 1.f : 0.f;
    float m10 = (fy1 >= 0.f && fy1 <= 63.f && fx0 >= 0.f && fx0 <= 63.f) ? 1.f : 0.f;
    float m11 = (fy1 >= 0.f && fy1 <= 63.f && fx1 >= 0.f && fx1 <= 63.f) ? 1.f : 0.f;
    int xi0 = min(max((int)fx0, 0), 63), xi1 = min(max((int)fx1, 0), 63);
    int yi0 = min(max((int)fy0, 0), 63), yi1 = min(max((int)fy1, 0), 63);
    sid[p] = make_int4(yi0 * 64 + xi0, yi0 * 64 + xi1, yi1 * 64 + xi0, yi1 * 64 + xi1);
    swt[p] = make_float4(wx0 * wy0 * m00, wx1 * wy0 * m01, wx0 * wy1 * m10, wx1 * wy1 * m11);
  }
  __syncthreads();
  int4 id = sid[p];
  float4 wt = swt[p];
  const float* xb = x + (size_t)b * HWSZ * CDIM;
  float4 a = ((const float4*)(xb + (size_t)id.x * CDIM))[l128];
  float4 bb = ((const float4*)(xb + (size_t)id.y * CDIM))[l128];
  float4 cc = ((const float4*)(xb + (size_t)id.z * CDIM))[l128];
  float4 dd = ((const float4*)(xb + (size_t)id.w * CDIM))[l128];
  ushort4 o;
  o.x = f2bf(a.x * wt.x + bb.x * wt.y + cc.x * wt.z + dd.x * wt.w);
  o.y = f2bf(a.y * wt.x + bb.y * wt.y + cc.y * wt.z + dd.y * wt.w);
  o.z = f2bf(a.z * wt.x + bb.z * wt.y + cc.z * wt.z + dd.z * wt.w);
  o.w = f2bf(a.w * wt.x + bb.w * wt.y + cc.w * wt.z + dd.w * wt.w);
  size_t posg = (size_t)b * HWSZ + h * 64 + w0 + p;
  *(ushort4*)(xs + posg * CDIM + l128 * 4) = o;
}

// ------- split-L attention: every block = 128 keys; emits unnormalized partials -------
__global__ __launch_bounds__(256) void attn_split_kernel(const float* __restrict__ qh,
                                                         const unsigned short* __restrict__ kk,
                                                         const unsigned short* __restrict__ vv,
                                                         float* __restrict__ pm,
                                                         float* __restrict__ ps,
                                                         float* __restrict__ po) {
  __shared__ float sc[128];
  __shared__ float qs[64];
  __shared__ float red[4];
  __shared__ float part[4][64];
  int bid = blockIdx.x;
  int h = bid & 7;
  int bs = bid >> 3;
  int b = bs >> 6, s = bs & 63;
  int l0 = (s & 31) << 7;
  int task = b * 33 + (s < 32 ? 0 : s - 31);
  int tid = threadIdx.x;
  if (tid < 64) qs[tid] = qh[(size_t)task * CDIM + h * 64 + tid];
  __syncthreads();

  const unsigned short* kb = kk + ((size_t)b * HWSZ + l0) * CDIM + h * 64;
  float lmax = -INFINITY;
  if (tid < 128) {
    const uint4* kr = (const uint4*)(kb + (size_t)tid * CDIM);
    float sv = 0.f;
#pragma unroll
    for (int c = 0; c < 8; ++c) {
      uint4 kv = kr[c];
      sv = fmaf(__uint_as_float(kv.x << 16), qs[8 * c + 0], sv);
      sv = fmaf(__uint_as_float(kv.x & 0xffff0000u), qs[8 * c + 1], sv);
      sv = fmaf(__uint_as_float(kv.y << 16), qs[8 * c + 2], sv);
      sv = fmaf(__uint_as_float(kv.y & 0xffff0000u), qs[8 * c + 3], sv);
      sv = fmaf(__uint_as_float(kv.z << 16), qs[8 * c + 4], sv);
      sv = fmaf(__uint_as_float(kv.z & 0xffff0000u), qs[8 * c + 5], sv);
      sv = fmaf(__uint_as_float(kv.w << 16), qs[8 * c + 6], sv);
      sv = fmaf(__uint_as_float(kv.w & 0xffff0000u), qs[8 * c + 7], sv);
    }
    sv *= 0.125f;
    sc[tid] = sv;
    lmax = sv;
  }
#pragma unroll
  for (int off = 32; off; off >>= 1) lmax = fmaxf(lmax, __shfl_xor(lmax, off, 64));
  if (!(tid & 63)) red[tid >> 6] = lmax;
  __syncthreads();
  lmax = fmaxf(fmaxf(red[0], red[1]), fmaxf(red[2], red[3]));
  __syncthreads();

  float lsum = 0.f;
  if (tid < 128) {
    float e = expf(sc[tid] - lmax);
    sc[tid] = e;
    lsum = e;
  }
#pragma unroll
  for (int off = 32; off; off >>= 1) lsum += __shfl_xor(lsum, off, 64);
  if (!(tid & 63)) red[tid >> 6] = lsum;
  __syncthreads();
  float tsum = red[0] + red[1] + red[2] + red[3];

  int ch = tid & 63, g = tid >> 6;
  const unsigned short* vb = vv + ((size_t)b * HWSZ + l0) * CDIM + h * 64 + ch;
  float o = 0.f;
#pragma unroll 4
  for (int l = g; l < 128; l += 4) o = fmaf(sc[l], bf2f(vb[(size_t)l * CDIM]), o);
  part[g][ch] = o;
  __syncthreads();
  if (tid < 64) {
    float r = part[0][tid] + part[1][tid] + part[2][tid] + part[3][tid];
    po[(size_t)bid * 64 + tid] = r;
    if (tid == 0) { pm[bid] = lmax; ps[bid] = tsum; }
  }
}

// ------- merge partials (LSE combine) -------
__global__ __launch_bounds__(64) void attn_reduce_kernel(const float* __restrict__ pm,
                                                         const float* __restrict__ ps,
                                                         const float* __restrict__ po,
                                                         float* __restrict__ oo) {
  int bid = blockIdx.x;
  int h = bid & 7, task = bid >> 3;
  int b = task / 33, qidx = task - b * 33;
  int sbase = (qidx == 0) ? 0 : 31 + qidx;
  int ns = (qidx == 0) ? 32 : 1;
  int t = threadIdx.x;
  float mg = -INFINITY;
  for (int i = 0; i < ns; ++i) mg = fmaxf(mg, pm[((size_t)(b * 64 + sbase + i)) * 8 + h]);
  float tot = 0.f, o = 0.f;
  for (int i = 0; i < ns; ++i) {
    size_t pi = ((size_t)(b * 64 + sbase + i)) * 8 + h;
    float w = expf(pm[pi] - mg);
    tot = fmaf(ps[pi], w, tot);
    o = fmaf(po[pi * 64 + t], w, o);
  }
  oo[(size_t)task * CDIM + h * 64 + t] = o / tot;
}

extern "C" void kernel_launch(void* const* d_in, const int* in_sizes, int n_in,
                              void* d_out, int out_size, void* d_ws, size_t ws_size,
                              hipStream_t stream) {
  const float* q          = (const float*)d_in[0];
  const float* x          = (const float*)d_in[1];
  const float* w_off_proj = (const float*)d_in[2];
  const float* b_off_proj = (const float*)d_in[3];
  const float* w_dw       = (const float*)d_in[4];
  const float* b_dw       = (const float*)d_in[5];
  const float* ln_g       = (const float*)d_in[6];
  const float* ln_b       = (const float*)d_in[7];
  const float* w_off      = (const float*)d_in[8];
  const float* w_q        = (const float*)d_in[9];
  const float* b_q        = (const float*)d_in[10];
  const float* w_k        = (const float*)d_in[11];
  const float* b_k        = (const float*)d_in[12];
  const float* w_v        = (const float*)d_in[13];
  const float* b_v        = (const float*)d_in[14];
  const float* w_o        = (const float*)d_in[15];
  const float* b_o        = (const float*)d_in[16];

  char* ws = (char*)d_ws;
  size_t off = 0;
  const size_t NBIG = (size_t)BATCH * HWSZ * CDIM;
  const int NSPLIT = BATCH * 64 * 8;
  float* t0    = (float*)(ws + off);                  off += NBIG * 4;   // 134 MB
  unsigned short* xs_bf = (unsigned short*)(ws + off); off += NBIG * 2;
  unsigned short* k_bf  = (unsigned short*)(ws + off); off += NBIG * 2;
  unsigned short* v_bf  = (unsigned short*)(ws + off); off += NBIG * 2;
  unsigned short* wphi = (unsigned short*)(ws + off);  off += (size_t)CDIM * CDIM * 2;
  unsigned short* wplo = (unsigned short*)(ws + off);  off += (size_t)CDIM * CDIM * 2;
  unsigned short* wkv_bf = (unsigned short*)(ws + off); off += (size_t)2 * CDIM * CDIM * 2;
  float* w_dwT = (float*)(ws + off);                  off += (size_t)9 * CDIM * 4;
  float* qh    = (float*)(ws + off);                  off += (size_t)BATCH * NQTOT * CDIM * 4;
  float* o_all = (float*)(ws + off);                  off += (size_t)BATCH * NQTOT * CDIM * 4;
  float* pm    = (float*)(ws + off);                  off += (size_t)NSPLIT * 4;
  float* ps    = (float*)(ws + off);                  off += (size_t)NSPLIT * 4;
  float* po    = (float*)(ws + off);                  off += (size_t)NSPLIT * 64 * 4;

  const int Mbig = BATCH * HWSZ;  // 65536
  const int Msm  = BATCH * NQTOT; // 528
  dim3 gSm(CDIM / BN, (Msm + BM - 1) / BM);
  dim3 gMf(CDIM / 128, Mbig / 128);
  dim3 gKV(2 * CDIM / 128, Mbig / 128);

  // 0) all weight conversions in one launch
  conv_all<<<786, 256, 0, stream>>>(w_off_proj, w_k, w_v, w_dw, wphi, wplo, wkv_bf, w_dwT);
  // 1) t0 = x @ w_off_proj^T + b ; BK=64, swizzled, in-kernel split
  gemm3_nt<<<gMf, 256, 0, stream>>>(x, wphi, wplo, b_off_proj, t0);
  // 2) fused depthwise+LN+GELU+offset+gather -> bf16 xs
  offset_gather_kernel<<<Mbig / 4, 512, 0, stream>>>(t0, x, w_dwT, b_dw, ln_g, ln_b, w_off, xs_bf);
  // 3) merged K|V projection; BK=64 + swizzle
  gemm_kv_nt<<<gKV, 256, 0, stream>>>(xs_bf, wkv_bf, b_k, b_v, k_bf, v_bf);
  // 4) Q projection
  gemm_nt<<<gSm, 256, 0, stream>>>(q, w_q, b_q, qh, Msm);
  // 5) split-L attention + LSE merge
  attn_split_kernel<<<NSPLIT, 256, 0, stream>>>(qh, k_bf, v_bf, pm, ps, po);
  attn_reduce_kernel<<<Msm * 8, 64, 0, stream>>>(pm, ps, po, o_all);
  // 6) output projection -> d_out
  gemm_nt<<<gSm, 256, 0, stream>>>(o_all, w_o, b_o, (float*)d_out, Msm);
}

// Round 18
// 597.793 us; speedup vs baseline: 1.0256x; 1.0256x over previous
//
#include <hip/hip_runtime.h>
#include <hip/hip_bf16.h>

#define CDIM 512
#define HWSZ 4096
#define BATCH 16
#define NQTOT 33

typedef short bf16x8 __attribute__((ext_vector_type(8)));
typedef float f32x4 __attribute__((ext_vector_type(4)));

__device__ __forceinline__ unsigned short f2bf(float f) {
  unsigned int u = __float_as_uint(f);
  u += 0x7fffu + ((u >> 16) & 1u);   // round-to-nearest-even
  return (unsigned short)(u >> 16);
}
__device__ __forceinline__ float bf2f(unsigned short s) {
  return __uint_as_float((unsigned int)s << 16);
}
__device__ __forceinline__ void gload16(const void* g, void* l) {
  __builtin_amdgcn_global_load_lds((const __attribute__((address_space(1))) void*)g,
                                   (__attribute__((address_space(3))) void*)l, 16, 0, 0);
}
// XCD-aware bijective swizzle (nwg % 8 == 0)
__device__ __forceinline__ int2 swz_tiles(int nwgx) {
  int nwg = gridDim.x * gridDim.y;
  int l = blockIdx.y * gridDim.x + blockIdx.x;
  int w = (l & 7) * (nwg >> 3) + (l >> 3);
  return make_int2((w % nwgx) * 128, (w / nwgx) * 128);  // (n0, m0)
}
// Lessons: (r12) never break global coalescing for LDS conflicts; (r17) BK=64
// only pays when a per-phase VALU stream overlaps MFMA (gemm3's split); for
// pure-gload staging kernels keep BK=32 / small LDS for block-level TLP.

// ---------------- f32 NT GEMM (small M only): C = A*W^T + bias ----------------
#define BM 128
#define BN 128
#define BK 16

__global__ __launch_bounds__(256) void gemm_nt(const float* __restrict__ A,
                                               const float* __restrict__ Wt,
                                               const float* __restrict__ bias,
                                               float* __restrict__ C, int M) {
  const int K = CDIM, N = CDIM;
  __shared__ float As[BK][BM + 4];
  __shared__ float Bs[BK][BN + 4];
  int tid = threadIdx.x;
  int n0 = blockIdx.x * BN;
  int m0 = blockIdx.y * BM;
  int ty = tid >> 4, tx = tid & 15;
  float acc[8][8];
#pragma unroll
  for (int i = 0; i < 8; ++i)
#pragma unroll
    for (int j = 0; j < 8; ++j) acc[i][j] = 0.f;

  for (int k0 = 0; k0 < K; k0 += BK) {
    for (int e = tid; e < (BM * BK / 4); e += 256) {
      int row = e >> 2, kk = (e & 3) << 2;
      float4 va = make_float4(0.f, 0.f, 0.f, 0.f);
      if (m0 + row < M) va = *(const float4*)(A + (size_t)(m0 + row) * K + k0 + kk);
      As[kk + 0][row] = va.x; As[kk + 1][row] = va.y;
      As[kk + 2][row] = va.z; As[kk + 3][row] = va.w;
      float4 vb = *(const float4*)(Wt + (size_t)(n0 + row) * K + k0 + kk);
      Bs[kk + 0][row] = vb.x; Bs[kk + 1][row] = vb.y;
      Bs[kk + 2][row] = vb.z; Bs[kk + 3][row] = vb.w;
    }
    __syncthreads();
#pragma unroll
    for (int k = 0; k < BK; ++k) {
      float a[8], b[8];
      *(float4*)&a[0] = *(float4*)&As[k][ty * 4];
      *(float4*)&a[4] = *(float4*)&As[k][ty * 4 + 64];
      *(float4*)&b[0] = *(float4*)&Bs[k][tx * 4];
      *(float4*)&b[4] = *(float4*)&Bs[k][tx * 4 + 64];
#pragma unroll
      for (int i = 0; i < 8; ++i)
#pragma unroll
        for (int j = 0; j < 8; ++j) acc[i][j] = fmaf(a[i], b[j], acc[i][j]);
    }
    __syncthreads();
  }
#pragma unroll
  for (int i = 0; i < 8; ++i) {
    int m = m0 + ty * 4 + (i < 4 ? i : 60 + i);
    if (m >= M) continue;
#pragma unroll
    for (int jh = 0; jh < 2; ++jh) {
      int n = n0 + tx * 4 + jh * 64;
      float4 v;
      v.x = acc[i][jh * 4 + 0] + bias[n + 0];
      v.y = acc[i][jh * 4 + 1] + bias[n + 1];
      v.z = acc[i][jh * 4 + 2] + bias[n + 2];
      v.w = acc[i][jh * 4 + 3] + bias[n + 3];
      *(float4*)(C + (size_t)m * N + n) = v;
    }
  }
}

// ------- merged K|V bf16 MFMA NT GEMM over Wkv[1024][512]; BK=32 (r15-proven) -------
__global__ __launch_bounds__(256) void gemm_kv_nt(const unsigned short* __restrict__ A,
                                                  const unsigned short* __restrict__ Wkv,
                                                  const float* __restrict__ bk,
                                                  const float* __restrict__ bv,
                                                  unsigned short* __restrict__ K,
                                                  unsigned short* __restrict__ V) {
  __shared__ unsigned short As[128 * 32];
  __shared__ unsigned short Ws[128 * 32];
  int tid = threadIdx.x;
  int wave = tid >> 6, lane = tid & 63;
  int2 t = swz_tiles(gridDim.x);        // gridDim.x = 8 N-tiles
  int n0 = t.x, m0 = t.y;
  int wm = (wave >> 1) * 64, wn = (wave & 1) * 64;
  f32x4 acc[4][4];
#pragma unroll
  for (int i = 0; i < 4; ++i)
#pragma unroll
    for (int j = 0; j < 4; ++j) acc[i][j] = (f32x4){0.f, 0.f, 0.f, 0.f};

  int rsel = lane & 15;
  int ksel = (lane >> 4) * 8;

  for (int k0 = 0; k0 < CDIM; k0 += 32) {
#pragma unroll
    for (int c = 0; c < 2; ++c) {
      int s = c * 256 + tid;
      int row = s >> 2, ch = s & 3;
      gload16(A + (size_t)(m0 + row) * CDIM + k0 + ch * 8, (void*)(As + (size_t)s * 8));
      gload16(Wkv + (size_t)(n0 + row) * CDIM + k0 + ch * 8, (void*)(Ws + (size_t)s * 8));
    }
    __syncthreads();
    bf16x8 af[4], bfr[4];
#pragma unroll
    for (int mf = 0; mf < 4; ++mf)
      af[mf] = *(const bf16x8*)&As[(wm + mf * 16 + rsel) * 32 + ksel];
#pragma unroll
    for (int nf = 0; nf < 4; ++nf)
      bfr[nf] = *(const bf16x8*)&Ws[(wn + nf * 16 + rsel) * 32 + ksel];
#pragma unroll
    for (int mf = 0; mf < 4; ++mf)
#pragma unroll
      for (int nf = 0; nf < 4; ++nf)
        acc[mf][nf] = __builtin_amdgcn_mfma_f32_16x16x32_bf16(af[mf], bfr[nf], acc[mf][nf], 0, 0, 0);
    __syncthreads();
  }
  const float* bias = (n0 < 512) ? bk : bv;
  unsigned short* C = (n0 < 512) ? K : V;
  int nb = (n0 < 512) ? n0 : n0 - 512;
#pragma unroll
  for (int nf = 0; nf < 4; ++nf) {
    int col = nb + wn + nf * 16 + (lane & 15);
    float bv2 = bias[col];
#pragma unroll
    for (int mf = 0; mf < 4; ++mf) {
      int rbase = m0 + wm + mf * 16 + (lane >> 4) * 4;
#pragma unroll
      for (int i = 0; i < 4; ++i)
        C[(size_t)(rbase + i) * CDIM + col] = f2bf(acc[mf][nf][i] + bv2);
    }
  }
}

// ------- split-bf16 f32-precision NT GEMM; BK=64, XOR chunk swizzle (r16-proven) -------
__global__ __launch_bounds__(256) void gemm3_nt(const float* __restrict__ A,
                                                const unsigned short* __restrict__ Whi,
                                                const unsigned short* __restrict__ Wlo,
                                                const float* __restrict__ bias,
                                                float* __restrict__ C) {
  __shared__ unsigned short AsH[128 * 64];
  __shared__ unsigned short AsL[128 * 64];
  __shared__ unsigned short WsH[128 * 64];
  __shared__ unsigned short WsL[128 * 64];
  int tid = threadIdx.x;
  int wave = tid >> 6, lane = tid & 63;
  int2 t = swz_tiles(gridDim.x);
  int n0 = t.x, m0 = t.y;
  int wm = (wave >> 1) * 64, wn = (wave & 1) * 64;
  f32x4 acc[4][4];
#pragma unroll
  for (int i = 0; i < 4; ++i)
#pragma unroll
    for (int j = 0; j < 4; ++j) acc[i][j] = (f32x4){0.f, 0.f, 0.f, 0.f};

  int rsel = lane & 15;
  int kcsel = lane >> 4;

  for (int k0 = 0; k0 < CDIM; k0 += 64) {
#pragma unroll
    for (int c = 0; c < 4; ++c) {
      int s = c * 256 + tid;
      int row = s >> 3, ch = s & 7;
      size_t gw = (size_t)(n0 + row) * CDIM + k0 + (size_t)(ch ^ (row & 7)) * 8;
      gload16(Whi + gw, (void*)(WsH + (size_t)s * 8));
      gload16(Wlo + gw, (void*)(WsL + (size_t)s * 8));
    }
#pragma unroll
    for (int c = 0; c < 4; ++c) {
      int s = c * 256 + tid;
      int row = s >> 3, q = s & 7;
      const float4* src = (const float4*)(A + (size_t)(m0 + row) * CDIM + k0 + (size_t)(q ^ (row & 7)) * 8);
      float4 v0 = src[0], v1 = src[1];
      float vv[8] = {v0.x, v0.y, v0.z, v0.w, v1.x, v1.y, v1.z, v1.w};
      unsigned int hw[4], lw[4];
#pragma unroll
      for (int j = 0; j < 4; ++j) {
        unsigned int u0 = __float_as_uint(vv[2 * j]);
        unsigned int u1 = __float_as_uint(vv[2 * j + 1]);
        hw[j] = (u0 >> 16) | (u1 & 0xffff0000u);        // truncated hi pair
        float l0 = vv[2 * j] - __uint_as_float(u0 & 0xffff0000u);
        float l1 = vv[2 * j + 1] - __uint_as_float(u1 & 0xffff0000u);
        __hip_bfloat162 l2 = __float22bfloat162_rn(make_float2(l0, l1));
        lw[j] = *reinterpret_cast<unsigned int*>(&l2);  // RNE lo pair
      }
      *(uint4*)&AsH[(size_t)s * 8] = make_uint4(hw[0], hw[1], hw[2], hw[3]);
      *(uint4*)&AsL[(size_t)s * 8] = make_uint4(lw[0], lw[1], lw[2], lw[3]);
    }
    __syncthreads();
#pragma unroll
    for (int half = 0; half < 2; ++half) {
      int cb = half * 4 + kcsel;
      bf16x8 ah[4], al[4], bh[4], bl[4];
#pragma unroll
      for (int mf = 0; mf < 4; ++mf) {
        int row = wm + mf * 16 + rsel;
        int off = (row * 8 + (cb ^ (row & 7))) * 8;
        ah[mf] = *(const bf16x8*)&AsH[off];
        al[mf] = *(const bf16x8*)&AsL[off];
      }
#pragma unroll
      for (int nf = 0; nf < 4; ++nf) {
        int row = wn + nf * 16 + rsel;
        int off = (row * 8 + (cb ^ (row & 7))) * 8;
        bh[nf] = *(const bf16x8*)&WsH[off];
        bl[nf] = *(const bf16x8*)&WsL[off];
      }
#pragma unroll
      for (int mf = 0; mf < 4; ++mf)
#pragma unroll
        for (int nf = 0; nf < 4; ++nf) {
          acc[mf][nf] = __builtin_amdgcn_mfma_f32_16x16x32_bf16(ah[mf], bh[nf], acc[mf][nf], 0, 0, 0);
          acc[mf][nf] = __builtin_amdgcn_mfma_f32_16x16x32_bf16(ah[mf], bl[nf], acc[mf][nf], 0, 0, 0);
          acc[mf][nf] = __builtin_amdgcn_mfma_f32_16x16x32_bf16(al[mf], bh[nf], acc[mf][nf], 0, 0, 0);
        }
    }
    __syncthreads();
  }
#pragma unroll
  for (int nf = 0; nf < 4; ++nf) {
    int col = n0 + wn + nf * 16 + (lane & 15);
    float bvs = bias[col];
#pragma unroll
    for (int mf = 0; mf < 4; ++mf) {
      int rbase = m0 + wm + mf * 16 + (lane >> 4) * 4;
#pragma unroll
      for (int i = 0; i < 4; ++i)
        C[(size_t)(rbase + i) * CDIM + col] = acc[mf][nf][i] + bvs;
    }
  }
}

// ------- ONE-SHOT weight prep -------
__global__ __launch_bounds__(256) void conv_all(const float* __restrict__ w_off_proj,
                                                const float* __restrict__ w_k,
                                                const float* __restrict__ w_v,
                                                const float* __restrict__ w_dw,
                                                unsigned short* __restrict__ wphi,
                                                unsigned short* __restrict__ wplo,
                                                unsigned short* __restrict__ wkv,
                                                float* __restrict__ wdwT) {
  int blk = blockIdx.x, tid = threadIdx.x;
  if (blk < 256) {
    int i = blk * 256 + tid;
    float4 v = ((const float4*)w_off_proj)[i];
    ushort4 h, l;
    h.x = f2bf(v.x); l.x = f2bf(v.x - bf2f(h.x));
    h.y = f2bf(v.y); l.y = f2bf(v.y - bf2f(h.y));
    h.z = f2bf(v.z); l.z = f2bf(v.z - bf2f(h.z));
    h.w = f2bf(v.w); l.w = f2bf(v.w - bf2f(h.w));
    ((ushort4*)wphi)[i] = h;
    ((ushort4*)wplo)[i] = l;
  } else if (blk < 512) {
    int i = (blk - 256) * 256 + tid;
    float4 v = ((const float4*)w_k)[i];
    ushort4 o;
    o.x = f2bf(v.x); o.y = f2bf(v.y); o.z = f2bf(v.z); o.w = f2bf(v.w);
    ((ushort4*)wkv)[i] = o;
  } else if (blk < 768) {
    int i = (blk - 512) * 256 + tid;
    float4 v = ((const float4*)w_v)[i];
    ushort4 o;
    o.x = f2bf(v.x); o.y = f2bf(v.y); o.z = f2bf(v.z); o.w = f2bf(v.w);
    ((ushort4*)(wkv + (size_t)CDIM * CDIM))[i] = o;
  } else {
    int id = (blk - 768) * 256 + tid;
    if (id < 9 * CDIM) wdwT[id] = w_dw[(id & 511) * 9 + (id >> 9)];
  }
}

// ------- FUSED: depthwise3x3 + LN + GELU + offset head + bilinear gather -> bf16 xs -------
__global__ __launch_bounds__(512) void offset_gather_kernel(
    const float* __restrict__ t0, const float* __restrict__ x,
    const float* __restrict__ w_dwT, const float* __restrict__ b_dw,
    const float* __restrict__ ln_g, const float* __restrict__ ln_b,
    const float* __restrict__ w_off, unsigned short* __restrict__ xs) {
  __shared__ float4 sten[18 * 128];
  __shared__ float redA[8], redB[8], redC[8], redD[8];
  __shared__ int4 sid[4];
  __shared__ float4 swt[4];

  int blk = blockIdx.x;
  int b = blk >> 10, rem = blk & 1023;
  int h = rem >> 4, w0 = (rem & 15) << 2;
  int t = threadIdx.x;
  const float* base = t0 + (size_t)b * HWSZ * CDIM;

  for (int s = t; s < 18 * 128; s += 512) {
    int ps = s >> 7, q = s & 127;
    int r = ps / 6, cs = ps - r * 6;
    int hh = h + r - 1, ww = w0 + cs - 1;
    if ((unsigned)hh < 64u && (unsigned)ww < 64u) {
      gload16(base + (size_t)(hh * 64 + ww) * CDIM + 4 * q, (void*)(sten + s));
    } else {
      sten[s] = make_float4(0.f, 0.f, 0.f, 0.f);
    }
  }
  __syncthreads();

  int p = t >> 7;
  int l128 = t & 127;
  float4 acc = ((const float4*)b_dw)[l128];
#pragma unroll
  for (int r = 0; r < 3; ++r)
#pragma unroll
    for (int dxi = 0; dxi < 3; ++dxi) {
      float4 w4 = ((const float4*)(w_dwT + (size_t)(r * 3 + dxi) * CDIM))[l128];
      float4 v = sten[(r * 6 + p + dxi) * 128 + l128];
      acc.x = fmaf(v.x, w4.x, acc.x);
      acc.y = fmaf(v.y, w4.y, acc.y);
      acc.z = fmaf(v.z, w4.z, acc.z);
      acc.w = fmaf(v.w, w4.w, acc.w);
    }
  float s = acc.x + acc.y + acc.z + acc.w;
  float s2 = acc.x * acc.x + acc.y * acc.y + acc.z * acc.z + acc.w * acc.w;
#pragma unroll
  for (int off = 32; off; off >>= 1) {
    s += __shfl_xor(s, off, 64);
    s2 += __shfl_xor(s2, off, 64);
  }
  int wv = t >> 6, lane = t & 63;
  if (!lane) { redA[wv] = s; redB[wv] = s2; }
  __syncthreads();
  s = redA[2 * p] + redA[2 * p + 1];
  s2 = redB[2 * p] + redB[2 * p + 1];
  float mean = s * (1.f / 512.f);
  float var = s2 * (1.f / 512.f) - mean * mean;
  float inv = 1.f / sqrtf(var + 1e-5f);

  float4 g4 = ((const float4*)ln_g)[l128];
  float4 lb4 = ((const float4*)ln_b)[l128];
  float4 wy4 = ((const float4*)w_off)[l128];
  float4 wx4 = ((const float4*)(w_off + CDIM))[l128];
  float4 xn;
  xn.x = (acc.x - mean) * inv * g4.x + lb4.x;
  xn.y = (acc.y - mean) * inv * g4.y + lb4.y;
  xn.z = (acc.z - mean) * inv * g4.z + lb4.z;
  xn.w = (acc.w - mean) * inv * g4.w + lb4.w;
  float4 ge;
  ge.x = xn.x * 0.5f * (1.f + erff(xn.x * 0.70710678118654752f));
  ge.y = xn.y * 0.5f * (1.f + erff(xn.y * 0.70710678118654752f));
  ge.z = xn.z * 0.5f * (1.f + erff(xn.z * 0.70710678118654752f));
  ge.w = xn.w * 0.5f * (1.f + erff(xn.w * 0.70710678118654752f));
  float oy = ge.x * wy4.x + ge.y * wy4.y + ge.z * wy4.z + ge.w * wy4.w;
  float ox = ge.x * wx4.x + ge.y * wx4.y + ge.z * wx4.z + ge.w * wx4.w;
#pragma unroll
  for (int off = 32; off; off >>= 1) {
    oy += __shfl_xor(oy, off, 64);
    ox += __shfl_xor(ox, off, 64);
  }
  if (!lane) { redC[wv] = oy; redD[wv] = ox; }
  __syncthreads();
  if (l128 == 0) {
    oy = redC[2 * p] + redC[2 * p + 1];
    ox = redD[2 * p] + redD[2 * p + 1];
    int wcol = w0 + p;
    float ry = ((float)h + 0.5f) / 64.f * 2.f - 1.f;
    float rx = ((float)wcol + 0.5f) / 64.f * 2.f - 1.f;
    float py = tanhf(oy + ry);
    float px = tanhf(ox + rx);
    float fx = (px + 1.f) * 0.5f * 63.f;
    float fy = (py + 1.f) * 0.5f * 63.f;
    float fx0 = floorf(fx), fy0 = floorf(fy);
    float fx1 = fx0 + 1.f, fy1 = fy0 + 1.f;
    float wx1 = fx - fx0, wx0 = fx1 - fx;
    float wy1 = fy - fy0, wy0 = fy1 - fy;
    float m00 = (fy0 >= 0.f && fy0 <= 63.f && fx0 >= 0.f && fx0 <= 63.f) ? 1.f : 0.f;
    float m01 = (fy0 >= 0.f && fy0 <= 63.f && fx1 >= 0.f && fx1 <= 63.f) ? 1.f : 0.f;
    float m10 = (fy1 >= 0.f && fy1 <= 63.f && fx0 >= 0.f && fx0 <= 63.f) ? 1.f : 0.f;
    float m11 = (fy1 >= 0.f && fy1 <= 63.f && fx1 >= 0.f && fx1 <= 63.f) ? 1.f : 0.f;
    int xi0 = min(max((int)fx0, 0), 63), xi1 = min(max((int)fx1, 0), 63);
    int yi0 = min(max((int)fy0, 0), 63), yi1 = min(max((int)fy1, 0), 63);
    sid[p] = make_int4(yi0 * 64 + xi0, yi0 * 64 + xi1, yi1 * 64 + xi0, yi1 * 64 + xi1);
    swt[p] = make_float4(wx0 * wy0 * m00, wx1 * wy0 * m01, wx0 * wy1 * m10, wx1 * wy1 * m11);
  }
  __syncthreads();
  int4 id = sid[p];
  float4 wt = swt[p];
  const float* xb = x + (size_t)b * HWSZ * CDIM;
  float4 a = ((const float4*)(xb + (size_t)id.x * CDIM))[l128];
  float4 bb = ((const float4*)(xb + (size_t)id.y * CDIM))[l128];
  float4 cc = ((const float4*)(xb + (size_t)id.z * CDIM))[l128];
  float4 dd = ((const float4*)(xb + (size_t)id.w * CDIM))[l128];
  ushort4 o;
  o.x = f2bf(a.x * wt.x + bb.x * wt.y + cc.x * wt.z + dd.x * wt.w);
  o.y = f2bf(a.y * wt.x + bb.y * wt.y + cc.y * wt.z + dd.y * wt.w);
  o.z = f2bf(a.z * wt.x + bb.z * wt.y + cc.z * wt.z + dd.z * wt.w);
  o.w = f2bf(a.w * wt.x + bb.w * wt.y + cc.w * wt.z + dd.w * wt.w);
  size_t posg = (size_t)b * HWSZ + h * 64 + w0 + p;
  *(ushort4*)(xs + posg * CDIM + l128 * 4) = o;
}

// ------- split-L attention: every block = 128 keys; emits unnormalized partials -------
__global__ __launch_bounds__(256) void attn_split_kernel(const float* __restrict__ qh,
                                                         const unsigned short* __restrict__ kk,
                                                         const unsigned short* __restrict__ vv,
                                                         float* __restrict__ pm,
                                                         float* __restrict__ ps,
                                                         float* __restrict__ po) {
  __shared__ float sc[128];
  __shared__ float qs[64];
  __shared__ float red[4];
  __shared__ float part[4][64];
  int bid = blockIdx.x;
  int h = bid & 7;
  int bs = bid >> 3;
  int b = bs >> 6, s = bs & 63;
  int l0 = (s & 31) << 7;
  int task = b * 33 + (s < 32 ? 0 : s - 31);
  int tid = threadIdx.x;
  if (tid < 64) qs[tid] = qh[(size_t)task * CDIM + h * 64 + tid];
  __syncthreads();

  const unsigned short* kb = kk + ((size_t)b * HWSZ + l0) * CDIM + h * 64;
  float lmax = -INFINITY;
  if (tid < 128) {
    const uint4* kr = (const uint4*)(kb + (size_t)tid * CDIM);
    float sv = 0.f;
#pragma unroll
    for (int c = 0; c < 8; ++c) {
      uint4 kv = kr[c];
      sv = fmaf(__uint_as_float(kv.x << 16), qs[8 * c + 0], sv);
      sv = fmaf(__uint_as_float(kv.x & 0xffff0000u), qs[8 * c + 1], sv);
      sv = fmaf(__uint_as_float(kv.y << 16), qs[8 * c + 2], sv);
      sv = fmaf(__uint_as_float(kv.y & 0xffff0000u), qs[8 * c + 3], sv);
      sv = fmaf(__uint_as_float(kv.z << 16), qs[8 * c + 4], sv);
      sv = fmaf(__uint_as_float(kv.z & 0xffff0000u), qs[8 * c + 5], sv);
      sv = fmaf(__uint_as_float(kv.w << 16), qs[8 * c + 6], sv);
      sv = fmaf(__uint_as_float(kv.w & 0xffff0000u), qs[8 * c + 7], sv);
    }
    sv *= 0.125f;
    sc[tid] = sv;
    lmax = sv;
  }
#pragma unroll
  for (int off = 32; off; off >>= 1) lmax = fmaxf(lmax, __shfl_xor(lmax, off, 64));
  if (!(tid & 63)) red[tid >> 6] = lmax;
  __syncthreads();
  lmax = fmaxf(fmaxf(red[0], red[1]), fmaxf(red[2], red[3]));
  __syncthreads();

  float lsum = 0.f;
  if (tid < 128) {
    float e = expf(sc[tid] - lmax);
    sc[tid] = e;
    lsum = e;
  }
#pragma unroll
  for (int off = 32; off; off >>= 1) lsum += __shfl_xor(lsum, off, 64);
  if (!(tid & 63)) red[tid >> 6] = lsum;
  __syncthreads();
  float tsum = red[0] + red[1] + red[2] + red[3];

  int ch = tid & 63, g = tid >> 6;
  const unsigned short* vb = vv + ((size_t)b * HWSZ + l0) * CDIM + h * 64 + ch;
  float o = 0.f;
#pragma unroll 4
  for (int l = g; l < 128; l += 4) o = fmaf(sc[l], bf2f(vb[(size_t)l * CDIM]), o);
  part[g][ch] = o;
  __syncthreads();
  if (tid < 64) {
    float r = part[0][tid] + part[1][tid] + part[2][tid] + part[3][tid];
    po[(size_t)bid * 64 + tid] = r;
    if (tid == 0) { pm[bid] = lmax; ps[bid] = tsum; }
  }
}

// ------- merge partials (LSE combine) -------
__global__ __launch_bounds__(64) void attn_reduce_kernel(const float* __restrict__ pm,
                                                         const float* __restrict__ ps,
                                                         const float* __restrict__ po,
                                                         float* __restrict__ oo) {
  int bid = blockIdx.x;
  int h = bid & 7, task = bid >> 3;
  int b = task / 33, qidx = task - b * 33;
  int sbase = (qidx == 0) ? 0 : 31 + qidx;
  int ns = (qidx == 0) ? 32 : 1;
  int t = threadIdx.x;
  float mg = -INFINITY;
  for (int i = 0; i < ns; ++i) mg = fmaxf(mg, pm[((size_t)(b * 64 + sbase + i)) * 8 + h]);
  float tot = 0.f, o = 0.f;
  for (int i = 0; i < ns; ++i) {
    size_t pi = ((size_t)(b * 64 + sbase + i)) * 8 + h;
    float w = expf(pm[pi] - mg);
    tot = fmaf(ps[pi], w, tot);
    o = fmaf(po[pi * 64 + t], w, o);
  }
  oo[(size_t)task * CDIM + h * 64 + t] = o / tot;
}

extern "C" void kernel_launch(void* const* d_in, const int* in_sizes, int n_in,
                              void* d_out, int out_size, void* d_ws, size_t ws_size,
                              hipStream_t stream) {
  const float* q          = (const float*)d_in[0];
  const float* x          = (const float*)d_in[1];
  const float* w_off_proj = (const float*)d_in[2];
  const float* b_off_proj = (const float*)d_in[3];
  const float* w_dw       = (const float*)d_in[4];
  const float* b_dw       = (const float*)d_in[5];
  const float* ln_g       = (const float*)d_in[6];
  const float* ln_b       = (const float*)d_in[7];
  const float* w_off      = (const float*)d_in[8];
  const float* w_q        = (const float*)d_in[9];
  const float* b_q        = (const float*)d_in[10];
  const float* w_k        = (const float*)d_in[11];
  const float* b_k        = (const float*)d_in[12];
  const float* w_v        = (const float*)d_in[13];
  const float* b_v        = (const float*)d_in[14];
  const float* w_o        = (const float*)d_in[15];
  const float* b_o        = (const float*)d_in[16];

  char* ws = (char*)d_ws;
  size_t off = 0;
  const size_t NBIG = (size_t)BATCH * HWSZ * CDIM;
  const int NSPLIT = BATCH * 64 * 8;
  float* t0    = (float*)(ws + off);                  off += NBIG * 4;   // 134 MB
  unsigned short* xs_bf = (unsigned short*)(ws + off); off += NBIG * 2;
  unsigned short* k_bf  = (unsigned short*)(ws + off); off += NBIG * 2;
  unsigned short* v_bf  = (unsigned short*)(ws + off); off += NBIG * 2;
  unsigned short* wphi = (unsigned short*)(ws + off);  off += (size_t)CDIM * CDIM * 2;
  unsigned short* wplo = (unsigned short*)(ws + off);  off += (size_t)CDIM * CDIM * 2;
  unsigned short* wkv_bf = (unsigned short*)(ws + off); off += (size_t)2 * CDIM * CDIM * 2;
  float* w_dwT = (float*)(ws + off);                  off += (size_t)9 * CDIM * 4;
  float* qh    = (float*)(ws + off);                  off += (size_t)BATCH * NQTOT * CDIM * 4;
  float* o_all = (float*)(ws + off);                  off += (size_t)BATCH * NQTOT * CDIM * 4;
  float* pm    = (float*)(ws + off);                  off += (size_t)NSPLIT * 4;
  float* ps    = (float*)(ws + off);                  off += (size_t)NSPLIT * 4;
  float* po    = (float*)(ws + off);                  off += (size_t)NSPLIT * 64 * 4;

  const int Mbig = BATCH * HWSZ;  // 65536
  const int Msm  = BATCH * NQTOT; // 528
  dim3 gSm(CDIM / BN, (Msm + BM - 1) / BM);
  dim3 gMf(CDIM / 128, Mbig / 128);
  dim3 gKV(2 * CDIM / 128, Mbig / 128);

  // 0) all weight conversions in one launch
  conv_all<<<786, 256, 0, stream>>>(w_off_proj, w_k, w_v, w_dw, wphi, wplo, wkv_bf, w_dwT);
  // 1) t0 = x @ w_off_proj^T + b ; BK=64, swizzled, in-kernel split
  gemm3_nt<<<gMf, 256, 0, stream>>>(x, wphi, wplo, b_off_proj, t0);
  // 2) fused depthwise+LN+GELU+offset+gather -> bf16 xs
  offset_gather_kernel<<<Mbig / 4, 512, 0, stream>>>(t0, x, w_dwT, b_dw, ln_g, ln_b, w_off, xs_bf);
  // 3) merged K|V projection; BK=32 (r17: BK=64 regressed pure-gload kernels)
  gemm_kv_nt<<<gKV, 256, 0, stream>>>(xs_bf, wkv_bf, b_k, b_v, k_bf, v_bf);
  // 4) Q projection
  gemm_nt<<<gSm, 256, 0, stream>>>(q, w_q, b_q, qh, Msm);
  // 5) split-L attention + LSE merge
  attn_split_kernel<<<NSPLIT, 256, 0, stream>>>(qh, k_bf, v_bf, pm, ps, po);
  attn_reduce_kernel<<<Msm * 8, 64, 0, stream>>>(pm, ps, po, o_all);
  // 6) output projection -> d_out
  gemm_nt<<<gSm, 256, 0, stream>>>(o_all, w_o, b_o, (float*)d_out, Msm);
}

// Round 19
// 567.756 us; speedup vs baseline: 1.0799x; 1.0529x over previous
//
#include <hip/hip_runtime.h>
#include <hip/hip_bf16.h>

#define CDIM 512
#define HWSZ 4096
#define BATCH 16
#define NQTOT 33

typedef short bf16x8 __attribute__((ext_vector_type(8)));
typedef float f32x4 __attribute__((ext_vector_type(4)));

__device__ __forceinline__ unsigned short f2bf(float f) {
  unsigned int u = __float_as_uint(f);
  u += 0x7fffu + ((u >> 16) & 1u);   // round-to-nearest-even
  return (unsigned short)(u >> 16);
}
__device__ __forceinline__ float bf2f(unsigned short s) {
  return __uint_as_float((unsigned int)s << 16);
}
__device__ __forceinline__ void gload16(const void* g, void* l) {
  __builtin_amdgcn_global_load_lds((const __attribute__((address_space(1))) void*)g,
                                   (__attribute__((address_space(3))) void*)l, 16, 0, 0);
}
// XCD-aware bijective swizzle (nwg % 8 == 0)
__device__ __forceinline__ int2 swz_tiles(int nwgx) {
  int nwg = gridDim.x * gridDim.y;
  int l = blockIdx.y * gridDim.x + blockIdx.x;
  int w = (l & 7) * (nwg >> 3) + (l >> 3);
  return make_int2((w % nwgx) * 128, (w / nwgx) * 128);  // (n0, m0)
}
// Lessons: (r12) never break global coalescing for LDS conflicts; (r17) BK=64
// only pays when a per-phase VALU stream overlaps MFMA; pure-gload kernels
// keep BK=32 small-LDS TLP.

// ---------------- f32 NT GEMM (small M only): C = A*W^T + bias ----------------
#define BM 128
#define BN 128
#define BK 16

__global__ __launch_bounds__(256) void gemm_nt(const float* __restrict__ A,
                                               const float* __restrict__ Wt,
                                               const float* __restrict__ bias,
                                               float* __restrict__ C, int M) {
  const int K = CDIM, N = CDIM;
  __shared__ float As[BK][BM + 4];
  __shared__ float Bs[BK][BN + 4];
  int tid = threadIdx.x;
  int n0 = blockIdx.x * BN;
  int m0 = blockIdx.y * BM;
  int ty = tid >> 4, tx = tid & 15;
  float acc[8][8];
#pragma unroll
  for (int i = 0; i < 8; ++i)
#pragma unroll
    for (int j = 0; j < 8; ++j) acc[i][j] = 0.f;

  for (int k0 = 0; k0 < K; k0 += BK) {
    for (int e = tid; e < (BM * BK / 4); e += 256) {
      int row = e >> 2, kk = (e & 3) << 2;
      float4 va = make_float4(0.f, 0.f, 0.f, 0.f);
      if (m0 + row < M) va = *(const float4*)(A + (size_t)(m0 + row) * K + k0 + kk);
      As[kk + 0][row] = va.x; As[kk + 1][row] = va.y;
      As[kk + 2][row] = va.z; As[kk + 3][row] = va.w;
      float4 vb = *(const float4*)(Wt + (size_t)(n0 + row) * K + k0 + kk);
      Bs[kk + 0][row] = vb.x; Bs[kk + 1][row] = vb.y;
      Bs[kk + 2][row] = vb.z; Bs[kk + 3][row] = vb.w;
    }
    __syncthreads();
#pragma unroll
    for (int k = 0; k < BK; ++k) {
      float a[8], b[8];
      *(float4*)&a[0] = *(float4*)&As[k][ty * 4];
      *(float4*)&a[4] = *(float4*)&As[k][ty * 4 + 64];
      *(float4*)&b[0] = *(float4*)&Bs[k][tx * 4];
      *(float4*)&b[4] = *(float4*)&Bs[k][tx * 4 + 64];
#pragma unroll
      for (int i = 0; i < 8; ++i)
#pragma unroll
        for (int j = 0; j < 8; ++j) acc[i][j] = fmaf(a[i], b[j], acc[i][j]);
    }
    __syncthreads();
  }
#pragma unroll
  for (int i = 0; i < 8; ++i) {
    int m = m0 + ty * 4 + (i < 4 ? i : 60 + i);
    if (m >= M) continue;
#pragma unroll
    for (int jh = 0; jh < 2; ++jh) {
      int n = n0 + tx * 4 + jh * 64;
      float4 v;
      v.x = acc[i][jh * 4 + 0] + bias[n + 0];
      v.y = acc[i][jh * 4 + 1] + bias[n + 1];
      v.z = acc[i][jh * 4 + 2] + bias[n + 2];
      v.w = acc[i][jh * 4 + 3] + bias[n + 3];
      *(float4*)(C + (size_t)m * N + n) = v;
    }
  }
}

// ------- merged K|V bf16 MFMA NT GEMM over Wkv[1024][512]; BK=32 -------
__global__ __launch_bounds__(256) void gemm_kv_nt(const unsigned short* __restrict__ A,
                                                  const unsigned short* __restrict__ Wkv,
                                                  const float* __restrict__ bk,
                                                  const float* __restrict__ bv,
                                                  unsigned short* __restrict__ K,
                                                  unsigned short* __restrict__ V) {
  __shared__ unsigned short As[128 * 32];
  __shared__ unsigned short Ws[128 * 32];
  int tid = threadIdx.x;
  int wave = tid >> 6, lane = tid & 63;
  int2 t = swz_tiles(gridDim.x);
  int n0 = t.x, m0 = t.y;
  int wm = (wave >> 1) * 64, wn = (wave & 1) * 64;
  f32x4 acc[4][4];
#pragma unroll
  for (int i = 0; i < 4; ++i)
#pragma unroll
    for (int j = 0; j < 4; ++j) acc[i][j] = (f32x4){0.f, 0.f, 0.f, 0.f};

  int rsel = lane & 15;
  int ksel = (lane >> 4) * 8;

  for (int k0 = 0; k0 < CDIM; k0 += 32) {
#pragma unroll
    for (int c = 0; c < 2; ++c) {
      int s = c * 256 + tid;
      int row = s >> 2, ch = s & 3;
      gload16(A + (size_t)(m0 + row) * CDIM + k0 + ch * 8, (void*)(As + (size_t)s * 8));
      gload16(Wkv + (size_t)(n0 + row) * CDIM + k0 + ch * 8, (void*)(Ws + (size_t)s * 8));
    }
    __syncthreads();
    bf16x8 af[4], bfr[4];
#pragma unroll
    for (int mf = 0; mf < 4; ++mf)
      af[mf] = *(const bf16x8*)&As[(wm + mf * 16 + rsel) * 32 + ksel];
#pragma unroll
    for (int nf = 0; nf < 4; ++nf)
      bfr[nf] = *(const bf16x8*)&Ws[(wn + nf * 16 + rsel) * 32 + ksel];
#pragma unroll
    for (int mf = 0; mf < 4; ++mf)
#pragma unroll
      for (int nf = 0; nf < 4; ++nf)
        acc[mf][nf] = __builtin_amdgcn_mfma_f32_16x16x32_bf16(af[mf], bfr[nf], acc[mf][nf], 0, 0, 0);
    __syncthreads();
  }
  const float* bias = (n0 < 512) ? bk : bv;
  unsigned short* C = (n0 < 512) ? K : V;
  int nb = (n0 < 512) ? n0 : n0 - 512;
#pragma unroll
  for (int nf = 0; nf < 4; ++nf) {
    int col = nb + wn + nf * 16 + (lane & 15);
    float bv2 = bias[col];
#pragma unroll
    for (int mf = 0; mf < 4; ++mf) {
      int rbase = m0 + wm + mf * 16 + (lane >> 4) * 4;
#pragma unroll
      for (int i = 0; i < 4; ++i)
        C[(size_t)(rbase + i) * CDIM + col] = f2bf(acc[mf][nf][i] + bv2);
    }
  }
}

// ------- split-bf16 f32-precision NT GEMM; BK=64, XOR chunk swizzle -------
__global__ __launch_bounds__(256) void gemm3_nt(const float* __restrict__ A,
                                                const unsigned short* __restrict__ Whi,
                                                const unsigned short* __restrict__ Wlo,
                                                const float* __restrict__ bias,
                                                float* __restrict__ C) {
  __shared__ unsigned short AsH[128 * 64];
  __shared__ unsigned short AsL[128 * 64];
  __shared__ unsigned short WsH[128 * 64];
  __shared__ unsigned short WsL[128 * 64];
  int tid = threadIdx.x;
  int wave = tid >> 6, lane = tid & 63;
  int2 t = swz_tiles(gridDim.x);
  int n0 = t.x, m0 = t.y;
  int wm = (wave >> 1) * 64, wn = (wave & 1) * 64;
  f32x4 acc[4][4];
#pragma unroll
  for (int i = 0; i < 4; ++i)
#pragma unroll
    for (int j = 0; j < 4; ++j) acc[i][j] = (f32x4){0.f, 0.f, 0.f, 0.f};

  int rsel = lane & 15;
  int kcsel = lane >> 4;

  for (int k0 = 0; k0 < CDIM; k0 += 64) {
#pragma unroll
    for (int c = 0; c < 4; ++c) {
      int s = c * 256 + tid;
      int row = s >> 3, ch = s & 7;
      size_t gw = (size_t)(n0 + row) * CDIM + k0 + (size_t)(ch ^ (row & 7)) * 8;
      gload16(Whi + gw, (void*)(WsH + (size_t)s * 8));
      gload16(Wlo + gw, (void*)(WsL + (size_t)s * 8));
    }
#pragma unroll
    for (int c = 0; c < 4; ++c) {
      int s = c * 256 + tid;
      int row = s >> 3, q = s & 7;
      const float4* src = (const float4*)(A + (size_t)(m0 + row) * CDIM + k0 + (size_t)(q ^ (row & 7)) * 8);
      float4 v0 = src[0], v1 = src[1];
      float vv[8] = {v0.x, v0.y, v0.z, v0.w, v1.x, v1.y, v1.z, v1.w};
      unsigned int hw[4], lw[4];
#pragma unroll
      for (int j = 0; j < 4; ++j) {
        unsigned int u0 = __float_as_uint(vv[2 * j]);
        unsigned int u1 = __float_as_uint(vv[2 * j + 1]);
        hw[j] = (u0 >> 16) | (u1 & 0xffff0000u);        // truncated hi pair
        float l0 = vv[2 * j] - __uint_as_float(u0 & 0xffff0000u);
        float l1 = vv[2 * j + 1] - __uint_as_float(u1 & 0xffff0000u);
        __hip_bfloat162 l2 = __float22bfloat162_rn(make_float2(l0, l1));
        lw[j] = *reinterpret_cast<unsigned int*>(&l2);  // RNE lo pair
      }
      *(uint4*)&AsH[(size_t)s * 8] = make_uint4(hw[0], hw[1], hw[2], hw[3]);
      *(uint4*)&AsL[(size_t)s * 8] = make_uint4(lw[0], lw[1], lw[2], lw[3]);
    }
    __syncthreads();
#pragma unroll
    for (int half = 0; half < 2; ++half) {
      int cb = half * 4 + kcsel;
      bf16x8 ah[4], al[4], bh[4], bl[4];
#pragma unroll
      for (int mf = 0; mf < 4; ++mf) {
        int row = wm + mf * 16 + rsel;
        int off = (row * 8 + (cb ^ (row & 7))) * 8;
        ah[mf] = *(const bf16x8*)&AsH[off];
        al[mf] = *(const bf16x8*)&AsL[off];
      }
#pragma unroll
      for (int nf = 0; nf < 4; ++nf) {
        int row = wn + nf * 16 + rsel;
        int off = (row * 8 + (cb ^ (row & 7))) * 8;
        bh[nf] = *(const bf16x8*)&WsH[off];
        bl[nf] = *(const bf16x8*)&WsL[off];
      }
#pragma unroll
      for (int mf = 0; mf < 4; ++mf)
#pragma unroll
        for (int nf = 0; nf < 4; ++nf) {
          acc[mf][nf] = __builtin_amdgcn_mfma_f32_16x16x32_bf16(ah[mf], bh[nf], acc[mf][nf], 0, 0, 0);
          acc[mf][nf] = __builtin_amdgcn_mfma_f32_16x16x32_bf16(ah[mf], bl[nf], acc[mf][nf], 0, 0, 0);
          acc[mf][nf] = __builtin_amdgcn_mfma_f32_16x16x32_bf16(al[mf], bh[nf], acc[mf][nf], 0, 0, 0);
        }
    }
    __syncthreads();
  }
#pragma unroll
  for (int nf = 0; nf < 4; ++nf) {
    int col = n0 + wn + nf * 16 + (lane & 15);
    float bvs = bias[col];
#pragma unroll
    for (int mf = 0; mf < 4; ++mf) {
      int rbase = m0 + wm + mf * 16 + (lane >> 4) * 4;
#pragma unroll
      for (int i = 0; i < 4; ++i)
        C[(size_t)(rbase + i) * CDIM + col] = acc[mf][nf][i] + bvs;
    }
  }
}

// ------- ONE-SHOT weight prep -------
__global__ __launch_bounds__(256) void conv_all(const float* __restrict__ w_off_proj,
                                                const float* __restrict__ w_k,
                                                const float* __restrict__ w_v,
                                                const float* __restrict__ w_dw,
                                                unsigned short* __restrict__ wphi,
                                                unsigned short* __restrict__ wplo,
                                                unsigned short* __restrict__ wkv,
                                                float* __restrict__ wdwT) {
  int blk = blockIdx.x, tid = threadIdx.x;
  if (blk < 256) {
    int i = blk * 256 + tid;
    float4 v = ((const float4*)w_off_proj)[i];
    ushort4 h, l;
    h.x = f2bf(v.x); l.x = f2bf(v.x - bf2f(h.x));
    h.y = f2bf(v.y); l.y = f2bf(v.y - bf2f(h.y));
    h.z = f2bf(v.z); l.z = f2bf(v.z - bf2f(h.z));
    h.w = f2bf(v.w); l.w = f2bf(v.w - bf2f(h.w));
    ((ushort4*)wphi)[i] = h;
    ((ushort4*)wplo)[i] = l;
  } else if (blk < 512) {
    int i = (blk - 256) * 256 + tid;
    float4 v = ((const float4*)w_k)[i];
    ushort4 o;
    o.x = f2bf(v.x); o.y = f2bf(v.y); o.z = f2bf(v.z); o.w = f2bf(v.w);
    ((ushort4*)wkv)[i] = o;
  } else if (blk < 768) {
    int i = (blk - 512) * 256 + tid;
    float4 v = ((const float4*)w_v)[i];
    ushort4 o;
    o.x = f2bf(v.x); o.y = f2bf(v.y); o.z = f2bf(v.z); o.w = f2bf(v.w);
    ((ushort4*)(wkv + (size_t)CDIM * CDIM))[i] = o;
  } else {
    int id = (blk - 768) * 256 + tid;
    if (id < 9 * CDIM) wdwT[id] = w_dw[(id & 511) * 9 + (id >> 9)];
  }
}

// ------- FUSED: depthwise3x3 + LN + GELU + offset head + bilinear gather -> bf16 xs -------
__global__ __launch_bounds__(512) void offset_gather_kernel(
    const float* __restrict__ t0, const float* __restrict__ x,
    const float* __restrict__ w_dwT, const float* __restrict__ b_dw,
    const float* __restrict__ ln_g, const float* __restrict__ ln_b,
    const float* __restrict__ w_off, unsigned short* __restrict__ xs) {
  __shared__ float4 sten[18 * 128];
  __shared__ float redA[8], redB[8], redC[8], redD[8];
  __shared__ int4 sid[4];
  __shared__ float4 swt[4];

  int blk = blockIdx.x;
  int b = blk >> 10, rem = blk & 1023;
  int h = rem >> 4, w0 = (rem & 15) << 2;
  int t = threadIdx.x;
  const float* base = t0 + (size_t)b * HWSZ * CDIM;

  for (int s = t; s < 18 * 128; s += 512) {
    int ps = s >> 7, q = s & 127;
    int r = ps / 6, cs = ps - r * 6;
    int hh = h + r - 1, ww = w0 + cs - 1;
    if ((unsigned)hh < 64u && (unsigned)ww < 64u) {
      gload16(base + (size_t)(hh * 64 + ww) * CDIM + 4 * q, (void*)(sten + s));
    } else {
      sten[s] = make_float4(0.f, 0.f, 0.f, 0.f);
    }
  }
  __syncthreads();

  int p = t >> 7;
  int l128 = t & 127;
  float4 acc = ((const float4*)b_dw)[l128];
#pragma unroll
  for (int r = 0; r < 3; ++r)
#pragma unroll
    for (int dxi = 0; dxi < 3; ++dxi) {
      float4 w4 = ((const float4*)(w_dwT + (size_t)(r * 3 + dxi) * CDIM))[l128];
      float4 v = sten[(r * 6 + p + dxi) * 128 + l128];
      acc.x = fmaf(v.x, w4.x, acc.x);
      acc.y = fmaf(v.y, w4.y, acc.y);
      acc.z = fmaf(v.z, w4.z, acc.z);
      acc.w = fmaf(v.w, w4.w, acc.w);
    }
  float s = acc.x + acc.y + acc.z + acc.w;
  float s2 = acc.x * acc.x + acc.y * acc.y + acc.z * acc.z + acc.w * acc.w;
#pragma unroll
  for (int off = 32; off; off >>= 1) {
    s += __shfl_xor(s, off, 64);
    s2 += __shfl_xor(s2, off, 64);
  }
  int wv = t >> 6, lane = t & 63;
  if (!lane) { redA[wv] = s; redB[wv] = s2; }
  __syncthreads();
  s = redA[2 * p] + redA[2 * p + 1];
  s2 = redB[2 * p] + redB[2 * p + 1];
  float mean = s * (1.f / 512.f);
  float var = s2 * (1.f / 512.f) - mean * mean;
  float inv = 1.f / sqrtf(var + 1e-5f);

  float4 g4 = ((const float4*)ln_g)[l128];
  float4 lb4 = ((const float4*)ln_b)[l128];
  float4 wy4 = ((const float4*)w_off)[l128];
  float4 wx4 = ((const float4*)(w_off + CDIM))[l128];
  float4 xn;
  xn.x = (acc.x - mean) * inv * g4.x + lb4.x;
  xn.y = (acc.y - mean) * inv * g4.y + lb4.y;
  xn.z = (acc.z - mean) * inv * g4.z + lb4.z;
  xn.w = (acc.w - mean) * inv * g4.w + lb4.w;
  float4 ge;
  ge.x = xn.x * 0.5f * (1.f + erff(xn.x * 0.70710678118654752f));
  ge.y = xn.y * 0.5f * (1.f + erff(xn.y * 0.70710678118654752f));
  ge.z = xn.z * 0.5f * (1.f + erff(xn.z * 0.70710678118654752f));
  ge.w = xn.w * 0.5f * (1.f + erff(xn.w * 0.70710678118654752f));
  float oy = ge.x * wy4.x + ge.y * wy4.y + ge.z * wy4.z + ge.w * wy4.w;
  float ox = ge.x * wx4.x + ge.y * wx4.y + ge.z * wx4.z + ge.w * wx4.w;
#pragma unroll
  for (int off = 32; off; off >>= 1) {
    oy += __shfl_xor(oy, off, 64);
    ox += __shfl_xor(ox, off, 64);
  }
  if (!lane) { redC[wv] = oy; redD[wv] = ox; }
  __syncthreads();
  if (l128 == 0) {
    oy = redC[2 * p] + redC[2 * p + 1];
    ox = redD[2 * p] + redD[2 * p + 1];
    int wcol = w0 + p;
    float ry = ((float)h + 0.5f) / 64.f * 2.f - 1.f;
    float rx = ((float)wcol + 0.5f) / 64.f * 2.f - 1.f;
    float py = tanhf(oy + ry);
    float px = tanhf(ox + rx);
    float fx = (px + 1.f) * 0.5f * 63.f;
    float fy = (py + 1.f) * 0.5f * 63.f;
    float fx0 = floorf(fx), fy0 = floorf(fy);
    float fx1 = fx0 + 1.f, fy1 = fy0 + 1.f;
    float wx1 = fx - fx0, wx0 = fx1 - fx;
    float wy1 = fy - fy0, wy0 = fy1 - fy;
    float m00 = (fy0 >= 0.f && fy0 <= 63.f && fx0 >= 0.f && fx0 <= 63.f) ? 1.f : 0.f;
    float m01 = (fy0 >= 0.f && fy0 <= 63.f && fx1 >= 0.f && fx1 <= 63.f) ? 1.f : 0.f;
    float m10 = (fy1 >= 0.f && fy1 <= 63.f && fx0 >= 0.f && fx0 <= 63.f) ? 1.f : 0.f;
    float m11 = (fy1 >= 0.f && fy1 <= 63.f && fx1 >= 0.f && fx1 <= 63.f) ? 1.f : 0.f;
    int xi0 = min(max((int)fx0, 0), 63), xi1 = min(max((int)fx1, 0), 63);
    int yi0 = min(max((int)fy0, 0), 63), yi1 = min(max((int)fy1, 0), 63);
    sid[p] = make_int4(yi0 * 64 + xi0, yi0 * 64 + xi1, yi1 * 64 + xi0, yi1 * 64 + xi1);
    swt[p] = make_float4(wx0 * wy0 * m00, wx1 * wy0 * m01, wx0 * wy1 * m10, wx1 * wy1 * m11);
  }
  __syncthreads();
  int4 id = sid[p];
  float4 wt = swt[p];
  const float* xb = x + (size_t)b * HWSZ * CDIM;
  float4 a = ((const float4*)(xb + (size_t)id.x * CDIM))[l128];
  float4 bb = ((const float4*)(xb + (size_t)id.y * CDIM))[l128];
  float4 cc = ((const float4*)(xb + (size_t)id.z * CDIM))[l128];
  float4 dd = ((const float4*)(xb + (size_t)id.w * CDIM))[l128];
  ushort4 o;
  o.x = f2bf(a.x * wt.x + bb.x * wt.y + cc.x * wt.z + dd.x * wt.w);
  o.y = f2bf(a.y * wt.x + bb.y * wt.y + cc.y * wt.z + dd.y * wt.w);
  o.z = f2bf(a.z * wt.x + bb.z * wt.y + cc.z * wt.z + dd.z * wt.w);
  o.w = f2bf(a.w * wt.x + bb.w * wt.y + cc.w * wt.z + dd.w * wt.w);
  size_t posg = (size_t)b * HWSZ + h * 64 + w0 + p;
  *(ushort4*)(xs + posg * CDIM + l128 * 4) = o;
}

// ------- split-L attention v2: one block serves TWO queries sharing a K/V slab -------
// s in [0,32): global-query chunk s (partial slot s) AND chunk-query qidx=s+1
// (partial slot 32+s); both use keys l0 = s*128. K/V loaded ONCE.
__global__ __launch_bounds__(256) void attn_split_kernel(const float* __restrict__ qh,
                                                         const unsigned short* __restrict__ kk,
                                                         const unsigned short* __restrict__ vv,
                                                         float* __restrict__ pm,
                                                         float* __restrict__ ps,
                                                         float* __restrict__ po) {
  __shared__ float sc0[128], sc1[128];
  __shared__ float qs0[64], qs1[64];
  __shared__ float red0[4], red1[4];
  __shared__ float part0[4][64], part1[4][64];
  int bid = blockIdx.x;
  int h = bid & 7;
  int bs = bid >> 3;
  int b = bs >> 5, s = bs & 31;
  int l0 = s << 7;
  int task0 = b * 33;           // global query
  int task1 = b * 33 + s + 1;   // chunk query
  int tid = threadIdx.x;
  if (tid < 64) qs0[tid] = qh[(size_t)task0 * CDIM + h * 64 + tid];
  else if (tid < 128) qs1[tid - 64] = qh[(size_t)task1 * CDIM + h * 64 + (tid - 64)];
  __syncthreads();

  const unsigned short* kb = kk + ((size_t)b * HWSZ + l0) * CDIM + h * 64;
  float lmax0 = -INFINITY, lmax1 = -INFINITY;
  if (tid < 128) {
    const uint4* kr = (const uint4*)(kb + (size_t)tid * CDIM);
    float sv0 = 0.f, sv1 = 0.f;
#pragma unroll
    for (int c = 0; c < 8; ++c) {
      uint4 kv = kr[c];
      float k0 = __uint_as_float(kv.x << 16);
      float k1 = __uint_as_float(kv.x & 0xffff0000u);
      float k2 = __uint_as_float(kv.y << 16);
      float k3 = __uint_as_float(kv.y & 0xffff0000u);
      float k4 = __uint_as_float(kv.z << 16);
      float k5 = __uint_as_float(kv.z & 0xffff0000u);
      float k6 = __uint_as_float(kv.w << 16);
      float k7 = __uint_as_float(kv.w & 0xffff0000u);
      sv0 = fmaf(k0, qs0[8 * c + 0], sv0); sv1 = fmaf(k0, qs1[8 * c + 0], sv1);
      sv0 = fmaf(k1, qs0[8 * c + 1], sv0); sv1 = fmaf(k1, qs1[8 * c + 1], sv1);
      sv0 = fmaf(k2, qs0[8 * c + 2], sv0); sv1 = fmaf(k2, qs1[8 * c + 2], sv1);
      sv0 = fmaf(k3, qs0[8 * c + 3], sv0); sv1 = fmaf(k3, qs1[8 * c + 3], sv1);
      sv0 = fmaf(k4, qs0[8 * c + 4], sv0); sv1 = fmaf(k4, qs1[8 * c + 4], sv1);
      sv0 = fmaf(k5, qs0[8 * c + 5], sv0); sv1 = fmaf(k5, qs1[8 * c + 5], sv1);
      sv0 = fmaf(k6, qs0[8 * c + 6], sv0); sv1 = fmaf(k6, qs1[8 * c + 6], sv1);
      sv0 = fmaf(k7, qs0[8 * c + 7], sv0); sv1 = fmaf(k7, qs1[8 * c + 7], sv1);
    }
    sv0 *= 0.125f; sv1 *= 0.125f;
    sc0[tid] = sv0; sc1[tid] = sv1;
    lmax0 = sv0; lmax1 = sv1;
  }
#pragma unroll
  for (int off = 32; off; off >>= 1) {
    lmax0 = fmaxf(lmax0, __shfl_xor(lmax0, off, 64));
    lmax1 = fmaxf(lmax1, __shfl_xor(lmax1, off, 64));
  }
  if (!(tid & 63)) { red0[tid >> 6] = lmax0; red1[tid >> 6] = lmax1; }
  __syncthreads();
  lmax0 = fmaxf(fmaxf(red0[0], red0[1]), fmaxf(red0[2], red0[3]));
  lmax1 = fmaxf(fmaxf(red1[0], red1[1]), fmaxf(red1[2], red1[3]));
  __syncthreads();

  float ls0 = 0.f, ls1 = 0.f;
  if (tid < 128) {
    float e0 = expf(sc0[tid] - lmax0);
    float e1 = expf(sc1[tid] - lmax1);
    sc0[tid] = e0; sc1[tid] = e1;
    ls0 = e0; ls1 = e1;
  }
#pragma unroll
  for (int off = 32; off; off >>= 1) {
    ls0 += __shfl_xor(ls0, off, 64);
    ls1 += __shfl_xor(ls1, off, 64);
  }
  if (!(tid & 63)) { red0[tid >> 6] = ls0; red1[tid >> 6] = ls1; }
  __syncthreads();
  float tsum0 = red0[0] + red0[1] + red0[2] + red0[3];
  float tsum1 = red1[0] + red1[1] + red1[2] + red1[3];

  int ch = tid & 63, g = tid >> 6;
  const unsigned short* vb = vv + ((size_t)b * HWSZ + l0) * CDIM + h * 64 + ch;
  float o0 = 0.f, o1 = 0.f;
#pragma unroll 4
  for (int l = g; l < 128; l += 4) {
    float vvv = bf2f(vb[(size_t)l * CDIM]);
    o0 = fmaf(sc0[l], vvv, o0);
    o1 = fmaf(sc1[l], vvv, o1);
  }
  part0[g][ch] = o0;
  part1[g][ch] = o1;
  __syncthreads();
  if (tid < 64) {
    float r0 = part0[0][tid] + part0[1][tid] + part0[2][tid] + part0[3][tid];
    float r1 = part1[0][tid] + part1[1][tid] + part1[2][tid] + part1[3][tid];
    int bid0 = (b * 64 + s) * 8 + h;
    int bid1 = (b * 64 + 32 + s) * 8 + h;
    po[(size_t)bid0 * 64 + tid] = r0;
    po[(size_t)bid1 * 64 + tid] = r1;
    if (tid == 0) {
      pm[bid0] = lmax0; ps[bid0] = tsum0;
      pm[bid1] = lmax1; ps[bid1] = tsum1;
    }
  }
}

// ------- merge partials (LSE combine) -------
__global__ __launch_bounds__(64) void attn_reduce_kernel(const float* __restrict__ pm,
                                                         const float* __restrict__ ps,
                                                         const float* __restrict__ po,
                                                         float* __restrict__ oo) {
  int bid = blockIdx.x;
  int h = bid & 7, task = bid >> 3;
  int b = task / 33, qidx = task - b * 33;
  int sbase = (qidx == 0) ? 0 : 31 + qidx;
  int ns = (qidx == 0) ? 32 : 1;
  int t = threadIdx.x;
  float mg = -INFINITY;
  for (int i = 0; i < ns; ++i) mg = fmaxf(mg, pm[((size_t)(b * 64 + sbase + i)) * 8 + h]);
  float tot = 0.f, o = 0.f;
  for (int i = 0; i < ns; ++i) {
    size_t pi = ((size_t)(b * 64 + sbase + i)) * 8 + h;
    float w = expf(pm[pi] - mg);
    tot = fmaf(ps[pi], w, tot);
    o = fmaf(po[pi * 64 + t], w, o);
  }
  oo[(size_t)task * CDIM + h * 64 + t] = o / tot;
}

extern "C" void kernel_launch(void* const* d_in, const int* in_sizes, int n_in,
                              void* d_out, int out_size, void* d_ws, size_t ws_size,
                              hipStream_t stream) {
  const float* q          = (const float*)d_in[0];
  const float* x          = (const float*)d_in[1];
  const float* w_off_proj = (const float*)d_in[2];
  const float* b_off_proj = (const float*)d_in[3];
  const float* w_dw       = (const float*)d_in[4];
  const float* b_dw       = (const float*)d_in[5];
  const float* ln_g       = (const float*)d_in[6];
  const float* ln_b       = (const float*)d_in[7];
  const float* w_off      = (const float*)d_in[8];
  const float* w_q        = (const float*)d_in[9];
  const float* b_q        = (const float*)d_in[10];
  const float* w_k        = (const float*)d_in[11];
  const float* b_k        = (const float*)d_in[12];
  const float* w_v        = (const float*)d_in[13];
  const float* b_v        = (const float*)d_in[14];
  const float* w_o        = (const float*)d_in[15];
  const float* b_o        = (const float*)d_in[16];

  char* ws = (char*)d_ws;
  size_t off = 0;
  const size_t NBIG = (size_t)BATCH * HWSZ * CDIM;
  const int NSPLIT = BATCH * 64 * 8;
  float* t0    = (float*)(ws + off);                  off += NBIG * 4;   // 134 MB
  unsigned short* xs_bf = (unsigned short*)(ws + off); off += NBIG * 2;
  unsigned short* k_bf  = (unsigned short*)(ws + off); off += NBIG * 2;
  unsigned short* v_bf  = (unsigned short*)(ws + off); off += NBIG * 2;
  unsigned short* wphi = (unsigned short*)(ws + off);  off += (size_t)CDIM * CDIM * 2;
  unsigned short* wplo = (unsigned short*)(ws + off);  off += (size_t)CDIM * CDIM * 2;
  unsigned short* wkv_bf = (unsigned short*)(ws + off); off += (size_t)2 * CDIM * CDIM * 2;
  float* w_dwT = (float*)(ws + off);                  off += (size_t)9 * CDIM * 4;
  float* qh    = (float*)(ws + off);                  off += (size_t)BATCH * NQTOT * CDIM * 4;
  float* o_all = (float*)(ws + off);                  off += (size_t)BATCH * NQTOT * CDIM * 4;
  float* pm    = (float*)(ws + off);                  off += (size_t)NSPLIT * 4;
  float* ps    = (float*)(ws + off);                  off += (size_t)NSPLIT * 4;
  float* po    = (float*)(ws + off);                  off += (size_t)NSPLIT * 64 * 4;

  const int Mbig = BATCH * HWSZ;  // 65536
  const int Msm  = BATCH * NQTOT; // 528
  dim3 gSm(CDIM / BN, (Msm + BM - 1) / BM);
  dim3 gMf(CDIM / 128, Mbig / 128);
  dim3 gKV(2 * CDIM / 128, Mbig / 128);

  // 0) all weight conversions in one launch
  conv_all<<<786, 256, 0, stream>>>(w_off_proj, w_k, w_v, w_dw, wphi, wplo, wkv_bf, w_dwT);
  // 1) t0 = x @ w_off_proj^T + b ; BK=64, swizzled, in-kernel split
  gemm3_nt<<<gMf, 256, 0, stream>>>(x, wphi, wplo, b_off_proj, t0);
  // 2) fused depthwise+LN+GELU+offset+gather -> bf16 xs
  offset_gather_kernel<<<Mbig / 4, 512, 0, stream>>>(t0, x, w_dwT, b_dw, ln_g, ln_b, w_off, xs_bf);
  // 3) merged K|V projection; BK=32
  gemm_kv_nt<<<gKV, 256, 0, stream>>>(xs_bf, wkv_bf, b_k, b_v, k_bf, v_bf);
  // 4) Q projection
  gemm_nt<<<gSm, 256, 0, stream>>>(q, w_q, b_q, qh, Msm);
  // 5) dual-query split-L attention (K/V slab loaded once per pair) + LSE merge
  attn_split_kernel<<<NSPLIT / 2, 256, 0, stream>>>(qh, k_bf, v_bf, pm, ps, po);
  attn_reduce_kernel<<<Msm * 8, 64, 0, stream>>>(pm, ps, po, o_all);
  // 6) output projection -> d_out
  gemm_nt<<<gSm, 256, 0, stream>>>(o_all, w_o, b_o, (float*)d_out, Msm);
}

// Round 20
// 474.245 us; speedup vs baseline: 1.2928x; 1.1972x over previous
//
#include <hip/hip_runtime.h>
#include <hip/hip_bf16.h>

#define CDIM 512
#define HWSZ 4096
#define BATCH 16
#define NQTOT 33

typedef short bf16x8 __attribute__((ext_vector_type(8)));
typedef float f32x4 __attribute__((ext_vector_type(4)));

__device__ __forceinline__ unsigned short f2bf(float f) {
  unsigned int u = __float_as_uint(f);
  u += 0x7fffu + ((u >> 16) & 1u);   // round-to-nearest-even
  return (unsigned short)(u >> 16);
}
__device__ __forceinline__ float bf2f(unsigned short s) {
  return __uint_as_float((unsigned int)s << 16);
}
__device__ __forceinline__ void gload16(const void* g, void* l) {
  __builtin_amdgcn_global_load_lds((const __attribute__((address_space(1))) void*)g,
                                   (__attribute__((address_space(3))) void*)l, 16, 0, 0);
}
// XCD-aware bijective swizzle (nwg % 8 == 0)
__device__ __forceinline__ int2 swz_tiles(int nwgx) {
  int nwg = gridDim.x * gridDim.y;
  int l = blockIdx.y * gridDim.x + blockIdx.x;
  int w = (l & 7) * (nwg >> 3) + (l >> 3);
  return make_int2((w % nwgx) * 128, (w / nwgx) * 128);  // (n0, m0)
}
// Lessons: (r12) never break global coalescing for LDS conflicts; (r17) BK=64
// only pays when a per-phase VALU stream overlaps MFMA; (r19) small-M GEMMs
// need small tiles for occupancy (20 blocks on 256 CUs was the hidden cost).

// ------- small-M f32 NT GEMM: 64x64 tiles for occupancy; C = A*W^T + bias -------
#define SBM 64
#define SBN 64
#define SBK 16

__global__ __launch_bounds__(256) void gemm_sm_nt(const float* __restrict__ A,
                                                  const float* __restrict__ Wt,
                                                  const float* __restrict__ bias,
                                                  float* __restrict__ C, int M) {
  const int K = CDIM, N = CDIM;
  __shared__ float As[SBK][SBM + 4];
  __shared__ float Bs[SBK][SBN + 4];
  int tid = threadIdx.x;
  int n0 = blockIdx.x * SBN;
  int m0 = blockIdx.y * SBM;
  int ty = tid >> 4, tx = tid & 15;
  float acc[4][4];
#pragma unroll
  for (int i = 0; i < 4; ++i)
#pragma unroll
    for (int j = 0; j < 4; ++j) acc[i][j] = 0.f;

  int lrow = tid >> 2, lkk = (tid & 3) << 2;   // 64 rows x 4 chunks = 256 threads
  for (int k0 = 0; k0 < K; k0 += SBK) {
    float4 va = make_float4(0.f, 0.f, 0.f, 0.f);
    if (m0 + lrow < M) va = *(const float4*)(A + (size_t)(m0 + lrow) * K + k0 + lkk);
    As[lkk + 0][lrow] = va.x; As[lkk + 1][lrow] = va.y;
    As[lkk + 2][lrow] = va.z; As[lkk + 3][lrow] = va.w;
    float4 vb = *(const float4*)(Wt + (size_t)(n0 + lrow) * K + k0 + lkk);
    Bs[lkk + 0][lrow] = vb.x; Bs[lkk + 1][lrow] = vb.y;
    Bs[lkk + 2][lrow] = vb.z; Bs[lkk + 3][lrow] = vb.w;
    __syncthreads();
#pragma unroll
    for (int k = 0; k < SBK; ++k) {
      float a[4], b[4];
      *(float4*)&a[0] = *(float4*)&As[k][ty * 4];
      *(float4*)&b[0] = *(float4*)&Bs[k][tx * 4];
#pragma unroll
      for (int i = 0; i < 4; ++i)
#pragma unroll
        for (int j = 0; j < 4; ++j) acc[i][j] = fmaf(a[i], b[j], acc[i][j]);
    }
    __syncthreads();
  }
#pragma unroll
  for (int i = 0; i < 4; ++i) {
    int m = m0 + ty * 4 + i;
    if (m >= M) continue;
    int n = n0 + tx * 4;
    float4 v;
    v.x = acc[i][0] + bias[n + 0];
    v.y = acc[i][1] + bias[n + 1];
    v.z = acc[i][2] + bias[n + 2];
    v.w = acc[i][3] + bias[n + 3];
    *(float4*)(C + (size_t)m * N + n) = v;
  }
}

// ------- merged K|V bf16 MFMA NT GEMM over Wkv[1024][512]; BK=32 -------
__global__ __launch_bounds__(256) void gemm_kv_nt(const unsigned short* __restrict__ A,
                                                  const unsigned short* __restrict__ Wkv,
                                                  const float* __restrict__ bk,
                                                  const float* __restrict__ bv,
                                                  unsigned short* __restrict__ K,
                                                  unsigned short* __restrict__ V) {
  __shared__ unsigned short As[128 * 32];
  __shared__ unsigned short Ws[128 * 32];
  int tid = threadIdx.x;
  int wave = tid >> 6, lane = tid & 63;
  int2 t = swz_tiles(gridDim.x);
  int n0 = t.x, m0 = t.y;
  int wm = (wave >> 1) * 64, wn = (wave & 1) * 64;
  f32x4 acc[4][4];
#pragma unroll
  for (int i = 0; i < 4; ++i)
#pragma unroll
    for (int j = 0; j < 4; ++j) acc[i][j] = (f32x4){0.f, 0.f, 0.f, 0.f};

  int rsel = lane & 15;
  int ksel = (lane >> 4) * 8;

  for (int k0 = 0; k0 < CDIM; k0 += 32) {
#pragma unroll
    for (int c = 0; c < 2; ++c) {
      int s = c * 256 + tid;
      int row = s >> 2, ch = s & 3;
      gload16(A + (size_t)(m0 + row) * CDIM + k0 + ch * 8, (void*)(As + (size_t)s * 8));
      gload16(Wkv + (size_t)(n0 + row) * CDIM + k0 + ch * 8, (void*)(Ws + (size_t)s * 8));
    }
    __syncthreads();
    bf16x8 af[4], bfr[4];
#pragma unroll
    for (int mf = 0; mf < 4; ++mf)
      af[mf] = *(const bf16x8*)&As[(wm + mf * 16 + rsel) * 32 + ksel];
#pragma unroll
    for (int nf = 0; nf < 4; ++nf)
      bfr[nf] = *(const bf16x8*)&Ws[(wn + nf * 16 + rsel) * 32 + ksel];
#pragma unroll
    for (int mf = 0; mf < 4; ++mf)
#pragma unroll
      for (int nf = 0; nf < 4; ++nf)
        acc[mf][nf] = __builtin_amdgcn_mfma_f32_16x16x32_bf16(af[mf], bfr[nf], acc[mf][nf], 0, 0, 0);
    __syncthreads();
  }
  const float* bias = (n0 < 512) ? bk : bv;
  unsigned short* C = (n0 < 512) ? K : V;
  int nb = (n0 < 512) ? n0 : n0 - 512;
#pragma unroll
  for (int nf = 0; nf < 4; ++nf) {
    int col = nb + wn + nf * 16 + (lane & 15);
    float bv2 = bias[col];
#pragma unroll
    for (int mf = 0; mf < 4; ++mf) {
      int rbase = m0 + wm + mf * 16 + (lane >> 4) * 4;
#pragma unroll
      for (int i = 0; i < 4; ++i)
        C[(size_t)(rbase + i) * CDIM + col] = f2bf(acc[mf][nf][i] + bv2);
    }
  }
}

// ------- split-bf16 f32-precision NT GEMM; BK=64, XOR chunk swizzle -------
__global__ __launch_bounds__(256) void gemm3_nt(const float* __restrict__ A,
                                                const unsigned short* __restrict__ Whi,
                                                const unsigned short* __restrict__ Wlo,
                                                const float* __restrict__ bias,
                                                float* __restrict__ C) {
  __shared__ unsigned short AsH[128 * 64];
  __shared__ unsigned short AsL[128 * 64];
  __shared__ unsigned short WsH[128 * 64];
  __shared__ unsigned short WsL[128 * 64];
  int tid = threadIdx.x;
  int wave = tid >> 6, lane = tid & 63;
  int2 t = swz_tiles(gridDim.x);
  int n0 = t.x, m0 = t.y;
  int wm = (wave >> 1) * 64, wn = (wave & 1) * 64;
  f32x4 acc[4][4];
#pragma unroll
  for (int i = 0; i < 4; ++i)
#pragma unroll
    for (int j = 0; j < 4; ++j) acc[i][j] = (f32x4){0.f, 0.f, 0.f, 0.f};

  int rsel = lane & 15;
  int kcsel = lane >> 4;

  for (int k0 = 0; k0 < CDIM; k0 += 64) {
#pragma unroll
    for (int c = 0; c < 4; ++c) {
      int s = c * 256 + tid;
      int row = s >> 3, ch = s & 7;
      size_t gw = (size_t)(n0 + row) * CDIM + k0 + (size_t)(ch ^ (row & 7)) * 8;
      gload16(Whi + gw, (void*)(WsH + (size_t)s * 8));
      gload16(Wlo + gw, (void*)(WsL + (size_t)s * 8));
    }
#pragma unroll
    for (int c = 0; c < 4; ++c) {
      int s = c * 256 + tid;
      int row = s >> 3, q = s & 7;
      const float4* src = (const float4*)(A + (size_t)(m0 + row) * CDIM + k0 + (size_t)(q ^ (row & 7)) * 8);
      float4 v0 = src[0], v1 = src[1];
      float vv[8] = {v0.x, v0.y, v0.z, v0.w, v1.x, v1.y, v1.z, v1.w};
      unsigned int hw[4], lw[4];
#pragma unroll
      for (int j = 0; j < 4; ++j) {
        unsigned int u0 = __float_as_uint(vv[2 * j]);
        unsigned int u1 = __float_as_uint(vv[2 * j + 1]);
        hw[j] = (u0 >> 16) | (u1 & 0xffff0000u);        // truncated hi pair
        float l0 = vv[2 * j] - __uint_as_float(u0 & 0xffff0000u);
        float l1 = vv[2 * j + 1] - __uint_as_float(u1 & 0xffff0000u);
        __hip_bfloat162 l2 = __float22bfloat162_rn(make_float2(l0, l1));
        lw[j] = *reinterpret_cast<unsigned int*>(&l2);  // RNE lo pair
      }
      *(uint4*)&AsH[(size_t)s * 8] = make_uint4(hw[0], hw[1], hw[2], hw[3]);
      *(uint4*)&AsL[(size_t)s * 8] = make_uint4(lw[0], lw[1], lw[2], lw[3]);
    }
    __syncthreads();
#pragma unroll
    for (int half = 0; half < 2; ++half) {
      int cb = half * 4 + kcsel;
      bf16x8 ah[4], al[4], bh[4], bl[4];
#pragma unroll
      for (int mf = 0; mf < 4; ++mf) {
        int row = wm + mf * 16 + rsel;
        int off = (row * 8 + (cb ^ (row & 7))) * 8;
        ah[mf] = *(const bf16x8*)&AsH[off];
        al[mf] = *(const bf16x8*)&AsL[off];
      }
#pragma unroll
      for (int nf = 0; nf < 4; ++nf) {
        int row = wn + nf * 16 + rsel;
        int off = (row * 8 + (cb ^ (row & 7))) * 8;
        bh[nf] = *(const bf16x8*)&WsH[off];
        bl[nf] = *(const bf16x8*)&WsL[off];
      }
#pragma unroll
      for (int mf = 0; mf < 4; ++mf)
#pragma unroll
        for (int nf = 0; nf < 4; ++nf) {
          acc[mf][nf] = __builtin_amdgcn_mfma_f32_16x16x32_bf16(ah[mf], bh[nf], acc[mf][nf], 0, 0, 0);
          acc[mf][nf] = __builtin_amdgcn_mfma_f32_16x16x32_bf16(ah[mf], bl[nf], acc[mf][nf], 0, 0, 0);
          acc[mf][nf] = __builtin_amdgcn_mfma_f32_16x16x32_bf16(al[mf], bh[nf], acc[mf][nf], 0, 0, 0);
        }
    }
    __syncthreads();
  }
#pragma unroll
  for (int nf = 0; nf < 4; ++nf) {
    int col = n0 + wn + nf * 16 + (lane & 15);
    float bvs = bias[col];
#pragma unroll
    for (int mf = 0; mf < 4; ++mf) {
      int rbase = m0 + wm + mf * 16 + (lane >> 4) * 4;
#pragma unroll
      for (int i = 0; i < 4; ++i)
        C[(size_t)(rbase + i) * CDIM + col] = acc[mf][nf][i] + bvs;
    }
  }
}

// ------- ONE-SHOT weight prep -------
__global__ __launch_bounds__(256) void conv_all(const float* __restrict__ w_off_proj,
                                                const float* __restrict__ w_k,
                                                const float* __restrict__ w_v,
                                                const float* __restrict__ w_dw,
                                                unsigned short* __restrict__ wphi,
                                                unsigned short* __restrict__ wplo,
                                                unsigned short* __restrict__ wkv,
                                                float* __restrict__ wdwT) {
  int blk = blockIdx.x, tid = threadIdx.x;
  if (blk < 256) {
    int i = blk * 256 + tid;
    float4 v = ((const float4*)w_off_proj)[i];
    ushort4 h, l;
    h.x = f2bf(v.x); l.x = f2bf(v.x - bf2f(h.x));
    h.y = f2bf(v.y); l.y = f2bf(v.y - bf2f(h.y));
    h.z = f2bf(v.z); l.z = f2bf(v.z - bf2f(h.z));
    h.w = f2bf(v.w); l.w = f2bf(v.w - bf2f(h.w));
    ((ushort4*)wphi)[i] = h;
    ((ushort4*)wplo)[i] = l;
  } else if (blk < 512) {
    int i = (blk - 256) * 256 + tid;
    float4 v = ((const float4*)w_k)[i];
    ushort4 o;
    o.x = f2bf(v.x); o.y = f2bf(v.y); o.z = f2bf(v.z); o.w = f2bf(v.w);
    ((ushort4*)wkv)[i] = o;
  } else if (blk < 768) {
    int i = (blk - 512) * 256 + tid;
    float4 v = ((const float4*)w_v)[i];
    ushort4 o;
    o.x = f2bf(v.x); o.y = f2bf(v.y); o.z = f2bf(v.z); o.w = f2bf(v.w);
    ((ushort4*)(wkv + (size_t)CDIM * CDIM))[i] = o;
  } else {
    int id = (blk - 768) * 256 + tid;
    if (id < 9 * CDIM) wdwT[id] = w_dw[(id & 511) * 9 + (id >> 9)];
  }
}

// ------- FUSED: depthwise3x3 + LN + GELU + offset head + bilinear gather -> bf16 xs -------
__global__ __launch_bounds__(512) void offset_gather_kernel(
    const float* __restrict__ t0, const float* __restrict__ x,
    const float* __restrict__ w_dwT, const float* __restrict__ b_dw,
    const float* __restrict__ ln_g, const float* __restrict__ ln_b,
    const float* __restrict__ w_off, unsigned short* __restrict__ xs) {
  __shared__ float4 sten[18 * 128];
  __shared__ float redA[8], redB[8], redC[8], redD[8];
  __shared__ int4 sid[4];
  __shared__ float4 swt[4];

  int blk = blockIdx.x;
  int b = blk >> 10, rem = blk & 1023;
  int h = rem >> 4, w0 = (rem & 15) << 2;
  int t = threadIdx.x;
  const float* base = t0 + (size_t)b * HWSZ * CDIM;

  for (int s = t; s < 18 * 128; s += 512) {
    int ps = s >> 7, q = s & 127;
    int r = ps / 6, cs = ps - r * 6;
    int hh = h + r - 1, ww = w0 + cs - 1;
    if ((unsigned)hh < 64u && (unsigned)ww < 64u) {
      gload16(base + (size_t)(hh * 64 + ww) * CDIM + 4 * q, (void*)(sten + s));
    } else {
      sten[s] = make_float4(0.f, 0.f, 0.f, 0.f);
    }
  }
  __syncthreads();

  int p = t >> 7;
  int l128 = t & 127;
  float4 acc = ((const float4*)b_dw)[l128];
#pragma unroll
  for (int r = 0; r < 3; ++r)
#pragma unroll
    for (int dxi = 0; dxi < 3; ++dxi) {
      float4 w4 = ((const float4*)(w_dwT + (size_t)(r * 3 + dxi) * CDIM))[l128];
      float4 v = sten[(r * 6 + p + dxi) * 128 + l128];
      acc.x = fmaf(v.x, w4.x, acc.x);
      acc.y = fmaf(v.y, w4.y, acc.y);
      acc.z = fmaf(v.z, w4.z, acc.z);
      acc.w = fmaf(v.w, w4.w, acc.w);
    }
  float s = acc.x + acc.y + acc.z + acc.w;
  float s2 = acc.x * acc.x + acc.y * acc.y + acc.z * acc.z + acc.w * acc.w;
#pragma unroll
  for (int off = 32; off; off >>= 1) {
    s += __shfl_xor(s, off, 64);
    s2 += __shfl_xor(s2, off, 64);
  }
  int wv = t >> 6, lane = t & 63;
  if (!lane) { redA[wv] = s; redB[wv] = s2; }
  __syncthreads();
  s = redA[2 * p] + redA[2 * p + 1];
  s2 = redB[2 * p] + redB[2 * p + 1];
  float mean = s * (1.f / 512.f);
  float var = s2 * (1.f / 512.f) - mean * mean;
  float inv = 1.f / sqrtf(var + 1e-5f);

  float4 g4 = ((const float4*)ln_g)[l128];
  float4 lb4 = ((const float4*)ln_b)[l128];
  float4 wy4 = ((const float4*)w_off)[l128];
  float4 wx4 = ((const float4*)(w_off + CDIM))[l128];
  float4 xn;
  xn.x = (acc.x - mean) * inv * g4.x + lb4.x;
  xn.y = (acc.y - mean) * inv * g4.y + lb4.y;
  xn.z = (acc.z - mean) * inv * g4.z + lb4.z;
  xn.w = (acc.w - mean) * inv * g4.w + lb4.w;
  float4 ge;
  ge.x = xn.x * 0.5f * (1.f + erff(xn.x * 0.70710678118654752f));
  ge.y = xn.y * 0.5f * (1.f + erff(xn.y * 0.70710678118654752f));
  ge.z = xn.z * 0.5f * (1.f + erff(xn.z * 0.70710678118654752f));
  ge.w = xn.w * 0.5f * (1.f + erff(xn.w * 0.70710678118654752f));
  float oy = ge.x * wy4.x + ge.y * wy4.y + ge.z * wy4.z + ge.w * wy4.w;
  float ox = ge.x * wx4.x + ge.y * wx4.y + ge.z * wx4.z + ge.w * wx4.w;
#pragma unroll
  for (int off = 32; off; off >>= 1) {
    oy += __shfl_xor(oy, off, 64);
    ox += __shfl_xor(ox, off, 64);
  }
  if (!lane) { redC[wv] = oy; redD[wv] = ox; }
  __syncthreads();
  if (l128 == 0) {
    oy = redC[2 * p] + redC[2 * p + 1];
    ox = redD[2 * p] + redD[2 * p + 1];
    int wcol = w0 + p;
    float ry = ((float)h + 0.5f) / 64.f * 2.f - 1.f;
    float rx = ((float)wcol + 0.5f) / 64.f * 2.f - 1.f;
    float py = tanhf(oy + ry);
    float px = tanhf(ox + rx);
    float fx = (px + 1.f) * 0.5f * 63.f;
    float fy = (py + 1.f) * 0.5f * 63.f;
    float fx0 = floorf(fx), fy0 = floorf(fy);
    float fx1 = fx0 + 1.f, fy1 = fy0 + 1.f;
    float wx1 = fx - fx0, wx0 = fx1 - fx;
    float wy1 = fy - fy0, wy0 = fy1 - fy;
    float m00 = (fy0 >= 0.f && fy0 <= 63.f && fx0 >= 0.f && fx0 <= 63.f) ? 1.f : 0.f;
    float m01 = (fy0 >= 0.f && fy0 <= 63.f && fx1 >= 0.f && fx1 <= 63.f) ? 1.f : 0.f;
    float m10 = (fy1 >= 0.f && fy1 <= 63.f && fx0 >= 0.f && fx0 <= 63.f) ? 1.f : 0.f;
    float m11 = (fy1 >= 0.f && fy1 <= 63.f && fx1 >= 0.f && fx1 <= 63.f) ? 1.f : 0.f;
    int xi0 = min(max((int)fx0, 0), 63), xi1 = min(max((int)fx1, 0), 63);
    int yi0 = min(max((int)fy0, 0), 63), yi1 = min(max((int)fy1, 0), 63);
    sid[p] = make_int4(yi0 * 64 + xi0, yi0 * 64 + xi1, yi1 * 64 + xi0, yi1 * 64 + xi1);
    swt[p] = make_float4(wx0 * wy0 * m00, wx1 * wy0 * m01, wx0 * wy1 * m10, wx1 * wy1 * m11);
  }
  __syncthreads();
  int4 id = sid[p];
  float4 wt = swt[p];
  const float* xb = x + (size_t)b * HWSZ * CDIM;
  float4 a = ((const float4*)(xb + (size_t)id.x * CDIM))[l128];
  float4 bb = ((const float4*)(xb + (size_t)id.y * CDIM))[l128];
  float4 cc = ((const float4*)(xb + (size_t)id.z * CDIM))[l128];
  float4 dd = ((const float4*)(xb + (size_t)id.w * CDIM))[l128];
  ushort4 o;
  o.x = f2bf(a.x * wt.x + bb.x * wt.y + cc.x * wt.z + dd.x * wt.w);
  o.y = f2bf(a.y * wt.x + bb.y * wt.y + cc.y * wt.z + dd.y * wt.w);
  o.z = f2bf(a.z * wt.x + bb.z * wt.y + cc.z * wt.z + dd.z * wt.w);
  o.w = f2bf(a.w * wt.x + bb.w * wt.y + cc.w * wt.z + dd.w * wt.w);
  size_t posg = (size_t)b * HWSZ + h * 64 + w0 + p;
  *(ushort4*)(xs + posg * CDIM + l128 * 4) = o;
}

// ------- split-L attention v2: one block serves TWO queries sharing a K/V slab -------
__global__ __launch_bounds__(256) void attn_split_kernel(const float* __restrict__ qh,
                                                         const unsigned short* __restrict__ kk,
                                                         const unsigned short* __restrict__ vv,
                                                         float* __restrict__ pm,
                                                         float* __restrict__ ps,
                                                         float* __restrict__ po) {
  __shared__ float sc0[128], sc1[128];
  __shared__ float qs0[64], qs1[64];
  __shared__ float red0[4], red1[4];
  __shared__ float part0[4][64], part1[4][64];
  int bid = blockIdx.x;
  int h = bid & 7;
  int bs = bid >> 3;
  int b = bs >> 5, s = bs & 31;
  int l0 = s << 7;
  int task0 = b * 33;
  int task1 = b * 33 + s + 1;
  int tid = threadIdx.x;
  if (tid < 64) qs0[tid] = qh[(size_t)task0 * CDIM + h * 64 + tid];
  else if (tid < 128) qs1[tid - 64] = qh[(size_t)task1 * CDIM + h * 64 + (tid - 64)];
  __syncthreads();

  const unsigned short* kb = kk + ((size_t)b * HWSZ + l0) * CDIM + h * 64;
  float lmax0 = -INFINITY, lmax1 = -INFINITY;
  if (tid < 128) {
    const uint4* kr = (const uint4*)(kb + (size_t)tid * CDIM);
    float sv0 = 0.f, sv1 = 0.f;
#pragma unroll
    for (int c = 0; c < 8; ++c) {
      uint4 kv = kr[c];
      float k0 = __uint_as_float(kv.x << 16);
      float k1 = __uint_as_float(kv.x & 0xffff0000u);
      float k2 = __uint_as_float(kv.y << 16);
      float k3 = __uint_as_float(kv.y & 0xffff0000u);
      float k4 = __uint_as_float(kv.z << 16);
      float k5 = __uint_as_float(kv.z & 0xffff0000u);
      float k6 = __uint_as_float(kv.w << 16);
      float k7 = __uint_as_float(kv.w & 0xffff0000u);
      sv0 = fmaf(k0, qs0[8 * c + 0], sv0); sv1 = fmaf(k0, qs1[8 * c + 0], sv1);
      sv0 = fmaf(k1, qs0[8 * c + 1], sv0); sv1 = fmaf(k1, qs1[8 * c + 1], sv1);
      sv0 = fmaf(k2, qs0[8 * c + 2], sv0); sv1 = fmaf(k2, qs1[8 * c + 2], sv1);
      sv0 = fmaf(k3, qs0[8 * c + 3], sv0); sv1 = fmaf(k3, qs1[8 * c + 3], sv1);
      sv0 = fmaf(k4, qs0[8 * c + 4], sv0); sv1 = fmaf(k4, qs1[8 * c + 4], sv1);
      sv0 = fmaf(k5, qs0[8 * c + 5], sv0); sv1 = fmaf(k5, qs1[8 * c + 5], sv1);
      sv0 = fmaf(k6, qs0[8 * c + 6], sv0); sv1 = fmaf(k6, qs1[8 * c + 6], sv1);
      sv0 = fmaf(k7, qs0[8 * c + 7], sv0); sv1 = fmaf(k7, qs1[8 * c + 7], sv1);
    }
    sv0 *= 0.125f; sv1 *= 0.125f;
    sc0[tid] = sv0; sc1[tid] = sv1;
    lmax0 = sv0; lmax1 = sv1;
  }
#pragma unroll
  for (int off = 32; off; off >>= 1) {
    lmax0 = fmaxf(lmax0, __shfl_xor(lmax0, off, 64));
    lmax1 = fmaxf(lmax1, __shfl_xor(lmax1, off, 64));
  }
  if (!(tid & 63)) { red0[tid >> 6] = lmax0; red1[tid >> 6] = lmax1; }
  __syncthreads();
  lmax0 = fmaxf(fmaxf(red0[0], red0[1]), fmaxf(red0[2], red0[3]));
  lmax1 = fmaxf(fmaxf(red1[0], red1[1]), fmaxf(red1[2], red1[3]));
  __syncthreads();

  float ls0 = 0.f, ls1 = 0.f;
  if (tid < 128) {
    float e0 = expf(sc0[tid] - lmax0);
    float e1 = expf(sc1[tid] - lmax1);
    sc0[tid] = e0; sc1[tid] = e1;
    ls0 = e0; ls1 = e1;
  }
#pragma unroll
  for (int off = 32; off; off >>= 1) {
    ls0 += __shfl_xor(ls0, off, 64);
    ls1 += __shfl_xor(ls1, off, 64);
  }
  if (!(tid & 63)) { red0[tid >> 6] = ls0; red1[tid >> 6] = ls1; }
  __syncthreads();
  float tsum0 = red0[0] + red0[1] + red0[2] + red0[3];
  float tsum1 = red1[0] + red1[1] + red1[2] + red1[3];

  int ch = tid & 63, g = tid >> 6;
  const unsigned short* vb = vv + ((size_t)b * HWSZ + l0) * CDIM + h * 64 + ch;
  float o0 = 0.f, o1 = 0.f;
#pragma unroll 4
  for (int l = g; l < 128; l += 4) {
    float vvv = bf2f(vb[(size_t)l * CDIM]);
    o0 = fmaf(sc0[l], vvv, o0);
    o1 = fmaf(sc1[l], vvv, o1);
  }
  part0[g][ch] = o0;
  part1[g][ch] = o1;
  __syncthreads();
  if (tid < 64) {
    float r0 = part0[0][tid] + part0[1][tid] + part0[2][tid] + part0[3][tid];
    float r1 = part1[0][tid] + part1[1][tid] + part1[2][tid] + part1[3][tid];
    int bid0 = (b * 64 + s) * 8 + h;
    int bid1 = (b * 64 + 32 + s) * 8 + h;
    po[(size_t)bid0 * 64 + tid] = r0;
    po[(size_t)bid1 * 64 + tid] = r1;
    if (tid == 0) {
      pm[bid0] = lmax0; ps[bid0] = tsum0;
      pm[bid1] = lmax1; ps[bid1] = tsum1;
    }
  }
}

// ------- merge partials (LSE combine) -------
__global__ __launch_bounds__(64) void attn_reduce_kernel(const float* __restrict__ pm,
                                                         const float* __restrict__ ps,
                                                         const float* __restrict__ po,
                                                         float* __restrict__ oo) {
  int bid = blockIdx.x;
  int h = bid & 7, task = bid >> 3;
  int b = task / 33, qidx = task - b * 33;
  int sbase = (qidx == 0) ? 0 : 31 + qidx;
  int ns = (qidx == 0) ? 32 : 1;
  int t = threadIdx.x;
  float mg = -INFINITY;
  for (int i = 0; i < ns; ++i) mg = fmaxf(mg, pm[((size_t)(b * 64 + sbase + i)) * 8 + h]);
  float tot = 0.f, o = 0.f;
  for (int i = 0; i < ns; ++i) {
    size_t pi = ((size_t)(b * 64 + sbase + i)) * 8 + h;
    float w = expf(pm[pi] - mg);
    tot = fmaf(ps[pi], w, tot);
    o = fmaf(po[pi * 64 + t], w, o);
  }
  oo[(size_t)task * CDIM + h * 64 + t] = o / tot;
}

extern "C" void kernel_launch(void* const* d_in, const int* in_sizes, int n_in,
                              void* d_out, int out_size, void* d_ws, size_t ws_size,
                              hipStream_t stream) {
  const float* q          = (const float*)d_in[0];
  const float* x          = (const float*)d_in[1];
  const float* w_off_proj = (const float*)d_in[2];
  const float* b_off_proj = (const float*)d_in[3];
  const float* w_dw       = (const float*)d_in[4];
  const float* b_dw       = (const float*)d_in[5];
  const float* ln_g       = (const float*)d_in[6];
  const float* ln_b       = (const float*)d_in[7];
  const float* w_off      = (const float*)d_in[8];
  const float* w_q        = (const float*)d_in[9];
  const float* b_q        = (const float*)d_in[10];
  const float* w_k        = (const float*)d_in[11];
  const float* b_k        = (const float*)d_in[12];
  const float* w_v        = (const float*)d_in[13];
  const float* b_v        = (const float*)d_in[14];
  const float* w_o        = (const float*)d_in[15];
  const float* b_o        = (const float*)d_in[16];

  char* ws = (char*)d_ws;
  size_t off = 0;
  const size_t NBIG = (size_t)BATCH * HWSZ * CDIM;
  const int NSPLIT = BATCH * 64 * 8;
  float* t0    = (float*)(ws + off);                  off += NBIG * 4;   // 134 MB
  unsigned short* xs_bf = (unsigned short*)(ws + off); off += NBIG * 2;
  unsigned short* k_bf  = (unsigned short*)(ws + off); off += NBIG * 2;
  unsigned short* v_bf  = (unsigned short*)(ws + off); off += NBIG * 2;
  unsigned short* wphi = (unsigned short*)(ws + off);  off += (size_t)CDIM * CDIM * 2;
  unsigned short* wplo = (unsigned short*)(ws + off);  off += (size_t)CDIM * CDIM * 2;
  unsigned short* wkv_bf = (unsigned short*)(ws + off); off += (size_t)2 * CDIM * CDIM * 2;
  float* w_dwT = (float*)(ws + off);                  off += (size_t)9 * CDIM * 4;
  float* qh    = (float*)(ws + off);                  off += (size_t)BATCH * NQTOT * CDIM * 4;
  float* o_all = (float*)(ws + off);                  off += (size_t)BATCH * NQTOT * CDIM * 4;
  float* pm    = (float*)(ws + off);                  off += (size_t)NSPLIT * 4;
  float* ps    = (float*)(ws + off);                  off += (size_t)NSPLIT * 4;
  float* po    = (float*)(ws + off);                  off += (size_t)NSPLIT * 64 * 4;

  const int Mbig = BATCH * HWSZ;  // 65536
  const int Msm  = BATCH * NQTOT; // 528
  dim3 gSm2(CDIM / SBN, (Msm + SBM - 1) / SBM);   // (8, 9) = 72 blocks
  dim3 gMf(CDIM / 128, Mbig / 128);
  dim3 gKV(2 * CDIM / 128, Mbig / 128);

  // 0) all weight conversions in one launch
  conv_all<<<786, 256, 0, stream>>>(w_off_proj, w_k, w_v, w_dw, wphi, wplo, wkv_bf, w_dwT);
  // 1) t0 = x @ w_off_proj^T + b ; BK=64, swizzled, in-kernel split
  gemm3_nt<<<gMf, 256, 0, stream>>>(x, wphi, wplo, b_off_proj, t0);
  // 2) fused depthwise+LN+GELU+offset+gather -> bf16 xs
  offset_gather_kernel<<<Mbig / 4, 512, 0, stream>>>(t0, x, w_dwT, b_dw, ln_g, ln_b, w_off, xs_bf);
  // 3) merged K|V projection; BK=32
  gemm_kv_nt<<<gKV, 256, 0, stream>>>(xs_bf, wkv_bf, b_k, b_v, k_bf, v_bf);
  // 4) Q projection (64x64 tiles: 72 blocks, occupancy fix per r19 ledger)
  gemm_sm_nt<<<gSm2, 256, 0, stream>>>(q, w_q, b_q, qh, Msm);
  // 5) dual-query split-L attention + LSE merge
  attn_split_kernel<<<NSPLIT / 2, 256, 0, stream>>>(qh, k_bf, v_bf, pm, ps, po);
  attn_reduce_kernel<<<Msm * 8, 64, 0, stream>>>(pm, ps, po, o_all);
  // 6) output projection -> d_out (64x64 tiles)
  gemm_sm_nt<<<gSm2, 256, 0, stream>>>(o_all, w_o, b_o, (float*)d_out, Msm);
}

// Round 21
// 470.690 us; speedup vs baseline: 1.3026x; 1.0076x over previous
//
#include <hip/hip_runtime.h>
#include <hip/hip_bf16.h>

#define CDIM 512
#define HWSZ 4096
#define BATCH 16
#define NQTOT 33

typedef short bf16x8 __attribute__((ext_vector_type(8)));
typedef float f32x4 __attribute__((ext_vector_type(4)));

__device__ __forceinline__ unsigned short f2bf(float f) {
  unsigned int u = __float_as_uint(f);
  u += 0x7fffu + ((u >> 16) & 1u);   // round-to-nearest-even
  return (unsigned short)(u >> 16);
}
__device__ __forceinline__ float bf2f(unsigned short s) {
  return __uint_as_float((unsigned int)s << 16);
}
__device__ __forceinline__ void gload16(const void* g, void* l) {
  __builtin_amdgcn_global_load_lds((const __attribute__((address_space(1))) void*)g,
                                   (__attribute__((address_space(3))) void*)l, 16, 0, 0);
}
// fast erf: Abramowitz-Stegun 7.1.26, |abs err| <= 1.5e-7 (invisible vs 4.9e-4 margin)
__device__ __forceinline__ float fast_erf(float x) {
  float ax = fabsf(x);
  float t = __builtin_amdgcn_rcpf(fmaf(0.3275911f, ax, 1.f));
  float p = fmaf(t, 1.061405429f, -1.453152027f);
  p = fmaf(t, p, 1.421413741f);
  p = fmaf(t, p, -0.284496736f);
  p = fmaf(t, p, 0.254829592f);
  p = p * t;
  float e = 1.f - p * __expf(-ax * ax);
  return copysignf(e, x);
}
__device__ __forceinline__ float gelu(float x) {
  return x * 0.5f * (1.f + fast_erf(x * 0.70710678118654752f));
}
// XCD-aware bijective swizzle (nwg % 8 == 0)
__device__ __forceinline__ int2 swz_tiles(int nwgx) {
  int nwg = gridDim.x * gridDim.y;
  int l = blockIdx.y * gridDim.x + blockIdx.x;
  int w = (l & 7) * (nwg >> 3) + (l >> 3);
  return make_int2((w % nwgx) * 128, (w / nwgx) * 128);  // (n0, m0)
}
// Lessons: (r12) never break global coalescing for LDS conflicts; (r17) BK=64
// only pays when a per-phase VALU stream overlaps MFMA; (r19) small-M GEMMs
// need small tiles for occupancy.

// ------- small-M f32 NT GEMM: 64x64 tiles for occupancy; C = A*W^T + bias -------
#define SBM 64
#define SBN 64
#define SBK 16

__global__ __launch_bounds__(256) void gemm_sm_nt(const float* __restrict__ A,
                                                  const float* __restrict__ Wt,
                                                  const float* __restrict__ bias,
                                                  float* __restrict__ C, int M) {
  const int K = CDIM, N = CDIM;
  __shared__ float As[SBK][SBM + 4];
  __shared__ float Bs[SBK][SBN + 4];
  int tid = threadIdx.x;
  int n0 = blockIdx.x * SBN;
  int m0 = blockIdx.y * SBM;
  int ty = tid >> 4, tx = tid & 15;
  float acc[4][4];
#pragma unroll
  for (int i = 0; i < 4; ++i)
#pragma unroll
    for (int j = 0; j < 4; ++j) acc[i][j] = 0.f;

  int lrow = tid >> 2, lkk = (tid & 3) << 2;
  for (int k0 = 0; k0 < K; k0 += SBK) {
    float4 va = make_float4(0.f, 0.f, 0.f, 0.f);
    if (m0 + lrow < M) va = *(const float4*)(A + (size_t)(m0 + lrow) * K + k0 + lkk);
    As[lkk + 0][lrow] = va.x; As[lkk + 1][lrow] = va.y;
    As[lkk + 2][lrow] = va.z; As[lkk + 3][lrow] = va.w;
    float4 vb = *(const float4*)(Wt + (size_t)(n0 + lrow) * K + k0 + lkk);
    Bs[lkk + 0][lrow] = vb.x; Bs[lkk + 1][lrow] = vb.y;
    Bs[lkk + 2][lrow] = vb.z; Bs[lkk + 3][lrow] = vb.w;
    __syncthreads();
#pragma unroll
    for (int k = 0; k < SBK; ++k) {
      float a[4], b[4];
      *(float4*)&a[0] = *(float4*)&As[k][ty * 4];
      *(float4*)&b[0] = *(float4*)&Bs[k][tx * 4];
#pragma unroll
      for (int i = 0; i < 4; ++i)
#pragma unroll
        for (int j = 0; j < 4; ++j) acc[i][j] = fmaf(a[i], b[j], acc[i][j]);
    }
    __syncthreads();
  }
#pragma unroll
  for (int i = 0; i < 4; ++i) {
    int m = m0 + ty * 4 + i;
    if (m >= M) continue;
    int n = n0 + tx * 4;
    float4 v;
    v.x = acc[i][0] + bias[n + 0];
    v.y = acc[i][1] + bias[n + 1];
    v.z = acc[i][2] + bias[n + 2];
    v.w = acc[i][3] + bias[n + 3];
    *(float4*)(C + (size_t)m * N + n) = v;
  }
}

// ------- merged K|V bf16 MFMA NT GEMM over Wkv[1024][512]; BK=32 -------
__global__ __launch_bounds__(256) void gemm_kv_nt(const unsigned short* __restrict__ A,
                                                  const unsigned short* __restrict__ Wkv,
                                                  const float* __restrict__ bk,
                                                  const float* __restrict__ bv,
                                                  unsigned short* __restrict__ K,
                                                  unsigned short* __restrict__ V) {
  __shared__ unsigned short As[128 * 32];
  __shared__ unsigned short Ws[128 * 32];
  int tid = threadIdx.x;
  int wave = tid >> 6, lane = tid & 63;
  int2 t = swz_tiles(gridDim.x);
  int n0 = t.x, m0 = t.y;
  int wm = (wave >> 1) * 64, wn = (wave & 1) * 64;
  f32x4 acc[4][4];
#pragma unroll
  for (int i = 0; i < 4; ++i)
#pragma unroll
    for (int j = 0; j < 4; ++j) acc[i][j] = (f32x4){0.f, 0.f, 0.f, 0.f};

  int rsel = lane & 15;
  int ksel = (lane >> 4) * 8;

  for (int k0 = 0; k0 < CDIM; k0 += 32) {
#pragma unroll
    for (int c = 0; c < 2; ++c) {
      int s = c * 256 + tid;
      int row = s >> 2, ch = s & 3;
      gload16(A + (size_t)(m0 + row) * CDIM + k0 + ch * 8, (void*)(As + (size_t)s * 8));
      gload16(Wkv + (size_t)(n0 + row) * CDIM + k0 + ch * 8, (void*)(Ws + (size_t)s * 8));
    }
    __syncthreads();
    bf16x8 af[4], bfr[4];
#pragma unroll
    for (int mf = 0; mf < 4; ++mf)
      af[mf] = *(const bf16x8*)&As[(wm + mf * 16 + rsel) * 32 + ksel];
#pragma unroll
    for (int nf = 0; nf < 4; ++nf)
      bfr[nf] = *(const bf16x8*)&Ws[(wn + nf * 16 + rsel) * 32 + ksel];
#pragma unroll
    for (int mf = 0; mf < 4; ++mf)
#pragma unroll
      for (int nf = 0; nf < 4; ++nf)
        acc[mf][nf] = __builtin_amdgcn_mfma_f32_16x16x32_bf16(af[mf], bfr[nf], acc[mf][nf], 0, 0, 0);
    __syncthreads();
  }
  const float* bias = (n0 < 512) ? bk : bv;
  unsigned short* C = (n0 < 512) ? K : V;
  int nb = (n0 < 512) ? n0 : n0 - 512;
#pragma unroll
  for (int nf = 0; nf < 4; ++nf) {
    int col = nb + wn + nf * 16 + (lane & 15);
    float bv2 = bias[col];
#pragma unroll
    for (int mf = 0; mf < 4; ++mf) {
      int rbase = m0 + wm + mf * 16 + (lane >> 4) * 4;
#pragma unroll
      for (int i = 0; i < 4; ++i)
        C[(size_t)(rbase + i) * CDIM + col] = f2bf(acc[mf][nf][i] + bv2);
    }
  }
}

// ------- split-bf16 f32-precision NT GEMM; BK=64, XOR chunk swizzle -------
__global__ __launch_bounds__(256) void gemm3_nt(const float* __restrict__ A,
                                                const unsigned short* __restrict__ Whi,
                                                const unsigned short* __restrict__ Wlo,
                                                const float* __restrict__ bias,
                                                float* __restrict__ C) {
  __shared__ unsigned short AsH[128 * 64];
  __shared__ unsigned short AsL[128 * 64];
  __shared__ unsigned short WsH[128 * 64];
  __shared__ unsigned short WsL[128 * 64];
  int tid = threadIdx.x;
  int wave = tid >> 6, lane = tid & 63;
  int2 t = swz_tiles(gridDim.x);
  int n0 = t.x, m0 = t.y;
  int wm = (wave >> 1) * 64, wn = (wave & 1) * 64;
  f32x4 acc[4][4];
#pragma unroll
  for (int i = 0; i < 4; ++i)
#pragma unroll
    for (int j = 0; j < 4; ++j) acc[i][j] = (f32x4){0.f, 0.f, 0.f, 0.f};

  int rsel = lane & 15;
  int kcsel = lane >> 4;

  for (int k0 = 0; k0 < CDIM; k0 += 64) {
#pragma unroll
    for (int c = 0; c < 4; ++c) {
      int s = c * 256 + tid;
      int row = s >> 3, ch = s & 7;
      size_t gw = (size_t)(n0 + row) * CDIM + k0 + (size_t)(ch ^ (row & 7)) * 8;
      gload16(Whi + gw, (void*)(WsH + (size_t)s * 8));
      gload16(Wlo + gw, (void*)(WsL + (size_t)s * 8));
    }
#pragma unroll
    for (int c = 0; c < 4; ++c) {
      int s = c * 256 + tid;
      int row = s >> 3, q = s & 7;
      const float4* src = (const float4*)(A + (size_t)(m0 + row) * CDIM + k0 + (size_t)(q ^ (row & 7)) * 8);
      float4 v0 = src[0], v1 = src[1];
      float vv[8] = {v0.x, v0.y, v0.z, v0.w, v1.x, v1.y, v1.z, v1.w};
      unsigned int hw[4], lw[4];
#pragma unroll
      for (int j = 0; j < 4; ++j) {
        unsigned int u0 = __float_as_uint(vv[2 * j]);
        unsigned int u1 = __float_as_uint(vv[2 * j + 1]);
        hw[j] = (u0 >> 16) | (u1 & 0xffff0000u);        // truncated hi pair
        float l0 = vv[2 * j] - __uint_as_float(u0 & 0xffff0000u);
        float l1 = vv[2 * j + 1] - __uint_as_float(u1 & 0xffff0000u);
        __hip_bfloat162 l2 = __float22bfloat162_rn(make_float2(l0, l1));
        lw[j] = *reinterpret_cast<unsigned int*>(&l2);  // RNE lo pair
      }
      *(uint4*)&AsH[(size_t)s * 8] = make_uint4(hw[0], hw[1], hw[2], hw[3]);
      *(uint4*)&AsL[(size_t)s * 8] = make_uint4(lw[0], lw[1], lw[2], lw[3]);
    }
    __syncthreads();
#pragma unroll
    for (int half = 0; half < 2; ++half) {
      int cb = half * 4 + kcsel;
      bf16x8 ah[4], al[4], bh[4], bl[4];
#pragma unroll
      for (int mf = 0; mf < 4; ++mf) {
        int row = wm + mf * 16 + rsel;
        int off = (row * 8 + (cb ^ (row & 7))) * 8;
        ah[mf] = *(const bf16x8*)&AsH[off];
        al[mf] = *(const bf16x8*)&AsL[off];
      }
#pragma unroll
      for (int nf = 0; nf < 4; ++nf) {
        int row = wn + nf * 16 + rsel;
        int off = (row * 8 + (cb ^ (row & 7))) * 8;
        bh[nf] = *(const bf16x8*)&WsH[off];
        bl[nf] = *(const bf16x8*)&WsL[off];
      }
#pragma unroll
      for (int mf = 0; mf < 4; ++mf)
#pragma unroll
        for (int nf = 0; nf < 4; ++nf) {
          acc[mf][nf] = __builtin_amdgcn_mfma_f32_16x16x32_bf16(ah[mf], bh[nf], acc[mf][nf], 0, 0, 0);
          acc[mf][nf] = __builtin_amdgcn_mfma_f32_16x16x32_bf16(ah[mf], bl[nf], acc[mf][nf], 0, 0, 0);
          acc[mf][nf] = __builtin_amdgcn_mfma_f32_16x16x32_bf16(al[mf], bh[nf], acc[mf][nf], 0, 0, 0);
        }
    }
    __syncthreads();
  }
#pragma unroll
  for (int nf = 0; nf < 4; ++nf) {
    int col = n0 + wn + nf * 16 + (lane & 15);
    float bvs = bias[col];
#pragma unroll
    for (int mf = 0; mf < 4; ++mf) {
      int rbase = m0 + wm + mf * 16 + (lane >> 4) * 4;
#pragma unroll
      for (int i = 0; i < 4; ++i)
        C[(size_t)(rbase + i) * CDIM + col] = acc[mf][nf][i] + bvs;
    }
  }
}

// ------- ONE-SHOT weight prep -------
__global__ __launch_bounds__(256) void conv_all(const float* __restrict__ w_off_proj,
                                                const float* __restrict__ w_k,
                                                const float* __restrict__ w_v,
                                                const float* __restrict__ w_dw,
                                                unsigned short* __restrict__ wphi,
                                                unsigned short* __restrict__ wplo,
                                                unsigned short* __restrict__ wkv,
                                                float* __restrict__ wdwT) {
  int blk = blockIdx.x, tid = threadIdx.x;
  if (blk < 256) {
    int i = blk * 256 + tid;
    float4 v = ((const float4*)w_off_proj)[i];
    ushort4 h, l;
    h.x = f2bf(v.x); l.x = f2bf(v.x - bf2f(h.x));
    h.y = f2bf(v.y); l.y = f2bf(v.y - bf2f(h.y));
    h.z = f2bf(v.z); l.z = f2bf(v.z - bf2f(h.z));
    h.w = f2bf(v.w); l.w = f2bf(v.w - bf2f(h.w));
    ((ushort4*)wphi)[i] = h;
    ((ushort4*)wplo)[i] = l;
  } else if (blk < 512) {
    int i = (blk - 256) * 256 + tid;
    float4 v = ((const float4*)w_k)[i];
    ushort4 o;
    o.x = f2bf(v.x); o.y = f2bf(v.y); o.z = f2bf(v.z); o.w = f2bf(v.w);
    ((ushort4*)wkv)[i] = o;
  } else if (blk < 768) {
    int i = (blk - 512) * 256 + tid;
    float4 v = ((const float4*)w_v)[i];
    ushort4 o;
    o.x = f2bf(v.x); o.y = f2bf(v.y); o.z = f2bf(v.z); o.w = f2bf(v.w);
    ((ushort4*)(wkv + (size_t)CDIM * CDIM))[i] = o;
  } else {
    int id = (blk - 768) * 256 + tid;
    if (id < 9 * CDIM) wdwT[id] = w_dw[(id & 511) * 9 + (id >> 9)];
  }
}

// ------- FUSED: depthwise3x3 + LN + GELU(fast erf) + offset head + gather -> bf16 xs -------
__global__ __launch_bounds__(512) void offset_gather_kernel(
    const float* __restrict__ t0, const float* __restrict__ x,
    const float* __restrict__ w_dwT, const float* __restrict__ b_dw,
    const float* __restrict__ ln_g, const float* __restrict__ ln_b,
    const float* __restrict__ w_off, unsigned short* __restrict__ xs) {
  __shared__ float4 sten[18 * 128];
  __shared__ float redA[8], redB[8], redC[8], redD[8];
  __shared__ int4 sid[4];
  __shared__ float4 swt[4];

  int blk = blockIdx.x;
  int b = blk >> 10, rem = blk & 1023;
  int h = rem >> 4, w0 = (rem & 15) << 2;
  int t = threadIdx.x;
  const float* base = t0 + (size_t)b * HWSZ * CDIM;

  for (int s = t; s < 18 * 128; s += 512) {
    int ps = s >> 7, q = s & 127;
    int r = ps / 6, cs = ps - r * 6;
    int hh = h + r - 1, ww = w0 + cs - 1;
    if ((unsigned)hh < 64u && (unsigned)ww < 64u) {
      gload16(base + (size_t)(hh * 64 + ww) * CDIM + 4 * q, (void*)(sten + s));
    } else {
      sten[s] = make_float4(0.f, 0.f, 0.f, 0.f);
    }
  }
  __syncthreads();

  int p = t >> 7;
  int l128 = t & 127;
  float4 acc = ((const float4*)b_dw)[l128];
#pragma unroll
  for (int r = 0; r < 3; ++r)
#pragma unroll
    for (int dxi = 0; dxi < 3; ++dxi) {
      float4 w4 = ((const float4*)(w_dwT + (size_t)(r * 3 + dxi) * CDIM))[l128];
      float4 v = sten[(r * 6 + p + dxi) * 128 + l128];
      acc.x = fmaf(v.x, w4.x, acc.x);
      acc.y = fmaf(v.y, w4.y, acc.y);
      acc.z = fmaf(v.z, w4.z, acc.z);
      acc.w = fmaf(v.w, w4.w, acc.w);
    }
  float s = acc.x + acc.y + acc.z + acc.w;
  float s2 = acc.x * acc.x + acc.y * acc.y + acc.z * acc.z + acc.w * acc.w;
#pragma unroll
  for (int off = 32; off; off >>= 1) {
    s += __shfl_xor(s, off, 64);
    s2 += __shfl_xor(s2, off, 64);
  }
  int wv = t >> 6, lane = t & 63;
  if (!lane) { redA[wv] = s; redB[wv] = s2; }
  __syncthreads();
  s = redA[2 * p] + redA[2 * p + 1];
  s2 = redB[2 * p] + redB[2 * p + 1];
  float mean = s * (1.f / 512.f);
  float var = s2 * (1.f / 512.f) - mean * mean;
  float inv = 1.f / sqrtf(var + 1e-5f);

  float4 g4 = ((const float4*)ln_g)[l128];
  float4 lb4 = ((const float4*)ln_b)[l128];
  float4 wy4 = ((const float4*)w_off)[l128];
  float4 wx4 = ((const float4*)(w_off + CDIM))[l128];
  float4 xn;
  xn.x = (acc.x - mean) * inv * g4.x + lb4.x;
  xn.y = (acc.y - mean) * inv * g4.y + lb4.y;
  xn.z = (acc.z - mean) * inv * g4.z + lb4.z;
  xn.w = (acc.w - mean) * inv * g4.w + lb4.w;
  float4 ge;
  ge.x = gelu(xn.x);
  ge.y = gelu(xn.y);
  ge.z = gelu(xn.z);
  ge.w = gelu(xn.w);
  float oy = ge.x * wy4.x + ge.y * wy4.y + ge.z * wy4.z + ge.w * wy4.w;
  float ox = ge.x * wx4.x + ge.y * wx4.y + ge.z * wx4.z + ge.w * wx4.w;
#pragma unroll
  for (int off = 32; off; off >>= 1) {
    oy += __shfl_xor(oy, off, 64);
    ox += __shfl_xor(ox, off, 64);
  }
  if (!lane) { redC[wv] = oy; redD[wv] = ox; }
  __syncthreads();
  if (l128 == 0) {
    oy = redC[2 * p] + redC[2 * p + 1];
    ox = redD[2 * p] + redD[2 * p + 1];
    int wcol = w0 + p;
    float ry = ((float)h + 0.5f) / 64.f * 2.f - 1.f;
    float rx = ((float)wcol + 0.5f) / 64.f * 2.f - 1.f;
    float py = tanhf(oy + ry);
    float px = tanhf(ox + rx);
    float fx = (px + 1.f) * 0.5f * 63.f;
    float fy = (py + 1.f) * 0.5f * 63.f;
    float fx0 = floorf(fx), fy0 = floorf(fy);
    float fx1 = fx0 + 1.f, fy1 = fy0 + 1.f;
    float wx1 = fx - fx0, wx0 = fx1 - fx;
    float wy1 = fy - fy0, wy0 = fy1 - fy;
    float m00 = (fy0 >= 0.f && fy0 <= 63.f && fx0 >= 0.f && fx0 <= 63.f) ? 1.f : 0.f;
    float m01 = (fy0 >= 0.f && fy0 <= 63.f && fx1 >= 0.f && fx1 <= 63.f) ? 1.f : 0.f;
    float m10 = (fy1 >= 0.f && fy1 <= 63.f && fx0 >= 0.f && fx0 <= 63.f) ? 1.f : 0.f;
    float m11 = (fy1 >= 0.f && fy1 <= 63.f && fx1 >= 0.f && fx1 <= 63.f) ? 1.f : 0.f;
    int xi0 = min(max((int)fx0, 0), 63), xi1 = min(max((int)fx1, 0), 63);
    int yi0 = min(max((int)fy0, 0), 63), yi1 = min(max((int)fy1, 0), 63);
    sid[p] = make_int4(yi0 * 64 + xi0, yi0 * 64 + xi1, yi1 * 64 + xi0, yi1 * 64 + xi1);
    swt[p] = make_float4(wx0 * wy0 * m00, wx1 * wy0 * m01, wx0 * wy1 * m10, wx1 * wy1 * m11);
  }
  __syncthreads();
  int4 id = sid[p];
  float4 wt = swt[p];
  const float* xb = x + (size_t)b * HWSZ * CDIM;
  float4 a = ((const float4*)(xb + (size_t)id.x * CDIM))[l128];
  float4 bb = ((const float4*)(xb + (size_t)id.y * CDIM))[l128];
  float4 cc = ((const float4*)(xb + (size_t)id.z * CDIM))[l128];
  float4 dd = ((const float4*)(xb + (size_t)id.w * CDIM))[l128];
  ushort4 o;
  o.x = f2bf(a.x * wt.x + bb.x * wt.y + cc.x * wt.z + dd.x * wt.w);
  o.y = f2bf(a.y * wt.x + bb.y * wt.y + cc.y * wt.z + dd.y * wt.w);
  o.z = f2bf(a.z * wt.x + bb.z * wt.y + cc.z * wt.z + dd.z * wt.w);
  o.w = f2bf(a.w * wt.x + bb.w * wt.y + cc.w * wt.z + dd.w * wt.w);
  size_t posg = (size_t)b * HWSZ + h * 64 + w0 + p;
  *(ushort4*)(xs + posg * CDIM + l128 * 4) = o;
}

// ------- split-L attention v2: one block serves TWO queries sharing a K/V slab -------
__global__ __launch_bounds__(256) void attn_split_kernel(const float* __restrict__ qh,
                                                         const unsigned short* __restrict__ kk,
                                                         const unsigned short* __restrict__ vv,
                                                         float* __restrict__ pm,
                                                         float* __restrict__ ps,
                                                         float* __restrict__ po) {
  __shared__ float sc0[128], sc1[128];
  __shared__ float qs0[64], qs1[64];
  __shared__ float red0[4], red1[4];
  __shared__ float part0[4][64], part1[4][64];
  int bid = blockIdx.x;
  int h = bid & 7;
  int bs = bid >> 3;
  int b = bs >> 5, s = bs & 31;
  int l0 = s << 7;
  int task0 = b * 33;
  int task1 = b * 33 + s + 1;
  int tid = threadIdx.x;
  if (tid < 64) qs0[tid] = qh[(size_t)task0 * CDIM + h * 64 + tid];
  else if (tid < 128) qs1[tid - 64] = qh[(size_t)task1 * CDIM + h * 64 + (tid - 64)];
  __syncthreads();

  const unsigned short* kb = kk + ((size_t)b * HWSZ + l0) * CDIM + h * 64;
  float lmax0 = -INFINITY, lmax1 = -INFINITY;
  if (tid < 128) {
    const uint4* kr = (const uint4*)(kb + (size_t)tid * CDIM);
    float sv0 = 0.f, sv1 = 0.f;
#pragma unroll
    for (int c = 0; c < 8; ++c) {
      uint4 kv = kr[c];
      float k0 = __uint_as_float(kv.x << 16);
      float k1 = __uint_as_float(kv.x & 0xffff0000u);
      float k2 = __uint_as_float(kv.y << 16);
      float k3 = __uint_as_float(kv.y & 0xffff0000u);
      float k4 = __uint_as_float(kv.z << 16);
      float k5 = __uint_as_float(kv.z & 0xffff0000u);
      float k6 = __uint_as_float(kv.w << 16);
      float k7 = __uint_as_float(kv.w & 0xffff0000u);
      sv0 = fmaf(k0, qs0[8 * c + 0], sv0); sv1 = fmaf(k0, qs1[8 * c + 0], sv1);
      sv0 = fmaf(k1, qs0[8 * c + 1], sv0); sv1 = fmaf(k1, qs1[8 * c + 1], sv1);
      sv0 = fmaf(k2, qs0[8 * c + 2], sv0); sv1 = fmaf(k2, qs1[8 * c + 2], sv1);
      sv0 = fmaf(k3, qs0[8 * c + 3], sv0); sv1 = fmaf(k3, qs1[8 * c + 3], sv1);
      sv0 = fmaf(k4, qs0[8 * c + 4], sv0); sv1 = fmaf(k4, qs1[8 * c + 4], sv1);
      sv0 = fmaf(k5, qs0[8 * c + 5], sv0); sv1 = fmaf(k5, qs1[8 * c + 5], sv1);
      sv0 = fmaf(k6, qs0[8 * c + 6], sv0); sv1 = fmaf(k6, qs1[8 * c + 6], sv1);
      sv0 = fmaf(k7, qs0[8 * c + 7], sv0); sv1 = fmaf(k7, qs1[8 * c + 7], sv1);
    }
    sv0 *= 0.125f; sv1 *= 0.125f;
    sc0[tid] = sv0; sc1[tid] = sv1;
    lmax0 = sv0; lmax1 = sv1;
  }
#pragma unroll
  for (int off = 32; off; off >>= 1) {
    lmax0 = fmaxf(lmax0, __shfl_xor(lmax0, off, 64));
    lmax1 = fmaxf(lmax1, __shfl_xor(lmax1, off, 64));
  }
  if (!(tid & 63)) { red0[tid >> 6] = lmax0; red1[tid >> 6] = lmax1; }
  __syncthreads();
  lmax0 = fmaxf(fmaxf(red0[0], red0[1]), fmaxf(red0[2], red0[3]));
  lmax1 = fmaxf(fmaxf(red1[0], red1[1]), fmaxf(red1[2], red1[3]));
  __syncthreads();

  float ls0 = 0.f, ls1 = 0.f;
  if (tid < 128) {
    float e0 = expf(sc0[tid] - lmax0);
    float e1 = expf(sc1[tid] - lmax1);
    sc0[tid] = e0; sc1[tid] = e1;
    ls0 = e0; ls1 = e1;
  }
#pragma unroll
  for (int off = 32; off; off >>= 1) {
    ls0 += __shfl_xor(ls0, off, 64);
    ls1 += __shfl_xor(ls1, off, 64);
  }
  if (!(tid & 63)) { red0[tid >> 6] = ls0; red1[tid >> 6] = ls1; }
  __syncthreads();
  float tsum0 = red0[0] + red0[1] + red0[2] + red0[3];
  float tsum1 = red1[0] + red1[1] + red1[2] + red1[3];

  int ch = tid & 63, g = tid >> 6;
  const unsigned short* vb = vv + ((size_t)b * HWSZ + l0) * CDIM + h * 64 + ch;
  float o0 = 0.f, o1 = 0.f;
#pragma unroll 4
  for (int l = g; l < 128; l += 4) {
    float vvv = bf2f(vb[(size_t)l * CDIM]);
    o0 = fmaf(sc0[l], vvv, o0);
    o1 = fmaf(sc1[l], vvv, o1);
  }
  part0[g][ch] = o0;
  part1[g][ch] = o1;
  __syncthreads();
  if (tid < 64) {
    float r0 = part0[0][tid] + part0[1][tid] + part0[2][tid] + part0[3][tid];
    float r1 = part1[0][tid] + part1[1][tid] + part1[2][tid] + part1[3][tid];
    int bid0 = (b * 64 + s) * 8 + h;
    int bid1 = (b * 64 + 32 + s) * 8 + h;
    po[(size_t)bid0 * 64 + tid] = r0;
    po[(size_t)bid1 * 64 + tid] = r1;
    if (tid == 0) {
      pm[bid0] = lmax0; ps[bid0] = tsum0;
      pm[bid1] = lmax1; ps[bid1] = tsum1;
    }
  }
}

// ------- merge partials (LSE combine) -------
__global__ __launch_bounds__(64) void attn_reduce_kernel(const float* __restrict__ pm,
                                                         const float* __restrict__ ps,
                                                         const float* __restrict__ po,
                                                         float* __restrict__ oo) {
  int bid = blockIdx.x;
  int h = bid & 7, task = bid >> 3;
  int b = task / 33, qidx = task - b * 33;
  int sbase = (qidx == 0) ? 0 : 31 + qidx;
  int ns = (qidx == 0) ? 32 : 1;
  int t = threadIdx.x;
  float mg = -INFINITY;
  for (int i = 0; i < ns; ++i) mg = fmaxf(mg, pm[((size_t)(b * 64 + sbase + i)) * 8 + h]);
  float tot = 0.f, o = 0.f;
  for (int i = 0; i < ns; ++i) {
    size_t pi = ((size_t)(b * 64 + sbase + i)) * 8 + h;
    float w = expf(pm[pi] - mg);
    tot = fmaf(ps[pi], w, tot);
    o = fmaf(po[pi * 64 + t], w, o);
  }
  oo[(size_t)task * CDIM + h * 64 + t] = o / tot;
}

extern "C" void kernel_launch(void* const* d_in, const int* in_sizes, int n_in,
                              void* d_out, int out_size, void* d_ws, size_t ws_size,
                              hipStream_t stream) {
  const float* q          = (const float*)d_in[0];
  const float* x          = (const float*)d_in[1];
  const float* w_off_proj = (const float*)d_in[2];
  const float* b_off_proj = (const float*)d_in[3];
  const float* w_dw       = (const float*)d_in[4];
  const float* b_dw       = (const float*)d_in[5];
  const float* ln_g       = (const float*)d_in[6];
  const float* ln_b       = (const float*)d_in[7];
  const float* w_off      = (const float*)d_in[8];
  const float* w_q        = (const float*)d_in[9];
  const float* b_q        = (const float*)d_in[10];
  const float* w_k        = (const float*)d_in[11];
  const float* b_k        = (const float*)d_in[12];
  const float* w_v        = (const float*)d_in[13];
  const float* b_v        = (const float*)d_in[14];
  const float* w_o        = (const float*)d_in[15];
  const float* b_o        = (const float*)d_in[16];

  char* ws = (char*)d_ws;
  size_t off = 0;
  const size_t NBIG = (size_t)BATCH * HWSZ * CDIM;
  const int NSPLIT = BATCH * 64 * 8;
  float* t0    = (float*)(ws + off);                  off += NBIG * 4;   // 134 MB
  unsigned short* xs_bf = (unsigned short*)(ws + off); off += NBIG * 2;
  unsigned short* k_bf  = (unsigned short*)(ws + off); off += NBIG * 2;
  unsigned short* v_bf  = (unsigned short*)(ws + off); off += NBIG * 2;
  unsigned short* wphi = (unsigned short*)(ws + off);  off += (size_t)CDIM * CDIM * 2;
  unsigned short* wplo = (unsigned short*)(ws + off);  off += (size_t)CDIM * CDIM * 2;
  unsigned short* wkv_bf = (unsigned short*)(ws + off); off += (size_t)2 * CDIM * CDIM * 2;
  float* w_dwT = (float*)(ws + off);                  off += (size_t)9 * CDIM * 4;
  float* qh    = (float*)(ws + off);                  off += (size_t)BATCH * NQTOT * CDIM * 4;
  float* o_all = (float*)(ws + off);                  off += (size_t)BATCH * NQTOT * CDIM * 4;
  float* pm    = (float*)(ws + off);                  off += (size_t)NSPLIT * 4;
  float* ps    = (float*)(ws + off);                  off += (size_t)NSPLIT * 4;
  float* po    = (float*)(ws + off);                  off += (size_t)NSPLIT * 64 * 4;

  const int Mbig = BATCH * HWSZ;  // 65536
  const int Msm  = BATCH * NQTOT; // 528
  dim3 gSm2(CDIM / SBN, (Msm + SBM - 1) / SBM);   // (8, 9)
  dim3 gMf(CDIM / 128, Mbig / 128);
  dim3 gKV(2 * CDIM / 128, Mbig / 128);

  // 0) all weight conversions in one launch
  conv_all<<<786, 256, 0, stream>>>(w_off_proj, w_k, w_v, w_dw, wphi, wplo, wkv_bf, w_dwT);
  // 1) t0 = x @ w_off_proj^T + b ; BK=64, swizzled, in-kernel split
  gemm3_nt<<<gMf, 256, 0, stream>>>(x, wphi, wplo, b_off_proj, t0);
  // 2) fused depthwise+LN+GELU(fast erf)+offset+gather -> bf16 xs
  offset_gather_kernel<<<Mbig / 4, 512, 0, stream>>>(t0, x, w_dwT, b_dw, ln_g, ln_b, w_off, xs_bf);
  // 3) merged K|V projection; BK=32
  gemm_kv_nt<<<gKV, 256, 0, stream>>>(xs_bf, wkv_bf, b_k, b_v, k_bf, v_bf);
  // 4) Q projection (64x64 tiles)
  gemm_sm_nt<<<gSm2, 256, 0, stream>>>(q, w_q, b_q, qh, Msm);
  // 5) dual-query split-L attention + LSE merge
  attn_split_kernel<<<NSPLIT / 2, 256, 0, stream>>>(qh, k_bf, v_bf, pm, ps, po);
  attn_reduce_kernel<<<Msm * 8, 64, 0, stream>>>(pm, ps, po, o_all);
  // 6) output projection -> d_out (64x64 tiles)
  gemm_sm_nt<<<gSm2, 256, 0, stream>>>(o_all, w_o, b_o, (float*)d_out, Msm);
}

// Round 22
// 467.981 us; speedup vs baseline: 1.3101x; 1.0058x over previous
//
#include <hip/hip_runtime.h>
#include <hip/hip_bf16.h>

#define CDIM 512
#define HWSZ 4096
#define BATCH 16
#define NQTOT 33

typedef short bf16x8 __attribute__((ext_vector_type(8)));
typedef float f32x4 __attribute__((ext_vector_type(4)));

__device__ __forceinline__ unsigned short f2bf(float f) {
  unsigned int u = __float_as_uint(f);
  u += 0x7fffu + ((u >> 16) & 1u);   // round-to-nearest-even
  return (unsigned short)(u >> 16);
}
__device__ __forceinline__ float bf2f(unsigned short s) {
  return __uint_as_float((unsigned int)s << 16);
}
__device__ __forceinline__ void gload16(const void* g, void* l) {
  __builtin_amdgcn_global_load_lds((const __attribute__((address_space(1))) void*)g,
                                   (__attribute__((address_space(3))) void*)l, 16, 0, 0);
}
// fast erf: Abramowitz-Stegun 7.1.26, |abs err| <= 1.5e-7
__device__ __forceinline__ float fast_erf(float x) {
  float ax = fabsf(x);
  float t = __builtin_amdgcn_rcpf(fmaf(0.3275911f, ax, 1.f));
  float p = fmaf(t, 1.061405429f, -1.453152027f);
  p = fmaf(t, p, 1.421413741f);
  p = fmaf(t, p, -0.284496736f);
  p = fmaf(t, p, 0.254829592f);
  p = p * t;
  float e = 1.f - p * __expf(-ax * ax);
  return copysignf(e, x);
}
__device__ __forceinline__ float gelu(float x) {
  return x * 0.5f * (1.f + fast_erf(x * 0.70710678118654752f));
}
// XCD-aware bijective swizzle (nwg % 8 == 0)
__device__ __forceinline__ int2 swz_tiles(int nwgx) {
  int nwg = gridDim.x * gridDim.y;
  int l = blockIdx.y * gridDim.x + blockIdx.x;
  int w = (l & 7) * (nwg >> 3) + (l >> 3);
  return make_int2((w % nwgx) * 128, (w / nwgx) * 128);  // (n0, m0)
}
// Lessons: (r12) never break global coalescing for LDS conflicts; (r17) BK=64
// only pays when a per-phase VALU stream overlaps MFMA; (r19) small-M GEMMs
// need small tiles; (r21) VALUBusy high != named-op dominant, count real insts.

// ------- small-M f32 NT GEMM: 64x64 tiles for occupancy; C = A*W^T + bias -------
#define SBM 64
#define SBN 64
#define SBK 16

__global__ __launch_bounds__(256) void gemm_sm_nt(const float* __restrict__ A,
                                                  const float* __restrict__ Wt,
                                                  const float* __restrict__ bias,
                                                  float* __restrict__ C, int M) {
  const int K = CDIM, N = CDIM;
  __shared__ float As[SBK][SBM + 4];
  __shared__ float Bs[SBK][SBN + 4];
  int tid = threadIdx.x;
  int n0 = blockIdx.x * SBN;
  int m0 = blockIdx.y * SBM;
  int ty = tid >> 4, tx = tid & 15;
  float acc[4][4];
#pragma unroll
  for (int i = 0; i < 4; ++i)
#pragma unroll
    for (int j = 0; j < 4; ++j) acc[i][j] = 0.f;

  int lrow = tid >> 2, lkk = (tid & 3) << 2;
  for (int k0 = 0; k0 < K; k0 += SBK) {
    float4 va = make_float4(0.f, 0.f, 0.f, 0.f);
    if (m0 + lrow < M) va = *(const float4*)(A + (size_t)(m0 + lrow) * K + k0 + lkk);
    As[lkk + 0][lrow] = va.x; As[lkk + 1][lrow] = va.y;
    As[lkk + 2][lrow] = va.z; As[lkk + 3][lrow] = va.w;
    float4 vb = *(const float4*)(Wt + (size_t)(n0 + lrow) * K + k0 + lkk);
    Bs[lkk + 0][lrow] = vb.x; Bs[lkk + 1][lrow] = vb.y;
    Bs[lkk + 2][lrow] = vb.z; Bs[lkk + 3][lrow] = vb.w;
    __syncthreads();
#pragma unroll
    for (int k = 0; k < SBK; ++k) {
      float a[4], b[4];
      *(float4*)&a[0] = *(float4*)&As[k][ty * 4];
      *(float4*)&b[0] = *(float4*)&Bs[k][tx * 4];
#pragma unroll
      for (int i = 0; i < 4; ++i)
#pragma unroll
        for (int j = 0; j < 4; ++j) acc[i][j] = fmaf(a[i], b[j], acc[i][j]);
    }
    __syncthreads();
  }
#pragma unroll
  for (int i = 0; i < 4; ++i) {
    int m = m0 + ty * 4 + i;
    if (m >= M) continue;
    int n = n0 + tx * 4;
    float4 v;
    v.x = acc[i][0] + bias[n + 0];
    v.y = acc[i][1] + bias[n + 1];
    v.z = acc[i][2] + bias[n + 2];
    v.w = acc[i][3] + bias[n + 3];
    *(float4*)(C + (size_t)m * N + n) = v;
  }
}

// ------- merged K|V bf16 MFMA NT GEMM over Wkv[1024][512]; BK=32 -------
__global__ __launch_bounds__(256) void gemm_kv_nt(const unsigned short* __restrict__ A,
                                                  const unsigned short* __restrict__ Wkv,
                                                  const float* __restrict__ bk,
                                                  const float* __restrict__ bv,
                                                  unsigned short* __restrict__ K,
                                                  unsigned short* __restrict__ V) {
  __shared__ unsigned short As[128 * 32];
  __shared__ unsigned short Ws[128 * 32];
  int tid = threadIdx.x;
  int wave = tid >> 6, lane = tid & 63;
  int2 t = swz_tiles(gridDim.x);
  int n0 = t.x, m0 = t.y;
  int wm = (wave >> 1) * 64, wn = (wave & 1) * 64;
  f32x4 acc[4][4];
#pragma unroll
  for (int i = 0; i < 4; ++i)
#pragma unroll
    for (int j = 0; j < 4; ++j) acc[i][j] = (f32x4){0.f, 0.f, 0.f, 0.f};

  int rsel = lane & 15;
  int ksel = (lane >> 4) * 8;

  for (int k0 = 0; k0 < CDIM; k0 += 32) {
#pragma unroll
    for (int c = 0; c < 2; ++c) {
      int s = c * 256 + tid;
      int row = s >> 2, ch = s & 3;
      gload16(A + (size_t)(m0 + row) * CDIM + k0 + ch * 8, (void*)(As + (size_t)s * 8));
      gload16(Wkv + (size_t)(n0 + row) * CDIM + k0 + ch * 8, (void*)(Ws + (size_t)s * 8));
    }
    __syncthreads();
    bf16x8 af[4], bfr[4];
#pragma unroll
    for (int mf = 0; mf < 4; ++mf)
      af[mf] = *(const bf16x8*)&As[(wm + mf * 16 + rsel) * 32 + ksel];
#pragma unroll
    for (int nf = 0; nf < 4; ++nf)
      bfr[nf] = *(const bf16x8*)&Ws[(wn + nf * 16 + rsel) * 32 + ksel];
#pragma unroll
    for (int mf = 0; mf < 4; ++mf)
#pragma unroll
      for (int nf = 0; nf < 4; ++nf)
        acc[mf][nf] = __builtin_amdgcn_mfma_f32_16x16x32_bf16(af[mf], bfr[nf], acc[mf][nf], 0, 0, 0);
    __syncthreads();
  }
  const float* bias = (n0 < 512) ? bk : bv;
  unsigned short* C = (n0 < 512) ? K : V;
  int nb = (n0 < 512) ? n0 : n0 - 512;
#pragma unroll
  for (int nf = 0; nf < 4; ++nf) {
    int col = nb + wn + nf * 16 + (lane & 15);
    float bv2 = bias[col];
#pragma unroll
    for (int mf = 0; mf < 4; ++mf) {
      int rbase = m0 + wm + mf * 16 + (lane >> 4) * 4;
#pragma unroll
      for (int i = 0; i < 4; ++i)
        C[(size_t)(rbase + i) * CDIM + col] = f2bf(acc[mf][nf][i] + bv2);
    }
  }
}

// ------- split-bf16 f32-precision NT GEMM; BK=64, XOR swizzle, A-reg prefetch -------
__global__ __launch_bounds__(256) void gemm3_nt(const float* __restrict__ A,
                                                const unsigned short* __restrict__ Whi,
                                                const unsigned short* __restrict__ Wlo,
                                                const float* __restrict__ bias,
                                                float* __restrict__ C) {
  __shared__ unsigned short AsH[128 * 64];
  __shared__ unsigned short AsL[128 * 64];
  __shared__ unsigned short WsH[128 * 64];
  __shared__ unsigned short WsL[128 * 64];
  int tid = threadIdx.x;
  int wave = tid >> 6, lane = tid & 63;
  int2 t = swz_tiles(gridDim.x);
  int n0 = t.x, m0 = t.y;
  int wm = (wave >> 1) * 64, wn = (wave & 1) * 64;
  f32x4 acc[4][4];
#pragma unroll
  for (int i = 0; i < 4; ++i)
#pragma unroll
    for (int j = 0; j < 4; ++j) acc[i][j] = (f32x4){0.f, 0.f, 0.f, 0.f};

  int rsel = lane & 15;
  int kcsel = lane >> 4;

  // A-register prefetch pipeline: load tile k's A f32 before the k-1 MFMA phase
  float4 ar0[4], ar1[4];
#pragma unroll
  for (int c = 0; c < 4; ++c) {
    int s = c * 256 + tid;
    int row = s >> 3, qc = s & 7;
    const float4* src = (const float4*)(A + (size_t)(m0 + row) * CDIM + (size_t)(qc ^ (row & 7)) * 8);
    ar0[c] = src[0];
    ar1[c] = src[1];
  }

  for (int k0 = 0; k0 < CDIM; k0 += 64) {
#pragma unroll
    for (int c = 0; c < 4; ++c) {
      int s = c * 256 + tid;
      int row = s >> 3, ch = s & 7;
      size_t gw = (size_t)(n0 + row) * CDIM + k0 + (size_t)(ch ^ (row & 7)) * 8;
      gload16(Whi + gw, (void*)(WsH + (size_t)s * 8));
      gload16(Wlo + gw, (void*)(WsL + (size_t)s * 8));
    }
    // split prefetched A regs -> LDS (truncated hi + RNE lo)
#pragma unroll
    for (int c = 0; c < 4; ++c) {
      int s = c * 256 + tid;
      float vv[8] = {ar0[c].x, ar0[c].y, ar0[c].z, ar0[c].w,
                     ar1[c].x, ar1[c].y, ar1[c].z, ar1[c].w};
      unsigned int hw[4], lw[4];
#pragma unroll
      for (int j = 0; j < 4; ++j) {
        unsigned int u0 = __float_as_uint(vv[2 * j]);
        unsigned int u1 = __float_as_uint(vv[2 * j + 1]);
        hw[j] = (u0 >> 16) | (u1 & 0xffff0000u);
        float l0 = vv[2 * j] - __uint_as_float(u0 & 0xffff0000u);
        float l1 = vv[2 * j + 1] - __uint_as_float(u1 & 0xffff0000u);
        __hip_bfloat162 l2 = __float22bfloat162_rn(make_float2(l0, l1));
        lw[j] = *reinterpret_cast<unsigned int*>(&l2);
      }
      *(uint4*)&AsH[(size_t)s * 8] = make_uint4(hw[0], hw[1], hw[2], hw[3]);
      *(uint4*)&AsL[(size_t)s * 8] = make_uint4(lw[0], lw[1], lw[2], lw[3]);
    }
    __syncthreads();
    // prefetch next tile's A f32 — latency hides under the MFMA phase below
    if (k0 + 64 < CDIM) {
#pragma unroll
      for (int c = 0; c < 4; ++c) {
        int s = c * 256 + tid;
        int row = s >> 3, qc = s & 7;
        const float4* src = (const float4*)(A + (size_t)(m0 + row) * CDIM + (k0 + 64) + (size_t)(qc ^ (row & 7)) * 8);
        ar0[c] = src[0];
        ar1[c] = src[1];
      }
    }
#pragma unroll
    for (int half = 0; half < 2; ++half) {
      int cb = half * 4 + kcsel;
      bf16x8 ah[4], al[4], bh[4], bl[4];
#pragma unroll
      for (int mf = 0; mf < 4; ++mf) {
        int row = wm + mf * 16 + rsel;
        int off = (row * 8 + (cb ^ (row & 7))) * 8;
        ah[mf] = *(const bf16x8*)&AsH[off];
        al[mf] = *(const bf16x8*)&AsL[off];
      }
#pragma unroll
      for (int nf = 0; nf < 4; ++nf) {
        int row = wn + nf * 16 + rsel;
        int off = (row * 8 + (cb ^ (row & 7))) * 8;
        bh[nf] = *(const bf16x8*)&WsH[off];
        bl[nf] = *(const bf16x8*)&WsL[off];
      }
#pragma unroll
      for (int mf = 0; mf < 4; ++mf)
#pragma unroll
        for (int nf = 0; nf < 4; ++nf) {
          acc[mf][nf] = __builtin_amdgcn_mfma_f32_16x16x32_bf16(ah[mf], bh[nf], acc[mf][nf], 0, 0, 0);
          acc[mf][nf] = __builtin_amdgcn_mfma_f32_16x16x32_bf16(ah[mf], bl[nf], acc[mf][nf], 0, 0, 0);
          acc[mf][nf] = __builtin_amdgcn_mfma_f32_16x16x32_bf16(al[mf], bh[nf], acc[mf][nf], 0, 0, 0);
        }
    }
    __syncthreads();
  }
#pragma unroll
  for (int nf = 0; nf < 4; ++nf) {
    int col = n0 + wn + nf * 16 + (lane & 15);
    float bvs = bias[col];
#pragma unroll
    for (int mf = 0; mf < 4; ++mf) {
      int rbase = m0 + wm + mf * 16 + (lane >> 4) * 4;
#pragma unroll
      for (int i = 0; i < 4; ++i)
        C[(size_t)(rbase + i) * CDIM + col] = acc[mf][nf][i] + bvs;
    }
  }
}

// ------- ONE-SHOT weight prep -------
__global__ __launch_bounds__(256) void conv_all(const float* __restrict__ w_off_proj,
                                                const float* __restrict__ w_k,
                                                const float* __restrict__ w_v,
                                                const float* __restrict__ w_dw,
                                                unsigned short* __restrict__ wphi,
                                                unsigned short* __restrict__ wplo,
                                                unsigned short* __restrict__ wkv,
                                                float* __restrict__ wdwT) {
  int blk = blockIdx.x, tid = threadIdx.x;
  if (blk < 256) {
    int i = blk * 256 + tid;
    float4 v = ((const float4*)w_off_proj)[i];
    ushort4 h, l;
    h.x = f2bf(v.x); l.x = f2bf(v.x - bf2f(h.x));
    h.y = f2bf(v.y); l.y = f2bf(v.y - bf2f(h.y));
    h.z = f2bf(v.z); l.z = f2bf(v.z - bf2f(h.z));
    h.w = f2bf(v.w); l.w = f2bf(v.w - bf2f(h.w));
    ((ushort4*)wphi)[i] = h;
    ((ushort4*)wplo)[i] = l;
  } else if (blk < 512) {
    int i = (blk - 256) * 256 + tid;
    float4 v = ((const float4*)w_k)[i];
    ushort4 o;
    o.x = f2bf(v.x); o.y = f2bf(v.y); o.z = f2bf(v.z); o.w = f2bf(v.w);
    ((ushort4*)wkv)[i] = o;
  } else if (blk < 768) {
    int i = (blk - 512) * 256 + tid;
    float4 v = ((const float4*)w_v)[i];
    ushort4 o;
    o.x = f2bf(v.x); o.y = f2bf(v.y); o.z = f2bf(v.z); o.w = f2bf(v.w);
    ((ushort4*)(wkv + (size_t)CDIM * CDIM))[i] = o;
  } else {
    int id = (blk - 768) * 256 + tid;
    if (id < 9 * CDIM) wdwT[id] = w_dw[(id & 511) * 9 + (id >> 9)];
  }
}

// ------- FUSED: depthwise3x3 + LN + GELU(fast erf) + offset head + gather -> bf16 xs -------
__global__ __launch_bounds__(512) void offset_gather_kernel(
    const float* __restrict__ t0, const float* __restrict__ x,
    const float* __restrict__ w_dwT, const float* __restrict__ b_dw,
    const float* __restrict__ ln_g, const float* __restrict__ ln_b,
    const float* __restrict__ w_off, unsigned short* __restrict__ xs) {
  __shared__ float4 sten[18 * 128];
  __shared__ float redA[8], redB[8], redC[8], redD[8];
  __shared__ int4 sid[4];
  __shared__ float4 swt[4];

  int blk = blockIdx.x;
  int b = blk >> 10, rem = blk & 1023;
  int h = rem >> 4, w0 = (rem & 15) << 2;
  int t = threadIdx.x;
  const float* base = t0 + (size_t)b * HWSZ * CDIM;

  for (int s = t; s < 18 * 128; s += 512) {
    int ps = s >> 7, q = s & 127;
    int r = ps / 6, cs = ps - r * 6;
    int hh = h + r - 1, ww = w0 + cs - 1;
    if ((unsigned)hh < 64u && (unsigned)ww < 64u) {
      gload16(base + (size_t)(hh * 64 + ww) * CDIM + 4 * q, (void*)(sten + s));
    } else {
      sten[s] = make_float4(0.f, 0.f, 0.f, 0.f);
    }
  }
  __syncthreads();

  int p = t >> 7;
  int l128 = t & 127;
  float4 acc = ((const float4*)b_dw)[l128];
#pragma unroll
  for (int r = 0; r < 3; ++r)
#pragma unroll
    for (int dxi = 0; dxi < 3; ++dxi) {
      float4 w4 = ((const float4*)(w_dwT + (size_t)(r * 3 + dxi) * CDIM))[l128];
      float4 v = sten[(r * 6 + p + dxi) * 128 + l128];
      acc.x = fmaf(v.x, w4.x, acc.x);
      acc.y = fmaf(v.y, w4.y, acc.y);
      acc.z = fmaf(v.z, w4.z, acc.z);
      acc.w = fmaf(v.w, w4.w, acc.w);
    }
  float s = acc.x + acc.y + acc.z + acc.w;
  float s2 = acc.x * acc.x + acc.y * acc.y + acc.z * acc.z + acc.w * acc.w;
#pragma unroll
  for (int off = 32; off; off >>= 1) {
    s += __shfl_xor(s, off, 64);
    s2 += __shfl_xor(s2, off, 64);
  }
  int wv = t >> 6, lane = t & 63;
  if (!lane) { redA[wv] = s; redB[wv] = s2; }
  __syncthreads();
  s = redA[2 * p] + redA[2 * p + 1];
  s2 = redB[2 * p] + redB[2 * p + 1];
  float mean = s * (1.f / 512.f);
  float var = s2 * (1.f / 512.f) - mean * mean;
  float inv = 1.f / sqrtf(var + 1e-5f);

  float4 g4 = ((const float4*)ln_g)[l128];
  float4 lb4 = ((const float4*)ln_b)[l128];
  float4 wy4 = ((const float4*)w_off)[l128];
  float4 wx4 = ((const float4*)(w_off + CDIM))[l128];
  float4 xn;
  xn.x = (acc.x - mean) * inv * g4.x + lb4.x;
  xn.y = (acc.y - mean) * inv * g4.y + lb4.y;
  xn.z = (acc.z - mean) * inv * g4.z + lb4.z;
  xn.w = (acc.w - mean) * inv * g4.w + lb4.w;
  float4 ge;
  ge.x = gelu(xn.x);
  ge.y = gelu(xn.y);
  ge.z = gelu(xn.z);
  ge.w = gelu(xn.w);
  float oy = ge.x * wy4.x + ge.y * wy4.y + ge.z * wy4.z + ge.w * wy4.w;
  float ox = ge.x * wx4.x + ge.y * wx4.y + ge.z * wx4.z + ge.w * wx4.w;
#pragma unroll
  for (int off = 32; off; off >>= 1) {
    oy += __shfl_xor(oy, off, 64);
    ox += __shfl_xor(ox, off, 64);
  }
  if (!lane) { redC[wv] = oy; redD[wv] = ox; }
  __syncthreads();
  if (l128 == 0) {
    oy = redC[2 * p] + redC[2 * p + 1];
    ox = redD[2 * p] + redD[2 * p + 1];
    int wcol = w0 + p;
    float ry = ((float)h + 0.5f) / 64.f * 2.f - 1.f;
    float rx = ((float)wcol + 0.5f) / 64.f * 2.f - 1.f;
    float py = tanhf(oy + ry);
    float px = tanhf(ox + rx);
    float fx = (px + 1.f) * 0.5f * 63.f;
    float fy = (py + 1.f) * 0.5f * 63.f;
    float fx0 = floorf(fx), fy0 = floorf(fy);
    float fx1 = fx0 + 1.f, fy1 = fy0 + 1.f;
    float wx1 = fx - fx0, wx0 = fx1 - fx;
    float wy1 = fy - fy0, wy0 = fy1 - fy;
    float m00 = (fy0 >= 0.f && fy0 <= 63.f && fx0 >= 0.f && fx0 <= 63.f) ? 1.f : 0.f;
    float m01 = (fy0 >= 0.f && fy0 <= 63.f && fx1 >= 0.f && fx1 <= 63.f) ? 1.f : 0.f;
    float m10 = (fy1 >= 0.f && fy1 <= 63.f && fx0 >= 0.f && fx0 <= 63.f) ? 1.f : 0.f;
    float m11 = (fy1 >= 0.f && fy1 <= 63.f && fx1 >= 0.f && fx1 <= 63.f) ? 1.f : 0.f;
    int xi0 = min(max((int)fx0, 0), 63), xi1 = min(max((int)fx1, 0), 63);
    int yi0 = min(max((int)fy0, 0), 63), yi1 = min(max((int)fy1, 0), 63);
    sid[p] = make_int4(yi0 * 64 + xi0, yi0 * 64 + xi1, yi1 * 64 + xi0, yi1 * 64 + xi1);
    swt[p] = make_float4(wx0 * wy0 * m00, wx1 * wy0 * m01, wx0 * wy1 * m10, wx1 * wy1 * m11);
  }
  __syncthreads();
  int4 id = sid[p];
  float4 wt = swt[p];
  const float* xb = x + (size_t)b * HWSZ * CDIM;
  float4 a = ((const float4*)(xb + (size_t)id.x * CDIM))[l128];
  float4 bb = ((const float4*)(xb + (size_t)id.y * CDIM))[l128];
  float4 cc = ((const float4*)(xb + (size_t)id.z * CDIM))[l128];
  float4 dd = ((const float4*)(xb + (size_t)id.w * CDIM))[l128];
  ushort4 o;
  o.x = f2bf(a.x * wt.x + bb.x * wt.y + cc.x * wt.z + dd.x * wt.w);
  o.y = f2bf(a.y * wt.x + bb.y * wt.y + cc.y * wt.z + dd.y * wt.w);
  o.z = f2bf(a.z * wt.x + bb.z * wt.y + cc.z * wt.z + dd.z * wt.w);
  o.w = f2bf(a.w * wt.x + bb.w * wt.y + cc.w * wt.z + dd.w * wt.w);
  size_t posg = (size_t)b * HWSZ + h * 64 + w0 + p;
  *(ushort4*)(xs + posg * CDIM + l128 * 4) = o;
}

// ------- split-L attention v2: one block serves TWO queries sharing a K/V slab -------
__global__ __launch_bounds__(256) void attn_split_kernel(const float* __restrict__ qh,
                                                         const unsigned short* __restrict__ kk,
                                                         const unsigned short* __restrict__ vv,
                                                         float* __restrict__ pm,
                                                         float* __restrict__ ps,
                                                         float* __restrict__ po) {
  __shared__ float sc0[128], sc1[128];
  __shared__ float qs0[64], qs1[64];
  __shared__ float red0[4], red1[4];
  __shared__ float part0[4][64], part1[4][64];
  int bid = blockIdx.x;
  int h = bid & 7;
  int bs = bid >> 3;
  int b = bs >> 5, s = bs & 31;
  int l0 = s << 7;
  int task0 = b * 33;
  int task1 = b * 33 + s + 1;
  int tid = threadIdx.x;
  if (tid < 64) qs0[tid] = qh[(size_t)task0 * CDIM + h * 64 + tid];
  else if (tid < 128) qs1[tid - 64] = qh[(size_t)task1 * CDIM + h * 64 + (tid - 64)];
  __syncthreads();

  const unsigned short* kb = kk + ((size_t)b * HWSZ + l0) * CDIM + h * 64;
  float lmax0 = -INFINITY, lmax1 = -INFINITY;
  if (tid < 128) {
    const uint4* kr = (const uint4*)(kb + (size_t)tid * CDIM);
    float sv0 = 0.f, sv1 = 0.f;
#pragma unroll
    for (int c = 0; c < 8; ++c) {
      uint4 kv = kr[c];
      float k0 = __uint_as_float(kv.x << 16);
      float k1 = __uint_as_float(kv.x & 0xffff0000u);
      float k2 = __uint_as_float(kv.y << 16);
      float k3 = __uint_as_float(kv.y & 0xffff0000u);
      float k4 = __uint_as_float(kv.z << 16);
      float k5 = __uint_as_float(kv.z & 0xffff0000u);
      float k6 = __uint_as_float(kv.w << 16);
      float k7 = __uint_as_float(kv.w & 0xffff0000u);
      sv0 = fmaf(k0, qs0[8 * c + 0], sv0); sv1 = fmaf(k0, qs1[8 * c + 0], sv1);
      sv0 = fmaf(k1, qs0[8 * c + 1], sv0); sv1 = fmaf(k1, qs1[8 * c + 1], sv1);
      sv0 = fmaf(k2, qs0[8 * c + 2], sv0); sv1 = fmaf(k2, qs1[8 * c + 2], sv1);
      sv0 = fmaf(k3, qs0[8 * c + 3], sv0); sv1 = fmaf(k3, qs1[8 * c + 3], sv1);
      sv0 = fmaf(k4, qs0[8 * c + 4], sv0); sv1 = fmaf(k4, qs1[8 * c + 4], sv1);
      sv0 = fmaf(k5, qs0[8 * c + 5], sv0); sv1 = fmaf(k5, qs1[8 * c + 5], sv1);
      sv0 = fmaf(k6, qs0[8 * c + 6], sv0); sv1 = fmaf(k6, qs1[8 * c + 6], sv1);
      sv0 = fmaf(k7, qs0[8 * c + 7], sv0); sv1 = fmaf(k7, qs1[8 * c + 7], sv1);
    }
    sv0 *= 0.125f; sv1 *= 0.125f;
    sc0[tid] = sv0; sc1[tid] = sv1;
    lmax0 = sv0; lmax1 = sv1;
  }
#pragma unroll
  for (int off = 32; off; off >>= 1) {
    lmax0 = fmaxf(lmax0, __shfl_xor(lmax0, off, 64));
    lmax1 = fmaxf(lmax1, __shfl_xor(lmax1, off, 64));
  }
  if (!(tid & 63)) { red0[tid >> 6] = lmax0; red1[tid >> 6] = lmax1; }
  __syncthreads();
  lmax0 = fmaxf(fmaxf(red0[0], red0[1]), fmaxf(red0[2], red0[3]));
  lmax1 = fmaxf(fmaxf(red1[0], red1[1]), fmaxf(red1[2], red1[3]));
  __syncthreads();

  float ls0 = 0.f, ls1 = 0.f;
  if (tid < 128) {
    float e0 = expf(sc0[tid] - lmax0);
    float e1 = expf(sc1[tid] - lmax1);
    sc0[tid] = e0; sc1[tid] = e1;
    ls0 = e0; ls1 = e1;
  }
#pragma unroll
  for (int off = 32; off; off >>= 1) {
    ls0 += __shfl_xor(ls0, off, 64);
    ls1 += __shfl_xor(ls1, off, 64);
  }
  if (!(tid & 63)) { red0[tid >> 6] = ls0; red1[tid >> 6] = ls1; }
  __syncthreads();
  float tsum0 = red0[0] + red0[1] + red0[2] + red0[3];
  float tsum1 = red1[0] + red1[1] + red1[2] + red1[3];

  int ch = tid & 63, g = tid >> 6;
  const unsigned short* vb = vv + ((size_t)b * HWSZ + l0) * CDIM + h * 64 + ch;
  float o0 = 0.f, o1 = 0.f;
#pragma unroll 4
  for (int l = g; l < 128; l += 4) {
    float vvv = bf2f(vb[(size_t)l * CDIM]);
    o0 = fmaf(sc0[l], vvv, o0);
    o1 = fmaf(sc1[l], vvv, o1);
  }
  part0[g][ch] = o0;
  part1[g][ch] = o1;
  __syncthreads();
  if (tid < 64) {
    float r0 = part0[0][tid] + part0[1][tid] + part0[2][tid] + part0[3][tid];
    float r1 = part1[0][tid] + part1[1][tid] + part1[2][tid] + part1[3][tid];
    int bid0 = (b * 64 + s) * 8 + h;
    int bid1 = (b * 64 + 32 + s) * 8 + h;
    po[(size_t)bid0 * 64 + tid] = r0;
    po[(size_t)bid1 * 64 + tid] = r1;
    if (tid == 0) {
      pm[bid0] = lmax0; ps[bid0] = tsum0;
      pm[bid1] = lmax1; ps[bid1] = tsum1;
    }
  }
}

// ------- merge partials (LSE combine) -------
__global__ __launch_bounds__(64) void attn_reduce_kernel(const float* __restrict__ pm,
                                                         const float* __restrict__ ps,
                                                         const float* __restrict__ po,
                                                         float* __restrict__ oo) {
  int bid = blockIdx.x;
  int h = bid & 7, task = bid >> 3;
  int b = task / 33, qidx = task - b * 33;
  int sbase = (qidx == 0) ? 0 : 31 + qidx;
  int ns = (qidx == 0) ? 32 : 1;
  int t = threadIdx.x;
  float mg = -INFINITY;
  for (int i = 0; i < ns; ++i) mg = fmaxf(mg, pm[((size_t)(b * 64 + sbase + i)) * 8 + h]);
  float tot = 0.f, o = 0.f;
  for (int i = 0; i < ns; ++i) {
    size_t pi = ((size_t)(b * 64 + sbase + i)) * 8 + h;
    float w = expf(pm[pi] - mg);
    tot = fmaf(ps[pi], w, tot);
    o = fmaf(po[pi * 64 + t], w, o);
  }
  oo[(size_t)task * CDIM + h * 64 + t] = o / tot;
}

extern "C" void kernel_launch(void* const* d_in, const int* in_sizes, int n_in,
                              void* d_out, int out_size, void* d_ws, size_t ws_size,
                              hipStream_t stream) {
  const float* q          = (const float*)d_in[0];
  const float* x          = (const float*)d_in[1];
  const float* w_off_proj = (const float*)d_in[2];
  const float* b_off_proj = (const float*)d_in[3];
  const float* w_dw       = (const float*)d_in[4];
  const float* b_dw       = (const float*)d_in[5];
  const float* ln_g       = (const float*)d_in[6];
  const float* ln_b       = (const float*)d_in[7];
  const float* w_off      = (const float*)d_in[8];
  const float* w_q        = (const float*)d_in[9];
  const float* b_q        = (const float*)d_in[10];
  const float* w_k        = (const float*)d_in[11];
  const float* b_k        = (const float*)d_in[12];
  const float* w_v        = (const float*)d_in[13];
  const float* b_v        = (const float*)d_in[14];
  const float* w_o        = (const float*)d_in[15];
  const float* b_o        = (const float*)d_in[16];

  char* ws = (char*)d_ws;
  size_t off = 0;
  const size_t NBIG = (size_t)BATCH * HWSZ * CDIM;
  const int NSPLIT = BATCH * 64 * 8;
  float* t0    = (float*)(ws + off);                  off += NBIG * 4;   // 134 MB
  unsigned short* xs_bf = (unsigned short*)(ws + off); off += NBIG * 2;
  unsigned short* k_bf  = (unsigned short*)(ws + off); off += NBIG * 2;
  unsigned short* v_bf  = (unsigned short*)(ws + off); off += NBIG * 2;
  unsigned short* wphi = (unsigned short*)(ws + off);  off += (size_t)CDIM * CDIM * 2;
  unsigned short* wplo = (unsigned short*)(ws + off);  off += (size_t)CDIM * CDIM * 2;
  unsigned short* wkv_bf = (unsigned short*)(ws + off); off += (size_t)2 * CDIM * CDIM * 2;
  float* w_dwT = (float*)(ws + off);                  off += (size_t)9 * CDIM * 4;
  float* qh    = (float*)(ws + off);                  off += (size_t)BATCH * NQTOT * CDIM * 4;
  float* o_all = (float*)(ws + off);                  off += (size_t)BATCH * NQTOT * CDIM * 4;
  float* pm    = (float*)(ws + off);                  off += (size_t)NSPLIT * 4;
  float* ps    = (float*)(ws + off);                  off += (size_t)NSPLIT * 4;
  float* po    = (float*)(ws + off);                  off += (size_t)NSPLIT * 64 * 4;

  const int Mbig = BATCH * HWSZ;  // 65536
  const int Msm  = BATCH * NQTOT; // 528
  dim3 gSm2(CDIM / SBN, (Msm + SBM - 1) / SBM);   // (8, 9)
  dim3 gMf(CDIM / 128, Mbig / 128);
  dim3 gKV(2 * CDIM / 128, Mbig / 128);

  // 0) all weight conversions in one launch
  conv_all<<<786, 256, 0, stream>>>(w_off_proj, w_k, w_v, w_dw, wphi, wplo, wkv_bf, w_dwT);
  // 1) t0 = x @ w_off_proj^T + b ; BK=64, swizzled, split, A-reg prefetch pipeline
  gemm3_nt<<<gMf, 256, 0, stream>>>(x, wphi, wplo, b_off_proj, t0);
  // 2) fused depthwise+LN+GELU(fast erf)+offset+gather -> bf16 xs
  offset_gather_kernel<<<Mbig / 4, 512, 0, stream>>>(t0, x, w_dwT, b_dw, ln_g, ln_b, w_off, xs_bf);
  // 3) merged K|V projection; BK=32
  gemm_kv_nt<<<gKV, 256, 0, stream>>>(xs_bf, wkv_bf, b_k, b_v, k_bf, v_bf);
  // 4) Q projection (64x64 tiles)
  gemm_sm_nt<<<gSm2, 256, 0, stream>>>(q, w_q, b_q, qh, Msm);
  // 5) dual-query split-L attention + LSE merge
  attn_split_kernel<<<NSPLIT / 2, 256, 0, stream>>>(qh, k_bf, v_bf, pm, ps, po);
  attn_reduce_kernel<<<Msm * 8, 64, 0, stream>>>(pm, ps, po, o_all);
  // 6) output projection -> d_out (64x64 tiles)
  gemm_sm_nt<<<gSm2, 256, 0, stream>>>(o_all, w_o, b_o, (float*)d_out, Msm);
}

// Round 23
// 458.628 us; speedup vs baseline: 1.3368x; 1.0204x over previous
//
#include <hip/hip_runtime.h>
#include <hip/hip_bf16.h>

#define CDIM 512
#define HWSZ 4096
#define BATCH 16
#define NQTOT 33

typedef short bf16x8 __attribute__((ext_vector_type(8)));
typedef float f32x4 __attribute__((ext_vector_type(4)));

__device__ __forceinline__ unsigned short f2bf(float f) {
  unsigned int u = __float_as_uint(f);
  u += 0x7fffu + ((u >> 16) & 1u);   // round-to-nearest-even
  return (unsigned short)(u >> 16);
}
__device__ __forceinline__ float bf2f(unsigned short s) {
  return __uint_as_float((unsigned int)s << 16);
}
__device__ __forceinline__ void gload16(const void* g, void* l) {
  __builtin_amdgcn_global_load_lds((const __attribute__((address_space(1))) void*)g,
                                   (__attribute__((address_space(3))) void*)l, 16, 0, 0);
}
// fast erf: Abramowitz-Stegun 7.1.26, |abs err| <= 1.5e-7
__device__ __forceinline__ float fast_erf(float x) {
  float ax = fabsf(x);
  float t = __builtin_amdgcn_rcpf(fmaf(0.3275911f, ax, 1.f));
  float p = fmaf(t, 1.061405429f, -1.453152027f);
  p = fmaf(t, p, 1.421413741f);
  p = fmaf(t, p, -0.284496736f);
  p = fmaf(t, p, 0.254829592f);
  p = p * t;
  float e = 1.f - p * __expf(-ax * ax);
  return copysignf(e, x);
}
__device__ __forceinline__ float gelu(float x) {
  return x * 0.5f * (1.f + fast_erf(x * 0.70710678118654752f));
}
// XCD-aware bijective swizzle (nwg % 8 == 0)
__device__ __forceinline__ int2 swz_tiles(int nwgx) {
  int nwg = gridDim.x * gridDim.y;
  int l = blockIdx.y * gridDim.x + blockIdx.x;
  int w = (l & 7) * (nwg >> 3) + (l >> 3);
  return make_int2((w % nwgx) * 128, (w / nwgx) * 128);  // (n0, m0)
}
// Lessons: (r12) never break global coalescing for LDS conflicts; (r17) BK=64
// only pays when a per-phase VALU stream overlaps MFMA; (r19) small-M GEMMs
// need small tiles; (r21) count real insts, not named ops; (r23) wave-per-row
// reductions remove barrier/LDS round trips.

// ------- small-M f32 NT GEMM: 64x64 tiles for occupancy; C = A*W^T + bias -------
#define SBM 64
#define SBN 64
#define SBK 16

__global__ __launch_bounds__(256) void gemm_sm_nt(const float* __restrict__ A,
                                                  const float* __restrict__ Wt,
                                                  const float* __restrict__ bias,
                                                  float* __restrict__ C, int M) {
  const int K = CDIM, N = CDIM;
  __shared__ float As[SBK][SBM + 4];
  __shared__ float Bs[SBK][SBN + 4];
  int tid = threadIdx.x;
  int n0 = blockIdx.x * SBN;
  int m0 = blockIdx.y * SBM;
  int ty = tid >> 4, tx = tid & 15;
  float acc[4][4];
#pragma unroll
  for (int i = 0; i < 4; ++i)
#pragma unroll
    for (int j = 0; j < 4; ++j) acc[i][j] = 0.f;

  int lrow = tid >> 2, lkk = (tid & 3) << 2;
  for (int k0 = 0; k0 < K; k0 += SBK) {
    float4 va = make_float4(0.f, 0.f, 0.f, 0.f);
    if (m0 + lrow < M) va = *(const float4*)(A + (size_t)(m0 + lrow) * K + k0 + lkk);
    As[lkk + 0][lrow] = va.x; As[lkk + 1][lrow] = va.y;
    As[lkk + 2][lrow] = va.z; As[lkk + 3][lrow] = va.w;
    float4 vb = *(const float4*)(Wt + (size_t)(n0 + lrow) * K + k0 + lkk);
    Bs[lkk + 0][lrow] = vb.x; Bs[lkk + 1][lrow] = vb.y;
    Bs[lkk + 2][lrow] = vb.z; Bs[lkk + 3][lrow] = vb.w;
    __syncthreads();
#pragma unroll
    for (int k = 0; k < SBK; ++k) {
      float a[4], b[4];
      *(float4*)&a[0] = *(float4*)&As[k][ty * 4];
      *(float4*)&b[0] = *(float4*)&Bs[k][tx * 4];
#pragma unroll
      for (int i = 0; i < 4; ++i)
#pragma unroll
        for (int j = 0; j < 4; ++j) acc[i][j] = fmaf(a[i], b[j], acc[i][j]);
    }
    __syncthreads();
  }
#pragma unroll
  for (int i = 0; i < 4; ++i) {
    int m = m0 + ty * 4 + i;
    if (m >= M) continue;
    int n = n0 + tx * 4;
    float4 v;
    v.x = acc[i][0] + bias[n + 0];
    v.y = acc[i][1] + bias[n + 1];
    v.z = acc[i][2] + bias[n + 2];
    v.w = acc[i][3] + bias[n + 3];
    *(float4*)(C + (size_t)m * N + n) = v;
  }
}

// ------- merged K|V bf16 MFMA NT GEMM over Wkv[1024][512]; BK=32 -------
__global__ __launch_bounds__(256) void gemm_kv_nt(const unsigned short* __restrict__ A,
                                                  const unsigned short* __restrict__ Wkv,
                                                  const float* __restrict__ bk,
                                                  const float* __restrict__ bv,
                                                  unsigned short* __restrict__ K,
                                                  unsigned short* __restrict__ V) {
  __shared__ unsigned short As[128 * 32];
  __shared__ unsigned short Ws[128 * 32];
  int tid = threadIdx.x;
  int wave = tid >> 6, lane = tid & 63;
  int2 t = swz_tiles(gridDim.x);
  int n0 = t.x, m0 = t.y;
  int wm = (wave >> 1) * 64, wn = (wave & 1) * 64;
  f32x4 acc[4][4];
#pragma unroll
  for (int i = 0; i < 4; ++i)
#pragma unroll
    for (int j = 0; j < 4; ++j) acc[i][j] = (f32x4){0.f, 0.f, 0.f, 0.f};

  int rsel = lane & 15;
  int ksel = (lane >> 4) * 8;

  for (int k0 = 0; k0 < CDIM; k0 += 32) {
#pragma unroll
    for (int c = 0; c < 2; ++c) {
      int s = c * 256 + tid;
      int row = s >> 2, ch = s & 3;
      gload16(A + (size_t)(m0 + row) * CDIM + k0 + ch * 8, (void*)(As + (size_t)s * 8));
      gload16(Wkv + (size_t)(n0 + row) * CDIM + k0 + ch * 8, (void*)(Ws + (size_t)s * 8));
    }
    __syncthreads();
    bf16x8 af[4], bfr[4];
#pragma unroll
    for (int mf = 0; mf < 4; ++mf)
      af[mf] = *(const bf16x8*)&As[(wm + mf * 16 + rsel) * 32 + ksel];
#pragma unroll
    for (int nf = 0; nf < 4; ++nf)
      bfr[nf] = *(const bf16x8*)&Ws[(wn + nf * 16 + rsel) * 32 + ksel];
#pragma unroll
    for (int mf = 0; mf < 4; ++mf)
#pragma unroll
      for (int nf = 0; nf < 4; ++nf)
        acc[mf][nf] = __builtin_amdgcn_mfma_f32_16x16x32_bf16(af[mf], bfr[nf], acc[mf][nf], 0, 0, 0);
    __syncthreads();
  }
  const float* bias = (n0 < 512) ? bk : bv;
  unsigned short* C = (n0 < 512) ? K : V;
  int nb = (n0 < 512) ? n0 : n0 - 512;
#pragma unroll
  for (int nf = 0; nf < 4; ++nf) {
    int col = nb + wn + nf * 16 + (lane & 15);
    float bv2 = bias[col];
#pragma unroll
    for (int mf = 0; mf < 4; ++mf) {
      int rbase = m0 + wm + mf * 16 + (lane >> 4) * 4;
#pragma unroll
      for (int i = 0; i < 4; ++i)
        C[(size_t)(rbase + i) * CDIM + col] = f2bf(acc[mf][nf][i] + bv2);
    }
  }
}

// ------- split-bf16 f32-precision NT GEMM; BK=64, XOR swizzle, A-reg prefetch -------
__global__ __launch_bounds__(256) void gemm3_nt(const float* __restrict__ A,
                                                const unsigned short* __restrict__ Whi,
                                                const unsigned short* __restrict__ Wlo,
                                                const float* __restrict__ bias,
                                                float* __restrict__ C) {
  __shared__ unsigned short AsH[128 * 64];
  __shared__ unsigned short AsL[128 * 64];
  __shared__ unsigned short WsH[128 * 64];
  __shared__ unsigned short WsL[128 * 64];
  int tid = threadIdx.x;
  int wave = tid >> 6, lane = tid & 63;
  int2 t = swz_tiles(gridDim.x);
  int n0 = t.x, m0 = t.y;
  int wm = (wave >> 1) * 64, wn = (wave & 1) * 64;
  f32x4 acc[4][4];
#pragma unroll
  for (int i = 0; i < 4; ++i)
#pragma unroll
    for (int j = 0; j < 4; ++j) acc[i][j] = (f32x4){0.f, 0.f, 0.f, 0.f};

  int rsel = lane & 15;
  int kcsel = lane >> 4;

  float4 ar0[4], ar1[4];
#pragma unroll
  for (int c = 0; c < 4; ++c) {
    int s = c * 256 + tid;
    int row = s >> 3, qc = s & 7;
    const float4* src = (const float4*)(A + (size_t)(m0 + row) * CDIM + (size_t)(qc ^ (row & 7)) * 8);
    ar0[c] = src[0];
    ar1[c] = src[1];
  }

  for (int k0 = 0; k0 < CDIM; k0 += 64) {
#pragma unroll
    for (int c = 0; c < 4; ++c) {
      int s = c * 256 + tid;
      int row = s >> 3, ch = s & 7;
      size_t gw = (size_t)(n0 + row) * CDIM + k0 + (size_t)(ch ^ (row & 7)) * 8;
      gload16(Whi + gw, (void*)(WsH + (size_t)s * 8));
      gload16(Wlo + gw, (void*)(WsL + (size_t)s * 8));
    }
#pragma unroll
    for (int c = 0; c < 4; ++c) {
      int s = c * 256 + tid;
      float vv[8] = {ar0[c].x, ar0[c].y, ar0[c].z, ar0[c].w,
                     ar1[c].x, ar1[c].y, ar1[c].z, ar1[c].w};
      unsigned int hw[4], lw[4];
#pragma unroll
      for (int j = 0; j < 4; ++j) {
        unsigned int u0 = __float_as_uint(vv[2 * j]);
        unsigned int u1 = __float_as_uint(vv[2 * j + 1]);
        hw[j] = (u0 >> 16) | (u1 & 0xffff0000u);
        float l0 = vv[2 * j] - __uint_as_float(u0 & 0xffff0000u);
        float l1 = vv[2 * j + 1] - __uint_as_float(u1 & 0xffff0000u);
        __hip_bfloat162 l2 = __float22bfloat162_rn(make_float2(l0, l1));
        lw[j] = *reinterpret_cast<unsigned int*>(&l2);
      }
      *(uint4*)&AsH[(size_t)s * 8] = make_uint4(hw[0], hw[1], hw[2], hw[3]);
      *(uint4*)&AsL[(size_t)s * 8] = make_uint4(lw[0], lw[1], lw[2], lw[3]);
    }
    __syncthreads();
    if (k0 + 64 < CDIM) {
#pragma unroll
      for (int c = 0; c < 4; ++c) {
        int s = c * 256 + tid;
        int row = s >> 3, qc = s & 7;
        const float4* src = (const float4*)(A + (size_t)(m0 + row) * CDIM + (k0 + 64) + (size_t)(qc ^ (row & 7)) * 8);
        ar0[c] = src[0];
        ar1[c] = src[1];
      }
    }
#pragma unroll
    for (int half = 0; half < 2; ++half) {
      int cb = half * 4 + kcsel;
      bf16x8 ah[4], al[4], bh[4], bl[4];
#pragma unroll
      for (int mf = 0; mf < 4; ++mf) {
        int row = wm + mf * 16 + rsel;
        int off = (row * 8 + (cb ^ (row & 7))) * 8;
        ah[mf] = *(const bf16x8*)&AsH[off];
        al[mf] = *(const bf16x8*)&AsL[off];
      }
#pragma unroll
      for (int nf = 0; nf < 4; ++nf) {
        int row = wn + nf * 16 + rsel;
        int off = (row * 8 + (cb ^ (row & 7))) * 8;
        bh[nf] = *(const bf16x8*)&WsH[off];
        bl[nf] = *(const bf16x8*)&WsL[off];
      }
#pragma unroll
      for (int mf = 0; mf < 4; ++mf)
#pragma unroll
        for (int nf = 0; nf < 4; ++nf) {
          acc[mf][nf] = __builtin_amdgcn_mfma_f32_16x16x32_bf16(ah[mf], bh[nf], acc[mf][nf], 0, 0, 0);
          acc[mf][nf] = __builtin_amdgcn_mfma_f32_16x16x32_bf16(ah[mf], bl[nf], acc[mf][nf], 0, 0, 0);
          acc[mf][nf] = __builtin_amdgcn_mfma_f32_16x16x32_bf16(al[mf], bh[nf], acc[mf][nf], 0, 0, 0);
        }
    }
    __syncthreads();
  }
#pragma unroll
  for (int nf = 0; nf < 4; ++nf) {
    int col = n0 + wn + nf * 16 + (lane & 15);
    float bvs = bias[col];
#pragma unroll
    for (int mf = 0; mf < 4; ++mf) {
      int rbase = m0 + wm + mf * 16 + (lane >> 4) * 4;
#pragma unroll
      for (int i = 0; i < 4; ++i)
        C[(size_t)(rbase + i) * CDIM + col] = acc[mf][nf][i] + bvs;
    }
  }
}

// ------- ONE-SHOT weight prep -------
__global__ __launch_bounds__(256) void conv_all(const float* __restrict__ w_off_proj,
                                                const float* __restrict__ w_k,
                                                const float* __restrict__ w_v,
                                                const float* __restrict__ w_dw,
                                                unsigned short* __restrict__ wphi,
                                                unsigned short* __restrict__ wplo,
                                                unsigned short* __restrict__ wkv,
                                                float* __restrict__ wdwT) {
  int blk = blockIdx.x, tid = threadIdx.x;
  if (blk < 256) {
    int i = blk * 256 + tid;
    float4 v = ((const float4*)w_off_proj)[i];
    ushort4 h, l;
    h.x = f2bf(v.x); l.x = f2bf(v.x - bf2f(h.x));
    h.y = f2bf(v.y); l.y = f2bf(v.y - bf2f(h.y));
    h.z = f2bf(v.z); l.z = f2bf(v.z - bf2f(h.z));
    h.w = f2bf(v.w); l.w = f2bf(v.w - bf2f(h.w));
    ((ushort4*)wphi)[i] = h;
    ((ushort4*)wplo)[i] = l;
  } else if (blk < 512) {
    int i = (blk - 256) * 256 + tid;
    float4 v = ((const float4*)w_k)[i];
    ushort4 o;
    o.x = f2bf(v.x); o.y = f2bf(v.y); o.z = f2bf(v.z); o.w = f2bf(v.w);
    ((ushort4*)wkv)[i] = o;
  } else if (blk < 768) {
    int i = (blk - 512) * 256 + tid;
    float4 v = ((const float4*)w_v)[i];
    ushort4 o;
    o.x = f2bf(v.x); o.y = f2bf(v.y); o.z = f2bf(v.z); o.w = f2bf(v.w);
    ((ushort4*)(wkv + (size_t)CDIM * CDIM))[i] = o;
  } else {
    int id = (blk - 768) * 256 + tid;
    if (id < 9 * CDIM) wdwT[id] = w_dw[(id & 511) * 9 + (id >> 9)];
  }
}

// ------- FUSED v4: wave-per-position; 8 positions/block; 8 ch/thread -------
// thread owns channels [4*lane..4*lane+3] and [256+4*lane..+3]; LN + offset
// reductions are single-wave butterflies (1 barrier total).
__global__ __launch_bounds__(512) void offset_gather_kernel(
    const float* __restrict__ t0, const float* __restrict__ x,
    const float* __restrict__ w_dwT, const float* __restrict__ b_dw,
    const float* __restrict__ ln_g, const float* __restrict__ ln_b,
    const float* __restrict__ w_off, unsigned short* __restrict__ xs) {
  __shared__ float4 sten[30 * 128];          // 3 rows x 10 cols x 512 ch = 61.4 KB

  int blk = blockIdx.x;
  int b = blk >> 9, rem = blk & 511;         // 512 blocks per batch
  int h = rem >> 3, w0 = (rem & 7) << 3;     // 8 positions per block
  int t = threadIdx.x;
  const float* base = t0 + (size_t)b * HWSZ * CDIM;

  for (int s = t; s < 30 * 128; s += 512) {
    int ps = s >> 7, q = s & 127;
    int r = ps / 10, cs = ps - r * 10;
    int hh = h + r - 1, ww = w0 + cs - 1;
    if ((unsigned)hh < 64u && (unsigned)ww < 64u) {
      gload16(base + (size_t)(hh * 64 + ww) * CDIM + 4 * q, (void*)(sten + s));
    } else {
      sten[s] = make_float4(0.f, 0.f, 0.f, 0.f);
    }
  }
  __syncthreads();

  int w = t >> 6;        // wave index = position offset within row-group
  int lane = t & 63;
  float4 acc0 = ((const float4*)b_dw)[lane];
  float4 acc1 = ((const float4*)b_dw)[64 + lane];
#pragma unroll
  for (int r = 0; r < 3; ++r)
#pragma unroll
    for (int dxi = 0; dxi < 3; ++dxi) {
      const float4* wrow = (const float4*)(w_dwT + (size_t)(r * 3 + dxi) * CDIM);
      float4 w40 = wrow[lane], w41 = wrow[64 + lane];
      int pt = (r * 10 + w + dxi) * 128;
      float4 v0 = sten[pt + lane];
      float4 v1 = sten[pt + 64 + lane];
      acc0.x = fmaf(v0.x, w40.x, acc0.x);
      acc0.y = fmaf(v0.y, w40.y, acc0.y);
      acc0.z = fmaf(v0.z, w40.z, acc0.z);
      acc0.w = fmaf(v0.w, w40.w, acc0.w);
      acc1.x = fmaf(v1.x, w41.x, acc1.x);
      acc1.y = fmaf(v1.y, w41.y, acc1.y);
      acc1.z = fmaf(v1.z, w41.z, acc1.z);
      acc1.w = fmaf(v1.w, w41.w, acc1.w);
    }
  // LayerNorm over 512 ch: one wave per position -> pure butterfly
  float s1 = acc0.x + acc0.y + acc0.z + acc0.w + acc1.x + acc1.y + acc1.z + acc1.w;
  float s2 = acc0.x * acc0.x + acc0.y * acc0.y + acc0.z * acc0.z + acc0.w * acc0.w +
             acc1.x * acc1.x + acc1.y * acc1.y + acc1.z * acc1.z + acc1.w * acc1.w;
#pragma unroll
  for (int off = 32; off; off >>= 1) {
    s1 += __shfl_xor(s1, off, 64);
    s2 += __shfl_xor(s2, off, 64);
  }
  float mean = s1 * (1.f / 512.f);
  float var = s2 * (1.f / 512.f) - mean * mean;
  float inv = 1.f / sqrtf(var + 1e-5f);

  float4 g0 = ((const float4*)ln_g)[lane], g1 = ((const float4*)ln_g)[64 + lane];
  float4 lb0 = ((const float4*)ln_b)[lane], lb1 = ((const float4*)ln_b)[64 + lane];
  float4 wy0 = ((const float4*)w_off)[lane], wy1 = ((const float4*)w_off)[64 + lane];
  float4 wx0 = ((const float4*)(w_off + CDIM))[lane], wx1 = ((const float4*)(w_off + CDIM))[64 + lane];
  float4 ge0, ge1;
  ge0.x = gelu((acc0.x - mean) * inv * g0.x + lb0.x);
  ge0.y = gelu((acc0.y - mean) * inv * g0.y + lb0.y);
  ge0.z = gelu((acc0.z - mean) * inv * g0.z + lb0.z);
  ge0.w = gelu((acc0.w - mean) * inv * g0.w + lb0.w);
  ge1.x = gelu((acc1.x - mean) * inv * g1.x + lb1.x);
  ge1.y = gelu((acc1.y - mean) * inv * g1.y + lb1.y);
  ge1.z = gelu((acc1.z - mean) * inv * g1.z + lb1.z);
  ge1.w = gelu((acc1.w - mean) * inv * g1.w + lb1.w);
  float oy = ge0.x * wy0.x + ge0.y * wy0.y + ge0.z * wy0.z + ge0.w * wy0.w +
             ge1.x * wy1.x + ge1.y * wy1.y + ge1.z * wy1.z + ge1.w * wy1.w;
  float ox = ge0.x * wx0.x + ge0.y * wx0.y + ge0.z * wx0.z + ge0.w * wx0.w +
             ge1.x * wx1.x + ge1.y * wx1.y + ge1.z * wx1.z + ge1.w * wx1.w;
#pragma unroll
  for (int off = 32; off; off >>= 1) {
    oy += __shfl_xor(oy, off, 64);
    ox += __shfl_xor(ox, off, 64);
  }
  // tail computed redundantly by all 64 lanes (identical, deterministic)
  int wcol = w0 + w;
  float ry = ((float)h + 0.5f) / 64.f * 2.f - 1.f;
  float rx = ((float)wcol + 0.5f) / 64.f * 2.f - 1.f;
  float py = tanhf(oy + ry);
  float px = tanhf(ox + rx);
  float fx = (px + 1.f) * 0.5f * 63.f;
  float fy = (py + 1.f) * 0.5f * 63.f;
  float fx0 = floorf(fx), fy0 = floorf(fy);
  float fx1 = fx0 + 1.f, fy1 = fy0 + 1.f;
  float wx1f = fx - fx0, wx0f = fx1 - fx;
  float wy1f = fy - fy0, wy0f = fy1 - fy;
  float m00 = (fy0 >= 0.f && fy0 <= 63.f && fx0 >= 0.f && fx0 <= 63.f) ? 1.f : 0.f;
  float m01 = (fy0 >= 0.f && fy0 <= 63.f && fx1 >= 0.f && fx1 <= 63.f) ? 1.f : 0.f;
  float m10 = (fy1 >= 0.f && fy1 <= 63.f && fx0 >= 0.f && fx0 <= 63.f) ? 1.f : 0.f;
  float m11 = (fy1 >= 0.f && fy1 <= 63.f && fx1 >= 0.f && fx1 <= 63.f) ? 1.f : 0.f;
  int xi0 = min(max((int)fx0, 0), 63), xi1 = min(max((int)fx1, 0), 63);
  int yi0 = min(max((int)fy0, 0), 63), yi1 = min(max((int)fy1, 0), 63);
  int i00 = yi0 * 64 + xi0, i01 = yi0 * 64 + xi1;
  int i10 = yi1 * 64 + xi0, i11 = yi1 * 64 + xi1;
  float wtx = wx0f * wy0f * m00, wty = wx1f * wy0f * m01;
  float wtz = wx0f * wy1f * m10, wtw = wx1f * wy1f * m11;

  const float* xb = x + (size_t)b * HWSZ * CDIM;
  float4 A0 = ((const float4*)(xb + (size_t)i00 * CDIM))[lane];
  float4 A1 = ((const float4*)(xb + (size_t)i00 * CDIM))[64 + lane];
  float4 B0 = ((const float4*)(xb + (size_t)i01 * CDIM))[lane];
  float4 B1 = ((const float4*)(xb + (size_t)i01 * CDIM))[64 + lane];
  float4 C0 = ((const float4*)(xb + (size_t)i10 * CDIM))[lane];
  float4 C1 = ((const float4*)(xb + (size_t)i10 * CDIM))[64 + lane];
  float4 D0 = ((const float4*)(xb + (size_t)i11 * CDIM))[lane];
  float4 D1 = ((const float4*)(xb + (size_t)i11 * CDIM))[64 + lane];
  ushort4 o0, o1;
  o0.x = f2bf(A0.x * wtx + B0.x * wty + C0.x * wtz + D0.x * wtw);
  o0.y = f2bf(A0.y * wtx + B0.y * wty + C0.y * wtz + D0.y * wtw);
  o0.z = f2bf(A0.z * wtx + B0.z * wty + C0.z * wtz + D0.z * wtw);
  o0.w = f2bf(A0.w * wtx + B0.w * wty + C0.w * wtz + D0.w * wtw);
  o1.x = f2bf(A1.x * wtx + B1.x * wty + C1.x * wtz + D1.x * wtw);
  o1.y = f2bf(A1.y * wtx + B1.y * wty + C1.y * wtz + D1.y * wtw);
  o1.z = f2bf(A1.z * wtx + B1.z * wty + C1.z * wtz + D1.z * wtw);
  o1.w = f2bf(A1.w * wtx + B1.w * wty + C1.w * wtz + D1.w * wtw);
  size_t posg = (size_t)b * HWSZ + h * 64 + wcol;
  *(ushort4*)(xs + posg * CDIM + 4 * lane) = o0;
  *(ushort4*)(xs + posg * CDIM + 256 + 4 * lane) = o1;
}

// ------- split-L attention v2: one block serves TWO queries sharing a K/V slab -------
__global__ __launch_bounds__(256) void attn_split_kernel(const float* __restrict__ qh,
                                                         const unsigned short* __restrict__ kk,
                                                         const unsigned short* __restrict__ vv,
                                                         float* __restrict__ pm,
                                                         float* __restrict__ ps,
                                                         float* __restrict__ po) {
  __shared__ float sc0[128], sc1[128];
  __shared__ float qs0[64], qs1[64];
  __shared__ float red0[4], red1[4];
  __shared__ float part0[4][64], part1[4][64];
  int bid = blockIdx.x;
  int h = bid & 7;
  int bs = bid >> 3;
  int b = bs >> 5, s = bs & 31;
  int l0 = s << 7;
  int task0 = b * 33;
  int task1 = b * 33 + s + 1;
  int tid = threadIdx.x;
  if (tid < 64) qs0[tid] = qh[(size_t)task0 * CDIM + h * 64 + tid];
  else if (tid < 128) qs1[tid - 64] = qh[(size_t)task1 * CDIM + h * 64 + (tid - 64)];
  __syncthreads();

  const unsigned short* kb = kk + ((size_t)b * HWSZ + l0) * CDIM + h * 64;
  float lmax0 = -INFINITY, lmax1 = -INFINITY;
  if (tid < 128) {
    const uint4* kr = (const uint4*)(kb + (size_t)tid * CDIM);
    float sv0 = 0.f, sv1 = 0.f;
#pragma unroll
    for (int c = 0; c < 8; ++c) {
      uint4 kv = kr[c];
      float k0 = __uint_as_float(kv.x << 16);
      float k1 = __uint_as_float(kv.x & 0xffff0000u);
      float k2 = __uint_as_float(kv.y << 16);
      float k3 = __uint_as_float(kv.y & 0xffff0000u);
      float k4 = __uint_as_float(kv.z << 16);
      float k5 = __uint_as_float(kv.z & 0xffff0000u);
      float k6 = __uint_as_float(kv.w << 16);
      float k7 = __uint_as_float(kv.w & 0xffff0000u);
      sv0 = fmaf(k0, qs0[8 * c + 0], sv0); sv1 = fmaf(k0, qs1[8 * c + 0], sv1);
      sv0 = fmaf(k1, qs0[8 * c + 1], sv0); sv1 = fmaf(k1, qs1[8 * c + 1], sv1);
      sv0 = fmaf(k2, qs0[8 * c + 2], sv0); sv1 = fmaf(k2, qs1[8 * c + 2], sv1);
      sv0 = fmaf(k3, qs0[8 * c + 3], sv0); sv1 = fmaf(k3, qs1[8 * c + 3], sv1);
      sv0 = fmaf(k4, qs0[8 * c + 4], sv0); sv1 = fmaf(k4, qs1[8 * c + 4], sv1);
      sv0 = fmaf(k5, qs0[8 * c + 5], sv0); sv1 = fmaf(k5, qs1[8 * c + 5], sv1);
      sv0 = fmaf(k6, qs0[8 * c + 6], sv0); sv1 = fmaf(k6, qs1[8 * c + 6], sv1);
      sv0 = fmaf(k7, qs0[8 * c + 7], sv0); sv1 = fmaf(k7, qs1[8 * c + 7], sv1);
    }
    sv0 *= 0.125f; sv1 *= 0.125f;
    sc0[tid] = sv0; sc1[tid] = sv1;
    lmax0 = sv0; lmax1 = sv1;
  }
#pragma unroll
  for (int off = 32; off; off >>= 1) {
    lmax0 = fmaxf(lmax0, __shfl_xor(lmax0, off, 64));
    lmax1 = fmaxf(lmax1, __shfl_xor(lmax1, off, 64));
  }
  if (!(tid & 63)) { red0[tid >> 6] = lmax0; red1[tid >> 6] = lmax1; }
  __syncthreads();
  lmax0 = fmaxf(fmaxf(red0[0], red0[1]), fmaxf(red0[2], red0[3]));
  lmax1 = fmaxf(fmaxf(red1[0], red1[1]), fmaxf(red1[2], red1[3]));
  __syncthreads();

  float ls0 = 0.f, ls1 = 0.f;
  if (tid < 128) {
    float e0 = expf(sc0[tid] - lmax0);
    float e1 = expf(sc1[tid] - lmax1);
    sc0[tid] = e0; sc1[tid] = e1;
    ls0 = e0; ls1 = e1;
  }
#pragma unroll
  for (int off = 32; off; off >>= 1) {
    ls0 += __shfl_xor(ls0, off, 64);
    ls1 += __shfl_xor(ls1, off, 64);
  }
  if (!(tid & 63)) { red0[tid >> 6] = ls0; red1[tid >> 6] = ls1; }
  __syncthreads();
  float tsum0 = red0[0] + red0[1] + red0[2] + red0[3];
  float tsum1 = red1[0] + red1[1] + red1[2] + red1[3];

  int ch = tid & 63, g = tid >> 6;
  const unsigned short* vb = vv + ((size_t)b * HWSZ + l0) * CDIM + h * 64 + ch;
  float o0 = 0.f, o1 = 0.f;
#pragma unroll 4
  for (int l = g; l < 128; l += 4) {
    float vvv = bf2f(vb[(size_t)l * CDIM]);
    o0 = fmaf(sc0[l], vvv, o0);
    o1 = fmaf(sc1[l], vvv, o1);
  }
  part0[g][ch] = o0;
  part1[g][ch] = o1;
  __syncthreads();
  if (tid < 64) {
    float r0 = part0[0][tid] + part0[1][tid] + part0[2][tid] + part0[3][tid];
    float r1 = part1[0][tid] + part1[1][tid] + part1[2][tid] + part1[3][tid];
    int bid0 = (b * 64 + s) * 8 + h;
    int bid1 = (b * 64 + 32 + s) * 8 + h;
    po[(size_t)bid0 * 64 + tid] = r0;
    po[(size_t)bid1 * 64 + tid] = r1;
    if (tid == 0) {
      pm[bid0] = lmax0; ps[bid0] = tsum0;
      pm[bid1] = lmax1; ps[bid1] = tsum1;
    }
  }
}

// ------- merge partials (LSE combine) -------
__global__ __launch_bounds__(64) void attn_reduce_kernel(const float* __restrict__ pm,
                                                         const float* __restrict__ ps,
                                                         const float* __restrict__ po,
                                                         float* __restrict__ oo) {
  int bid = blockIdx.x;
  int h = bid & 7, task = bid >> 3;
  int b = task / 33, qidx = task - b * 33;
  int sbase = (qidx == 0) ? 0 : 31 + qidx;
  int ns = (qidx == 0) ? 32 : 1;
  int t = threadIdx.x;
  float mg = -INFINITY;
  for (int i = 0; i < ns; ++i) mg = fmaxf(mg, pm[((size_t)(b * 64 + sbase + i)) * 8 + h]);
  float tot = 0.f, o = 0.f;
  for (int i = 0; i < ns; ++i) {
    size_t pi = ((size_t)(b * 64 + sbase + i)) * 8 + h;
    float w = expf(pm[pi] - mg);
    tot = fmaf(ps[pi], w, tot);
    o = fmaf(po[pi * 64 + t], w, o);
  }
  oo[(size_t)task * CDIM + h * 64 + t] = o / tot;
}

extern "C" void kernel_launch(void* const* d_in, const int* in_sizes, int n_in,
                              void* d_out, int out_size, void* d_ws, size_t ws_size,
                              hipStream_t stream) {
  const float* q          = (const float*)d_in[0];
  const float* x          = (const float*)d_in[1];
  const float* w_off_proj = (const float*)d_in[2];
  const float* b_off_proj = (const float*)d_in[3];
  const float* w_dw       = (const float*)d_in[4];
  const float* b_dw       = (const float*)d_in[5];
  const float* ln_g       = (const float*)d_in[6];
  const float* ln_b       = (const float*)d_in[7];
  const float* w_off      = (const float*)d_in[8];
  const float* w_q        = (const float*)d_in[9];
  const float* b_q        = (const float*)d_in[10];
  const float* w_k        = (const float*)d_in[11];
  const float* b_k        = (const float*)d_in[12];
  const float* w_v        = (const float*)d_in[13];
  const float* b_v        = (const float*)d_in[14];
  const float* w_o        = (const float*)d_in[15];
  const float* b_o        = (const float*)d_in[16];

  char* ws = (char*)d_ws;
  size_t off = 0;
  const size_t NBIG = (size_t)BATCH * HWSZ * CDIM;
  const int NSPLIT = BATCH * 64 * 8;
  float* t0    = (float*)(ws + off);                  off += NBIG * 4;   // 134 MB
  unsigned short* xs_bf = (unsigned short*)(ws + off); off += NBIG * 2;
  unsigned short* k_bf  = (unsigned short*)(ws + off); off += NBIG * 2;
  unsigned short* v_bf  = (unsigned short*)(ws + off); off += NBIG * 2;
  unsigned short* wphi = (unsigned short*)(ws + off);  off += (size_t)CDIM * CDIM * 2;
  unsigned short* wplo = (unsigned short*)(ws + off);  off += (size_t)CDIM * CDIM * 2;
  unsigned short* wkv_bf = (unsigned short*)(ws + off); off += (size_t)2 * CDIM * CDIM * 2;
  float* w_dwT = (float*)(ws + off);                  off += (size_t)9 * CDIM * 4;
  float* qh    = (float*)(ws + off);                  off += (size_t)BATCH * NQTOT * CDIM * 4;
  float* o_all = (float*)(ws + off);                  off += (size_t)BATCH * NQTOT * CDIM * 4;
  float* pm    = (float*)(ws + off);                  off += (size_t)NSPLIT * 4;
  float* ps    = (float*)(ws + off);                  off += (size_t)NSPLIT * 4;
  float* po    = (float*)(ws + off);                  off += (size_t)NSPLIT * 64 * 4;

  const int Mbig = BATCH * HWSZ;  // 65536
  const int Msm  = BATCH * NQTOT; // 528
  dim3 gSm2(CDIM / SBN, (Msm + SBM - 1) / SBM);   // (8, 9)
  dim3 gMf(CDIM / 128, Mbig / 128);
  dim3 gKV(2 * CDIM / 128, Mbig / 128);

  // 0) all weight conversions in one launch
  conv_all<<<786, 256, 0, stream>>>(w_off_proj, w_k, w_v, w_dw, wphi, wplo, wkv_bf, w_dwT);
  // 1) t0 = x @ w_off_proj^T + b ; BK=64, swizzled, split, A-reg prefetch
  gemm3_nt<<<gMf, 256, 0, stream>>>(x, wphi, wplo, b_off_proj, t0);
  // 2) fused depthwise+LN+GELU+offset+gather, wave-per-position -> bf16 xs
  offset_gather_kernel<<<Mbig / 8, 512, 0, stream>>>(t0, x, w_dwT, b_dw, ln_g, ln_b, w_off, xs_bf);
  // 3) merged K|V projection; BK=32
  gemm_kv_nt<<<gKV, 256, 0, stream>>>(xs_bf, wkv_bf, b_k, b_v, k_bf, v_bf);
  // 4) Q projection (64x64 tiles)
  gemm_sm_nt<<<gSm2, 256, 0, stream>>>(q, w_q, b_q, qh, Msm);
  // 5) dual-query split-L attention + LSE merge
  attn_split_kernel<<<NSPLIT / 2, 256, 0, stream>>>(qh, k_bf, v_bf, pm, ps, po);
  attn_reduce_kernel<<<Msm * 8, 64, 0, stream>>>(pm, ps, po, o_all);
  // 6) output projection -> d_out (64x64 tiles)
  gemm_sm_nt<<<gSm2, 256, 0, stream>>>(o_all, w_o, b_o, (float*)d_out, Msm);
}